// Round 6
// baseline (1263.189 us; speedup 1.0000x reference)
//
#include <hip/hip_runtime.h>
#include <hip/hip_bf16.h>

#define NB  4
#define NH  8
#define NC  16
#define ND  64
#define NN  16384
#define NG  32
#define NG3 32768
#define NKV 152
#define KEPS 1e-5f

// ---------------------------------------------------------------------------
// Kernel 1: fused kv-GEMM + BN + key transform + tanh + lattice coords.
// ---------------------------------------------------------------------------
__global__ __launch_bounds__(128)
void k_front(const float* __restrict__ x,      // [B,D,N]
             const float* __restrict__ orig,   // [B,3,N]
             const float* __restrict__ wkv,    // [152,64]
             const float* __restrict__ kg, const float* __restrict__ kb,
             const float* __restrict__ km, const float* __restrict__ kvv,
             const float* __restrict__ vg, const float* __restrict__ vb,
             const float* __restrict__ vm, const float* __restrict__ vv,
             const float* __restrict__ Wt,     // [8,3,3]
             const float* __restrict__ bt,     // [8,3]
             float* __restrict__ values,       // [B,H,N,C]
             float4* __restrict__ pre,         // [B,H,N]
             int* __restrict__ hist)           // [B*H*32]
{
    __shared__ float wl[NKV * ND];
    __shared__ float ksc[24], ksh[24], vsc[128], vsh[128], wts[72], bts[24];
    const int tid = threadIdx.x;

    for (int i = tid; i < NKV * ND; i += 128) wl[i] = wkv[i];
    if (tid < 24) {
        float s = rsqrtf(kvv[tid] + KEPS) * kg[tid];
        ksc[tid] = s;
        ksh[tid] = kb[tid] - km[tid] * s;
    }
    if (tid < 128) {
        float s = rsqrtf(vv[tid] + KEPS) * vg[tid];
        vsc[tid] = s;
        vsh[tid] = vb[tid] - vm[tid] * s;
    }
    if (tid < 72) wts[tid] = Wt[tid];
    if (tid < 24) bts[tid] = bt[tid];
    __syncthreads();

    const int bpb = NN / 128;                 // blocks per batch
    const int b = blockIdx.x / bpb;
    const int n = (blockIdx.x % bpb) * 128 + tid;

    float xr[ND];
    #pragma unroll
    for (int d = 0; d < ND; ++d)
        xr[d] = x[((long)b * ND + d) * NN + n];

    float ko[24];
    #pragma unroll 1
    for (int o = 0; o < 24; o += 4) {
        float s0 = 0.f, s1 = 0.f, s2 = 0.f, s3 = 0.f;
        #pragma unroll
        for (int d = 0; d < ND; ++d) {
            float xv = xr[d];
            s0 = fmaf(wl[(o + 0) * ND + d], xv, s0);
            s1 = fmaf(wl[(o + 1) * ND + d], xv, s1);
            s2 = fmaf(wl[(o + 2) * ND + d], xv, s2);
            s3 = fmaf(wl[(o + 3) * ND + d], xv, s3);
        }
        ko[o + 0] = fmaf(s0, ksc[o + 0], ksh[o + 0]);
        ko[o + 1] = fmaf(s1, ksc[o + 1], ksh[o + 1]);
        ko[o + 2] = fmaf(s2, ksc[o + 2], ksh[o + 2]);
        ko[o + 3] = fmaf(s3, ksc[o + 3], ksh[o + 3]);
    }

    #pragma unroll 1
    for (int oc = 0; oc < 128; oc += 4) {
        float s0 = 0.f, s1 = 0.f, s2 = 0.f, s3 = 0.f;
        #pragma unroll
        for (int d = 0; d < ND; ++d) {
            float xv = xr[d];
            s0 = fmaf(wl[(24 + oc + 0) * ND + d], xv, s0);
            s1 = fmaf(wl[(24 + oc + 1) * ND + d], xv, s1);
            s2 = fmaf(wl[(24 + oc + 2) * ND + d], xv, s2);
            s3 = fmaf(wl[(24 + oc + 3) * ND + d], xv, s3);
        }
        int h = oc >> 4, c = oc & 15;
        float* vp = values + (((long)(b * NH + h) * NN + n) * NC + c);
        vp[0] = fmaf(s0, vsc[oc + 0], vsh[oc + 0]);
        vp[1] = fmaf(s1, vsc[oc + 1], vsh[oc + 1]);
        vp[2] = fmaf(s2, vsc[oc + 2], vsh[oc + 2]);
        vp[3] = fmaf(s3, vsc[oc + 3], vsh[oc + 3]);
    }

    const float o0 = orig[((long)b * 3 + 0) * NN + n];
    const float o1 = orig[((long)b * 3 + 1) * NN + n];
    const float o2 = orig[((long)b * 3 + 2) * NN + n];

    #pragma unroll 1
    for (int h = 0; h < NH; ++h) {
        float p0 = o0 + ko[h * 3 + 0];
        float p1 = o1 + ko[h * 3 + 1];
        float p2 = o2 + ko[h * 3 + 2];
        float t0 = fmaf(wts[h * 9 + 0], p0, fmaf(wts[h * 9 + 1], p1, fmaf(wts[h * 9 + 2], p2, bts[h * 3 + 0])));
        float t1 = fmaf(wts[h * 9 + 3], p0, fmaf(wts[h * 9 + 4], p1, fmaf(wts[h * 9 + 5], p2, bts[h * 3 + 1])));
        float t2 = fmaf(wts[h * 9 + 6], p0, fmaf(wts[h * 9 + 7], p1, fmaf(wts[h * 9 + 8], p2, bts[h * 3 + 2])));
        float l0 = tanhf(t0), l1 = tanhf(t1), l2 = tanhf(t2);
        float pos0 = (l0 + 1.f) * 15.5f;
        float pos1 = (l1 + 1.f) * 15.5f;
        float pos2 = (l2 + 1.f) * 15.5f;
        float b0 = fminf(fmaxf(floorf(pos0), 0.f), 30.f);
        float b1 = fminf(fmaxf(floorf(pos1), 0.f), 30.f);
        float b2 = fminf(fmaxf(floorf(pos2), 0.f), 30.f);
        int ix = (int)b0, iy = (int)b1, iz = (int)b2;
        float fx = pos0 - b0, fy = pos1 - b1, fz = pos2 - b2;
        int ibase = (ix * NG + iy) * NG + iz;
        float4 pr;
        pr.x = __int_as_float(ibase);
        pr.y = fx; pr.z = fy; pr.w = fz;
        int bh = b * NH + h;
        pre[(long)bh * NN + n] = pr;
        atomicAdd(&hist[bh * NG + ix], 1);
    }
}

// ---------------------------------------------------------------------------
// Kernel 1b: exclusive prefix scan of the 1024 bucket counts (one block).
// ---------------------------------------------------------------------------
__global__ __launch_bounds__(1024)
void k_scan(const int* __restrict__ hist, int* __restrict__ offs,
            int* __restrict__ offs_live)
{
    __shared__ int tmp[1024];
    const int tid = threadIdx.x;
    int v = hist[tid];
    tmp[tid] = v;
    __syncthreads();
    #pragma unroll
    for (int d = 1; d < 1024; d <<= 1) {
        int t = (tid >= d) ? tmp[tid - d] : 0;
        __syncthreads();
        tmp[tid] += t;
        __syncthreads();
    }
    int excl = tmp[tid] - v;
    offs[tid] = excl;
    offs_live[tid] = excl;
}

// ---------------------------------------------------------------------------
// Kernel 1c: scatter records into bucket order.
// Record: {(lo | n<<10), fx, fy, fz}, lo = iy*32+iz (10 bits), n (14 bits).
// ---------------------------------------------------------------------------
__global__ __launch_bounds__(256)
void k_scatter(const float4* __restrict__ pre, int* __restrict__ offs_live,
               float4* __restrict__ binned)
{
    long t = (long)blockIdx.x * 256 + threadIdx.x;
    float4 r = pre[t];
    int ibase = __float_as_int(r.x);
    int bh = (int)(t / NN);
    int n  = (int)(t % NN);
    int bucket = bh * NG + (ibase >> 10);
    int slot = atomicAdd(&offs_live[bucket], 1);
    float4 rec;
    rec.x = __int_as_float((ibase & 1023) | (n << 10));
    rec.y = r.y; rec.z = r.z; rec.w = r.w;
    binned[slot] = rec;
}

// ---------------------------------------------------------------------------
// Kernel 2: splat — block (bh, rx) accumulates its x-plane from buckets
// rx (weight 1-fx) and rx-1 (weight fx). LDS accumulation via native
// ds_add_f32 (unsafeAtomicAdd). Channel slot rotated by (L>>1) so the bank
// index is a function of L mod 32 (full 32-bank spread).
// ---------------------------------------------------------------------------
__device__ __forceinline__ int rot_slot(int L, int c) {
    return (L << 4) | ((c + (L >> 1)) & 15);
}

__global__ __launch_bounds__(1024)
void k_splat3(const float* __restrict__ values, const float4* __restrict__ binned,
              const int* __restrict__ offs, const int* __restrict__ offs_end,
              float* __restrict__ grid)
{
    __shared__ float sg[NG * NG * NC];   // 64 KB, [L=y*32+z][c] rotated
    const int tid = threadIdx.x;
    const int rx = blockIdx.x & 31;
    const int bh = blockIdx.x >> 5;

    for (int i = tid; i < NG * NG * NC; i += 1024) sg[i] = 0.f;
    __syncthreads();

    const float* vbp = values + (long)bh * NN * NC;

    #pragma unroll 1
    for (int pass = 0; pass < 2; ++pass) {
        int bk = rx - pass;
        if (bk < 0) continue;
        int s = offs[bh * NG + bk];
        int e = offs_end[bh * NG + bk];
        for (int i = s + tid; i < e; i += 1024) {
            float4 r = binned[i];
            int pk = __float_as_int(r.x);
            int lo = pk & 1023;
            int n  = pk >> 10;
            float fx = r.y, fy = r.z, fz = r.w;
            float wx = pass ? fx : (1.f - fx);
            float gy = 1.f - fy, gz = 1.f - fz;
            float w00 = wx * gy * gz;
            float w01 = wx * gy * fz;
            float w10 = wx * fy * gz;
            float w11 = wx * fy * fz;
            const float4* vr = (const float4*)(vbp + (long)n * NC);
            float4 v0 = vr[0], v1 = vr[1], v2 = vr[2], v3 = vr[3];
            float v[16];
            ((float4*)v)[0] = v0; ((float4*)v)[1] = v1;
            ((float4*)v)[2] = v2; ((float4*)v)[3] = v3;
            const int L00 = lo, L01 = lo + 1, L10 = lo + 32, L11 = lo + 33;
            #pragma unroll
            for (int c = 0; c < 16; ++c) {
                float vc = v[c];
                unsafeAtomicAdd(&sg[rot_slot(L00, c)], vc * w00);
                unsafeAtomicAdd(&sg[rot_slot(L01, c)], vc * w01);
                unsafeAtomicAdd(&sg[rot_slot(L10, c)], vc * w10);
                unsafeAtomicAdd(&sg[rot_slot(L11, c)], vc * w11);
            }
        }
    }
    __syncthreads();

    float* gb = grid + ((long)bh * NG3 + rx * (NG * NG)) * NC;
    for (int i = tid; i < NG * NG * NC; i += 1024) {
        int L = i >> 4, c = i & 15;
        gb[i] = sg[rot_slot(L, c)];
    }
}

// ---------------------------------------------------------------------------
// Kernel 3: grouped 3x3x3 conv, SAME padding, direct fp32 with LDS tiles
// ---------------------------------------------------------------------------
__global__ __launch_bounds__(256)
void k_conv(const float* __restrict__ grid, const float* __restrict__ cw,
            const float* __restrict__ cb, float* __restrict__ convo)
{
    __shared__ float it[16 * 6 * 6 * 10];   // [ic][xx][yy][zz]
    __shared__ float wt[432 * 16];          // [r][oc]
    const int tid = threadIdx.x;
    const int bid = blockIdx.x;
    const int zb = bid & 3, yb = (bid >> 2) & 7, xb = (bid >> 5) & 7;
    const int bh = bid >> 8;
    const int h = bh & 7;

    for (int e = tid; e < 6912; e += 256) {
        int oc = e / 432, r = e % 432;
        wt[r * 16 + oc] = cw[(h * 16 + oc) * 432 + r];
    }
    const float* gbase = grid + (long)bh * NG3 * NC;
    for (int e = tid; e < 5760; e += 256) {
        int ic = e & 15, cell = e >> 4;
        int zz = cell % 10, yy = (cell / 10) % 6, xx = cell / 60;
        int gx = xb * 4 + xx - 1, gy = yb * 4 + yy - 1, gz = zb * 8 + zz - 1;
        float v = 0.f;
        if ((unsigned)gx < NG && (unsigned)gy < NG && (unsigned)gz < NG)
            v = gbase[(((long)gx * NG + gy) * NG + gz) * NC + ic];
        it[ic * 360 + xx * 60 + yy * 10 + zz] = v;
    }
    __syncthreads();

    const int oc = tid & 15, txty = tid >> 4;
    const int tx = txty & 3, ty = txty >> 2;
    float acc[8];
    #pragma unroll
    for (int z = 0; z < 8; ++z) acc[z] = 0.f;

    #pragma unroll 1
    for (int ic = 0; ic < 16; ++ic) {
        #pragma unroll
        for (int kx = 0; kx < 3; ++kx) {
            #pragma unroll
            for (int ky = 0; ky < 3; ++ky) {
                const float* ib = &it[ic * 360 + (tx + kx) * 60 + (ty + ky) * 10];
                const float* wp = &wt[(ic * 27 + kx * 9 + ky * 3) * 16 + oc];
                float w0 = wp[0], w1 = wp[16], w2 = wp[32];
                #pragma unroll
                for (int z = 0; z < 8; ++z)
                    acc[z] = fmaf(ib[z], w0, fmaf(ib[z + 1], w1, fmaf(ib[z + 2], w2, acc[z])));
            }
        }
    }
    float bias = cb[h * 16 + oc];
    int gx = xb * 4 + tx, gy = yb * 4 + ty;
    float* ob = convo + (long)bh * NG3 * NC + (((long)gx * NG + gy) * NG + zb * 8) * NC + oc;
    #pragma unroll
    for (int z = 0; z < 8; ++z) ob[z * NC] = acc[z] + bias;
}

// ---------------------------------------------------------------------------
// Kernel 4: slice (weighted gather) + BN + ReLU, output f32 [B, H*C, N]
// ---------------------------------------------------------------------------
__global__ __launch_bounds__(256)
void k_slice(const float* __restrict__ convo, const float4* __restrict__ pre,
             const float* __restrict__ ag, const float* __restrict__ ab,
             const float* __restrict__ am, const float* __restrict__ av,
             float* __restrict__ out)
{
    __shared__ float asc[128], ash[128];
    const int tid = threadIdx.x;
    if (tid < 128) {
        float s = rsqrtf(av[tid] + KEPS) * ag[tid];
        asc[tid] = s;
        ash[tid] = ab[tid] - am[tid] * s;
    }
    __syncthreads();

    long t = (long)blockIdx.x * 256 + tid;
    long bh = t / NN;
    int n = (int)(t % NN);
    int b = (int)(bh >> 3), h = (int)(bh & 7);
    const float* g = convo + bh * (long)NG3 * NC;

    float4 r = pre[t];
    int ibase = __float_as_int(r.x);
    float fx = r.y, fy = r.z, fz = r.w;
    float gx = 1.f - fx, gy = 1.f - fy, gz = 1.f - fz;
    const float ws8[8] = {gx*gy*gz, gx*gy*fz, gx*fy*gz, gx*fy*fz,
                          fx*gy*gz, fx*gy*fz, fx*fy*gz, fx*fy*fz};
    const int offs[8] = {0, 1, NG, NG + 1, NG*NG, NG*NG + 1, NG*NG + NG, NG*NG + NG + 1};

    float acc[NC];
    #pragma unroll
    for (int c = 0; c < NC; ++c) acc[c] = 0.f;
    #pragma unroll
    for (int ci = 0; ci < 8; ++ci) {
        float w = ws8[ci];
        const float* gc = g + (long)(ibase + offs[ci]) * NC;
        #pragma unroll
        for (int c = 0; c < NC; ++c) acc[c] = fmaf(gc[c], w, acc[c]);
    }
    float* ob = out + ((long)b * 128 + h * 16) * NN + n;
    #pragma unroll
    for (int c = 0; c < NC; ++c) {
        float rr = fmaf(acc[c], asc[h * 16 + c], ash[h * 16 + c]);
        ob[(long)c * NN] = fmaxf(rr, 0.f);
    }
}

// ---------------------------------------------------------------------------
extern "C" void kernel_launch(void* const* d_in, const int* in_sizes, int n_in,
                              void* d_out, int out_size, void* d_ws, size_t ws_size,
                              hipStream_t stream)
{
    (void)in_sizes; (void)n_in; (void)out_size; (void)ws_size;
    const float* x    = (const float*)d_in[0];
    const float* orig = (const float*)d_in[1];
    const float* wkv  = (const float*)d_in[2];
    const float* kg   = (const float*)d_in[3];
    const float* kb   = (const float*)d_in[4];
    const float* km   = (const float*)d_in[5];
    const float* kvv  = (const float*)d_in[6];
    const float* vg   = (const float*)d_in[7];
    const float* vb   = (const float*)d_in[8];
    const float* vm   = (const float*)d_in[9];
    const float* vv   = (const float*)d_in[10];
    const float* Wt   = (const float*)d_in[11];
    const float* bt   = (const float*)d_in[12];
    const float* cw   = (const float*)d_in[13];
    const float* cb   = (const float*)d_in[14];
    const float* ag   = (const float*)d_in[15];
    const float* ab   = (const float*)d_in[16];
    const float* am   = (const float*)d_in[17];
    const float* av   = (const float*)d_in[18];

    char* ws = (char*)d_ws;
    float*  values    = (float*) (ws);                 // 33,554,432 B
    float4* pre       = (float4*)(ws + 33554432);      //  8,388,608 B
    float4* binned    = (float4*)(ws + 41943040);      //  8,388,608 B
    int*    hist      = (int*)   (ws + 50331648);      //      4,096 B
    int*    offs      = (int*)   (ws + 50335744);      //      4,096 B
    int*    offs_live = (int*)   (ws + 50339840);      //      4,096 B
    float*  grid      = (float*) (ws + 50343936);      // 67,108,864 B
    float*  convo     = (float*) (ws + 117452800);     // 67,108,864 B

    hipMemsetAsync(hist, 0, NB * NH * NG * sizeof(int), stream);

    k_front<<<dim3((NB * NN) / 128), dim3(128), 0, stream>>>(
        x, orig, wkv, kg, kb, km, kvv, vg, vb, vm, vv, Wt, bt, values, pre, hist);

    k_scan<<<dim3(1), dim3(1024), 0, stream>>>(hist, offs, offs_live);

    k_scatter<<<dim3((NB * NH * NN) / 256), dim3(256), 0, stream>>>(pre, offs_live, binned);

    k_splat3<<<dim3(NB * NH * NG), dim3(1024), 0, stream>>>(values, binned, offs, offs_live, grid);

    k_conv<<<dim3(NB * NH * 256), dim3(256), 0, stream>>>(grid, cw, cb, convo);

    k_slice<<<dim3((NB * NH * NN) / 256), dim3(256), 0, stream>>>(
        convo, pre, ag, ab, am, av, (float*)d_out);
}

// Round 7
// 656.676 us; speedup vs baseline: 1.9236x; 1.9236x over previous
//
#include <hip/hip_runtime.h>
#include <hip/hip_bf16.h>

#define NB  4
#define NH  8
#define NC  16
#define ND  64
#define NN  16384
#define NG  32
#define NG3 32768
#define NKV 152
#define KEPS 1e-5f

// ---------------------------------------------------------------------------
// Kernel 1: fused kv-GEMM + BN + key transform + tanh + lattice coords.
// Emits values [B,H,N,C], pre [B,H,N] {ibase,fx,fy,fz}, and per-CELL
// histogram hist[bh*32768 + ibase] (1M buckets, ~0.5 records each).
// ---------------------------------------------------------------------------
__global__ __launch_bounds__(128)
void k_front(const float* __restrict__ x,      // [B,D,N]
             const float* __restrict__ orig,   // [B,3,N]
             const float* __restrict__ wkv,    // [152,64]
             const float* __restrict__ kg, const float* __restrict__ kb,
             const float* __restrict__ km, const float* __restrict__ kvv,
             const float* __restrict__ vg, const float* __restrict__ vb,
             const float* __restrict__ vm, const float* __restrict__ vv,
             const float* __restrict__ Wt,     // [8,3,3]
             const float* __restrict__ bt,     // [8,3]
             float* __restrict__ values,       // [B,H,N,C]
             float4* __restrict__ pre,         // [B,H,N]
             int* __restrict__ hist)           // [B*H*32768]
{
    __shared__ float wl[NKV * ND];
    __shared__ float ksc[24], ksh[24], vsc[128], vsh[128], wts[72], bts[24];
    const int tid = threadIdx.x;

    for (int i = tid; i < NKV * ND; i += 128) wl[i] = wkv[i];
    if (tid < 24) {
        float s = rsqrtf(kvv[tid] + KEPS) * kg[tid];
        ksc[tid] = s;
        ksh[tid] = kb[tid] - km[tid] * s;
    }
    if (tid < 128) {
        float s = rsqrtf(vv[tid] + KEPS) * vg[tid];
        vsc[tid] = s;
        vsh[tid] = vb[tid] - vm[tid] * s;
    }
    if (tid < 72) wts[tid] = Wt[tid];
    if (tid < 24) bts[tid] = bt[tid];
    __syncthreads();

    const int bpb = NN / 128;                 // blocks per batch
    const int b = blockIdx.x / bpb;
    const int n = (blockIdx.x % bpb) * 128 + tid;

    float xr[ND];
    #pragma unroll
    for (int d = 0; d < ND; ++d)
        xr[d] = x[((long)b * ND + d) * NN + n];

    float ko[24];
    #pragma unroll 1
    for (int o = 0; o < 24; o += 4) {
        float s0 = 0.f, s1 = 0.f, s2 = 0.f, s3 = 0.f;
        #pragma unroll
        for (int d = 0; d < ND; ++d) {
            float xv = xr[d];
            s0 = fmaf(wl[(o + 0) * ND + d], xv, s0);
            s1 = fmaf(wl[(o + 1) * ND + d], xv, s1);
            s2 = fmaf(wl[(o + 2) * ND + d], xv, s2);
            s3 = fmaf(wl[(o + 3) * ND + d], xv, s3);
        }
        ko[o + 0] = fmaf(s0, ksc[o + 0], ksh[o + 0]);
        ko[o + 1] = fmaf(s1, ksc[o + 1], ksh[o + 1]);
        ko[o + 2] = fmaf(s2, ksc[o + 2], ksh[o + 2]);
        ko[o + 3] = fmaf(s3, ksc[o + 3], ksh[o + 3]);
    }

    #pragma unroll 1
    for (int oc = 0; oc < 128; oc += 4) {
        float s0 = 0.f, s1 = 0.f, s2 = 0.f, s3 = 0.f;
        #pragma unroll
        for (int d = 0; d < ND; ++d) {
            float xv = xr[d];
            s0 = fmaf(wl[(24 + oc + 0) * ND + d], xv, s0);
            s1 = fmaf(wl[(24 + oc + 1) * ND + d], xv, s1);
            s2 = fmaf(wl[(24 + oc + 2) * ND + d], xv, s2);
            s3 = fmaf(wl[(24 + oc + 3) * ND + d], xv, s3);
        }
        int h = oc >> 4, c = oc & 15;
        float* vp = values + (((long)(b * NH + h) * NN + n) * NC + c);
        vp[0] = fmaf(s0, vsc[oc + 0], vsh[oc + 0]);
        vp[1] = fmaf(s1, vsc[oc + 1], vsh[oc + 1]);
        vp[2] = fmaf(s2, vsc[oc + 2], vsh[oc + 2]);
        vp[3] = fmaf(s3, vsc[oc + 3], vsh[oc + 3]);
    }

    const float o0 = orig[((long)b * 3 + 0) * NN + n];
    const float o1 = orig[((long)b * 3 + 1) * NN + n];
    const float o2 = orig[((long)b * 3 + 2) * NN + n];

    #pragma unroll 1
    for (int h = 0; h < NH; ++h) {
        float p0 = o0 + ko[h * 3 + 0];
        float p1 = o1 + ko[h * 3 + 1];
        float p2 = o2 + ko[h * 3 + 2];
        float t0 = fmaf(wts[h * 9 + 0], p0, fmaf(wts[h * 9 + 1], p1, fmaf(wts[h * 9 + 2], p2, bts[h * 3 + 0])));
        float t1 = fmaf(wts[h * 9 + 3], p0, fmaf(wts[h * 9 + 4], p1, fmaf(wts[h * 9 + 5], p2, bts[h * 3 + 1])));
        float t2 = fmaf(wts[h * 9 + 6], p0, fmaf(wts[h * 9 + 7], p1, fmaf(wts[h * 9 + 8], p2, bts[h * 3 + 2])));
        float l0 = tanhf(t0), l1 = tanhf(t1), l2 = tanhf(t2);
        float pos0 = (l0 + 1.f) * 15.5f;
        float pos1 = (l1 + 1.f) * 15.5f;
        float pos2 = (l2 + 1.f) * 15.5f;
        float b0 = fminf(fmaxf(floorf(pos0), 0.f), 30.f);
        float b1 = fminf(fmaxf(floorf(pos1), 0.f), 30.f);
        float b2 = fminf(fmaxf(floorf(pos2), 0.f), 30.f);
        int ix = (int)b0, iy = (int)b1, iz = (int)b2;
        float fx = pos0 - b0, fy = pos1 - b1, fz = pos2 - b2;
        int ibase = (ix * NG + iy) * NG + iz;
        float4 pr;
        pr.x = __int_as_float(ibase);
        pr.y = fx; pr.z = fy; pr.w = fz;
        int bh = b * NH + h;
        pre[(long)bh * NN + n] = pr;
        atomicAdd(&hist[bh * NG3 + ibase], 1);
    }
}

// ---------------------------------------------------------------------------
// Kernel 1b: per-bh exclusive prefix scan over 32768 cell counts.
// 32 blocks (one per bh) x 1024 threads; each thread handles 32 cells.
// ---------------------------------------------------------------------------
__global__ __launch_bounds__(1024)
void k_scan_cells(const int* __restrict__ hist, int* __restrict__ offs,
                  int* __restrict__ offs_live)
{
    __shared__ int tsum[1024];
    const int bh = blockIdx.x, tid = threadIdx.x;
    const int* hb = hist + (long)bh * NG3;

    int s = 0;
    #pragma unroll 4
    for (int j = 0; j < 32; ++j) s += hb[tid * 32 + j];
    tsum[tid] = s;
    __syncthreads();
    for (int d = 1; d < 1024; d <<= 1) {
        int t = (tid >= d) ? tsum[tid - d] : 0;
        __syncthreads();
        tsum[tid] += t;
        __syncthreads();
    }
    int run = bh * NN + tsum[tid] - s;   // global exclusive offset (per-bh region)
    int* ob = offs + (long)bh * NG3;
    int* lb = offs_live + (long)bh * NG3;
    #pragma unroll 4
    for (int j = 0; j < 32; ++j) {
        int c = tid * 32 + j;
        ob[c] = run;
        lb[c] = run;
        run += hb[c];
    }
}

// ---------------------------------------------------------------------------
// Kernel 1c: scatter records into cell order, embedding the 16 channel
// values (read coalesced here). Record = 5 x float4 = 80 B:
//   [0] = {fx, fy, fz, unused}, [1..4] = values[0..15]
// ---------------------------------------------------------------------------
__global__ __launch_bounds__(256)
void k_scatter(const float4* __restrict__ pre, const float* __restrict__ values,
               int* __restrict__ offs_live, float4* __restrict__ binned5)
{
    long t = (long)blockIdx.x * 256 + threadIdx.x;   // (b*H+h)*N + n
    float4 r = pre[t];
    int ibase = __float_as_int(r.x);
    int bh = (int)(t >> 14);
    int slot = atomicAdd(&offs_live[(long)bh * NG3 + ibase], 1);
    const float4* vp = (const float4*)(values + t * NC);
    float4 v0 = vp[0], v1 = vp[1], v2 = vp[2], v3 = vp[3];
    float4* out = binned5 + (long)slot * 5;
    out[0] = make_float4(r.y, r.z, r.w, 0.f);
    out[1] = v0; out[2] = v1; out[3] = v2; out[4] = v3;
}

// ---------------------------------------------------------------------------
// Kernel 2: splat — atomic-free. Block = (bh, x-plane); thread = one (y,z)
// cell, 16 accumulators in VGPRs. Walks its 8 neighbor base-cell segments
// (contiguous 80 B records), pure FMA, coalesced 64 B/thread output.
// ---------------------------------------------------------------------------
__global__ __launch_bounds__(1024)
void k_splat4(const float4* __restrict__ binned5, const int* __restrict__ hist,
              const int* __restrict__ offs, float* __restrict__ grid)
{
    const int tid = threadIdx.x;
    const int rx = blockIdx.x & 31;
    const int bh = blockIdx.x >> 5;
    const int y = tid >> 5, z = tid & 31;

    float acc[16];
    #pragma unroll
    for (int c = 0; c < 16; ++c) acc[c] = 0.f;

    const int* hb = hist + (long)bh * NG3;
    const int* ob = offs + (long)bh * NG3;

    #pragma unroll
    for (int dx = 0; dx < 2; ++dx) {
        int cx = rx - dx;
        if (cx < 0) continue;
        #pragma unroll
        for (int dy = 0; dy < 2; ++dy) {
            int cy = y - dy;
            if (cy < 0) continue;
            #pragma unroll
            for (int dz = 0; dz < 2; ++dz) {
                int cz = z - dz;
                if (cz < 0) continue;
                int cell = (cx << 10) | (cy << 5) | cz;
                int s = ob[cell];
                int cnt = hb[cell];
                for (int r = 0; r < cnt; ++r) {
                    const float4* R = binned5 + (long)(s + r) * 5;
                    float4 f = R[0];
                    float wx = dx ? f.x : 1.f - f.x;
                    float wy = dy ? f.y : 1.f - f.y;
                    float wz = dz ? f.z : 1.f - f.z;
                    float w = wx * wy * wz;
                    float4 a = R[1], b4 = R[2], c4 = R[3], d4 = R[4];
                    acc[0]  = fmaf(w, a.x,  acc[0]);
                    acc[1]  = fmaf(w, a.y,  acc[1]);
                    acc[2]  = fmaf(w, a.z,  acc[2]);
                    acc[3]  = fmaf(w, a.w,  acc[3]);
                    acc[4]  = fmaf(w, b4.x, acc[4]);
                    acc[5]  = fmaf(w, b4.y, acc[5]);
                    acc[6]  = fmaf(w, b4.z, acc[6]);
                    acc[7]  = fmaf(w, b4.w, acc[7]);
                    acc[8]  = fmaf(w, c4.x, acc[8]);
                    acc[9]  = fmaf(w, c4.y, acc[9]);
                    acc[10] = fmaf(w, c4.z, acc[10]);
                    acc[11] = fmaf(w, c4.w, acc[11]);
                    acc[12] = fmaf(w, d4.x, acc[12]);
                    acc[13] = fmaf(w, d4.y, acc[13]);
                    acc[14] = fmaf(w, d4.z, acc[14]);
                    acc[15] = fmaf(w, d4.w, acc[15]);
                }
            }
        }
    }

    float4* gb = (float4*)(grid + ((long)bh * NG3 + (rx << 10) + tid) * NC);
    gb[0] = make_float4(acc[0],  acc[1],  acc[2],  acc[3]);
    gb[1] = make_float4(acc[4],  acc[5],  acc[6],  acc[7]);
    gb[2] = make_float4(acc[8],  acc[9],  acc[10], acc[11]);
    gb[3] = make_float4(acc[12], acc[13], acc[14], acc[15]);
}

// ---------------------------------------------------------------------------
// Kernel 3: grouped 3x3x3 conv, SAME padding, direct fp32 with LDS tiles
// ---------------------------------------------------------------------------
__global__ __launch_bounds__(256)
void k_conv(const float* __restrict__ grid, const float* __restrict__ cw,
            const float* __restrict__ cb, float* __restrict__ convo)
{
    __shared__ float it[16 * 6 * 6 * 10];   // [ic][xx][yy][zz]
    __shared__ float wt[432 * 16];          // [r][oc]
    const int tid = threadIdx.x;
    const int bid = blockIdx.x;
    const int zb = bid & 3, yb = (bid >> 2) & 7, xb = (bid >> 5) & 7;
    const int bh = bid >> 8;
    const int h = bh & 7;

    for (int e = tid; e < 6912; e += 256) {
        int oc = e / 432, r = e % 432;
        wt[r * 16 + oc] = cw[(h * 16 + oc) * 432 + r];
    }
    const float* gbase = grid + (long)bh * NG3 * NC;
    for (int e = tid; e < 5760; e += 256) {
        int ic = e & 15, cell = e >> 4;
        int zz = cell % 10, yy = (cell / 10) % 6, xx = cell / 60;
        int gx = xb * 4 + xx - 1, gy = yb * 4 + yy - 1, gz = zb * 8 + zz - 1;
        float v = 0.f;
        if ((unsigned)gx < NG && (unsigned)gy < NG && (unsigned)gz < NG)
            v = gbase[(((long)gx * NG + gy) * NG + gz) * NC + ic];
        it[ic * 360 + xx * 60 + yy * 10 + zz] = v;
    }
    __syncthreads();

    const int oc = tid & 15, txty = tid >> 4;
    const int tx = txty & 3, ty = txty >> 2;
    float acc[8];
    #pragma unroll
    for (int z = 0; z < 8; ++z) acc[z] = 0.f;

    #pragma unroll 1
    for (int ic = 0; ic < 16; ++ic) {
        #pragma unroll
        for (int kx = 0; kx < 3; ++kx) {
            #pragma unroll
            for (int ky = 0; ky < 3; ++ky) {
                const float* ib = &it[ic * 360 + (tx + kx) * 60 + (ty + ky) * 10];
                const float* wp = &wt[(ic * 27 + kx * 9 + ky * 3) * 16 + oc];
                float w0 = wp[0], w1 = wp[16], w2 = wp[32];
                #pragma unroll
                for (int z = 0; z < 8; ++z)
                    acc[z] = fmaf(ib[z], w0, fmaf(ib[z + 1], w1, fmaf(ib[z + 2], w2, acc[z])));
            }
        }
    }
    float bias = cb[h * 16 + oc];
    int gx = xb * 4 + tx, gy = yb * 4 + ty;
    float* ob = convo + (long)bh * NG3 * NC + (((long)gx * NG + gy) * NG + zb * 8) * NC + oc;
    #pragma unroll
    for (int z = 0; z < 8; ++z) ob[z * NC] = acc[z] + bias;
}

// ---------------------------------------------------------------------------
// Kernel 4: slice (weighted gather) + BN + ReLU, output f32 [B, H*C, N]
// ---------------------------------------------------------------------------
__global__ __launch_bounds__(256)
void k_slice(const float* __restrict__ convo, const float4* __restrict__ pre,
             const float* __restrict__ ag, const float* __restrict__ ab,
             const float* __restrict__ am, const float* __restrict__ av,
             float* __restrict__ out)
{
    __shared__ float asc[128], ash[128];
    const int tid = threadIdx.x;
    if (tid < 128) {
        float s = rsqrtf(av[tid] + KEPS) * ag[tid];
        asc[tid] = s;
        ash[tid] = ab[tid] - am[tid] * s;
    }
    __syncthreads();

    long t = (long)blockIdx.x * 256 + tid;
    long bh = t / NN;
    int n = (int)(t % NN);
    int b = (int)(bh >> 3), h = (int)(bh & 7);
    const float* g = convo + bh * (long)NG3 * NC;

    float4 r = pre[t];
    int ibase = __float_as_int(r.x);
    float fx = r.y, fy = r.z, fz = r.w;
    float gx = 1.f - fx, gy = 1.f - fy, gz = 1.f - fz;
    const float ws8[8] = {gx*gy*gz, gx*gy*fz, gx*fy*gz, gx*fy*fz,
                          fx*gy*gz, fx*gy*fz, fx*fy*gz, fx*fy*fz};
    const int offs8[8] = {0, 1, NG, NG + 1, NG*NG, NG*NG + 1, NG*NG + NG, NG*NG + NG + 1};

    float acc[NC];
    #pragma unroll
    for (int c = 0; c < NC; ++c) acc[c] = 0.f;
    #pragma unroll
    for (int ci = 0; ci < 8; ++ci) {
        float w = ws8[ci];
        const float* gc = g + (long)(ibase + offs8[ci]) * NC;
        #pragma unroll
        for (int c = 0; c < NC; ++c) acc[c] = fmaf(gc[c], w, acc[c]);
    }
    float* ob = out + ((long)b * 128 + h * 16) * NN + n;
    #pragma unroll
    for (int c = 0; c < NC; ++c) {
        float rr = fmaf(acc[c], asc[h * 16 + c], ash[h * 16 + c]);
        ob[(long)c * NN] = fmaxf(rr, 0.f);
    }
}

// ---------------------------------------------------------------------------
extern "C" void kernel_launch(void* const* d_in, const int* in_sizes, int n_in,
                              void* d_out, int out_size, void* d_ws, size_t ws_size,
                              hipStream_t stream)
{
    (void)in_sizes; (void)n_in; (void)out_size; (void)ws_size;
    const float* x    = (const float*)d_in[0];
    const float* orig = (const float*)d_in[1];
    const float* wkv  = (const float*)d_in[2];
    const float* kg   = (const float*)d_in[3];
    const float* kb   = (const float*)d_in[4];
    const float* km   = (const float*)d_in[5];
    const float* kvv  = (const float*)d_in[6];
    const float* vg   = (const float*)d_in[7];
    const float* vb   = (const float*)d_in[8];
    const float* vm   = (const float*)d_in[9];
    const float* vv   = (const float*)d_in[10];
    const float* Wt   = (const float*)d_in[11];
    const float* bt   = (const float*)d_in[12];
    const float* cw   = (const float*)d_in[13];
    const float* cb   = (const float*)d_in[14];
    const float* ag   = (const float*)d_in[15];
    const float* ab   = (const float*)d_in[16];
    const float* am   = (const float*)d_in[17];
    const float* av   = (const float*)d_in[18];

    char* ws = (char*)d_ws;
    // Layout (bytes). convo aliases values+binned (both dead by k_conv).
    float4* pre       = (float4*)(ws);                  //  8,388,608
    int*    hist      = (int*)   (ws + 8388608);        //  4,194,304
    int*    offs      = (int*)   (ws + 12582912);       //  4,194,304
    int*    offs_live = (int*)   (ws + 16777216);       //  4,194,304
    float*  values    = (float*) (ws + 20971520);       // 33,554,432
    float4* binned5   = (float4*)(ws + 54525952);       // 41,943,040 -> end 96,468,992
    float*  grid      = (float*) (ws + 96468992);       // 67,108,864 -> end 163,577,856
    float*  convo     = (float*) (ws + 20971520);       // 67,108,864 (alias, end 88,080,384)

    hipMemsetAsync(hist, 0, (size_t)NB * NH * NG3 * sizeof(int), stream);

    k_front<<<dim3((NB * NN) / 128), dim3(128), 0, stream>>>(
        x, orig, wkv, kg, kb, km, kvv, vg, vb, vm, vv, Wt, bt, values, pre, hist);

    k_scan_cells<<<dim3(NB * NH), dim3(1024), 0, stream>>>(hist, offs, offs_live);

    k_scatter<<<dim3((NB * NH * NN) / 256), dim3(256), 0, stream>>>(
        pre, values, offs_live, binned5);

    k_splat4<<<dim3(NB * NH * NG), dim3(1024), 0, stream>>>(binned5, hist, offs, grid);

    k_conv<<<dim3(NB * NH * 256), dim3(256), 0, stream>>>(grid, cw, cb, convo);

    k_slice<<<dim3((NB * NH * NN) / 256), dim3(256), 0, stream>>>(
        convo, pre, ag, ab, am, av, (float*)d_out);
}

// Round 8
// 360.807 us; speedup vs baseline: 3.5010x; 1.8200x over previous
//
#include <hip/hip_runtime.h>
#include <hip/hip_bf16.h>

#define NB  4
#define NH  8
#define NC  16
#define ND  64
#define NN  16384
#define NG  32
#define NG3 32768
#define NKV 152
#define KEPS 1e-5f

typedef __attribute__((ext_vector_type(8))) short bf16x8;
typedef __attribute__((ext_vector_type(4))) float f32x4;

__device__ __forceinline__ unsigned pack_bf2(float lo, float hi) {
    __hip_bfloat16 a = __float2bfloat16(lo);
    __hip_bfloat16 b = __float2bfloat16(hi);
    return (unsigned)(*(unsigned short*)&a) | ((unsigned)(*(unsigned short*)&b) << 16);
}

// ---------------------------------------------------------------------------
// Kernel 1: fused kv-GEMM + BN + key transform + tanh + lattice coords.
// ---------------------------------------------------------------------------
__global__ __launch_bounds__(128)
void k_front(const float* __restrict__ x,      // [B,D,N]
             const float* __restrict__ orig,   // [B,3,N]
             const float* __restrict__ wkv,    // [152,64]
             const float* __restrict__ kg, const float* __restrict__ kb,
             const float* __restrict__ km, const float* __restrict__ kvv,
             const float* __restrict__ vg, const float* __restrict__ vb,
             const float* __restrict__ vm, const float* __restrict__ vv,
             const float* __restrict__ Wt,     // [8,3,3]
             const float* __restrict__ bt,     // [8,3]
             float* __restrict__ values,       // [B,H,N,C]
             float4* __restrict__ pre,         // [B,H,N]
             int* __restrict__ hist)           // [B*H*32768]
{
    __shared__ float wl[NKV * ND];
    __shared__ float ksc[24], ksh[24], vsc[128], vsh[128], wts[72], bts[24];
    const int tid = threadIdx.x;

    for (int i = tid; i < NKV * ND; i += 128) wl[i] = wkv[i];
    if (tid < 24) {
        float s = rsqrtf(kvv[tid] + KEPS) * kg[tid];
        ksc[tid] = s;
        ksh[tid] = kb[tid] - km[tid] * s;
    }
    if (tid < 128) {
        float s = rsqrtf(vv[tid] + KEPS) * vg[tid];
        vsc[tid] = s;
        vsh[tid] = vb[tid] - vm[tid] * s;
    }
    if (tid < 72) wts[tid] = Wt[tid];
    if (tid < 24) bts[tid] = bt[tid];
    __syncthreads();

    const int bpb = NN / 128;
    const int b = blockIdx.x / bpb;
    const int n = (blockIdx.x % bpb) * 128 + tid;

    float xr[ND];
    #pragma unroll
    for (int d = 0; d < ND; ++d)
        xr[d] = x[((long)b * ND + d) * NN + n];

    float ko[24];
    #pragma unroll 1
    for (int o = 0; o < 24; o += 4) {
        float s0 = 0.f, s1 = 0.f, s2 = 0.f, s3 = 0.f;
        #pragma unroll
        for (int d = 0; d < ND; ++d) {
            float xv = xr[d];
            s0 = fmaf(wl[(o + 0) * ND + d], xv, s0);
            s1 = fmaf(wl[(o + 1) * ND + d], xv, s1);
            s2 = fmaf(wl[(o + 2) * ND + d], xv, s2);
            s3 = fmaf(wl[(o + 3) * ND + d], xv, s3);
        }
        ko[o + 0] = fmaf(s0, ksc[o + 0], ksh[o + 0]);
        ko[o + 1] = fmaf(s1, ksc[o + 1], ksh[o + 1]);
        ko[o + 2] = fmaf(s2, ksc[o + 2], ksh[o + 2]);
        ko[o + 3] = fmaf(s3, ksc[o + 3], ksh[o + 3]);
    }

    #pragma unroll 1
    for (int oc = 0; oc < 128; oc += 4) {
        float s0 = 0.f, s1 = 0.f, s2 = 0.f, s3 = 0.f;
        #pragma unroll
        for (int d = 0; d < ND; ++d) {
            float xv = xr[d];
            s0 = fmaf(wl[(24 + oc + 0) * ND + d], xv, s0);
            s1 = fmaf(wl[(24 + oc + 1) * ND + d], xv, s1);
            s2 = fmaf(wl[(24 + oc + 2) * ND + d], xv, s2);
            s3 = fmaf(wl[(24 + oc + 3) * ND + d], xv, s3);
        }
        int h = oc >> 4, c = oc & 15;
        float* vp = values + (((long)(b * NH + h) * NN + n) * NC + c);
        vp[0] = fmaf(s0, vsc[oc + 0], vsh[oc + 0]);
        vp[1] = fmaf(s1, vsc[oc + 1], vsh[oc + 1]);
        vp[2] = fmaf(s2, vsc[oc + 2], vsh[oc + 2]);
        vp[3] = fmaf(s3, vsc[oc + 3], vsh[oc + 3]);
    }

    const float o0 = orig[((long)b * 3 + 0) * NN + n];
    const float o1 = orig[((long)b * 3 + 1) * NN + n];
    const float o2 = orig[((long)b * 3 + 2) * NN + n];

    #pragma unroll 1
    for (int h = 0; h < NH; ++h) {
        float p0 = o0 + ko[h * 3 + 0];
        float p1 = o1 + ko[h * 3 + 1];
        float p2 = o2 + ko[h * 3 + 2];
        float t0 = fmaf(wts[h * 9 + 0], p0, fmaf(wts[h * 9 + 1], p1, fmaf(wts[h * 9 + 2], p2, bts[h * 3 + 0])));
        float t1 = fmaf(wts[h * 9 + 3], p0, fmaf(wts[h * 9 + 4], p1, fmaf(wts[h * 9 + 5], p2, bts[h * 3 + 1])));
        float t2 = fmaf(wts[h * 9 + 6], p0, fmaf(wts[h * 9 + 7], p1, fmaf(wts[h * 9 + 8], p2, bts[h * 3 + 2])));
        float l0 = tanhf(t0), l1 = tanhf(t1), l2 = tanhf(t2);
        float pos0 = (l0 + 1.f) * 15.5f;
        float pos1 = (l1 + 1.f) * 15.5f;
        float pos2 = (l2 + 1.f) * 15.5f;
        float b0 = fminf(fmaxf(floorf(pos0), 0.f), 30.f);
        float b1 = fminf(fmaxf(floorf(pos1), 0.f), 30.f);
        float b2 = fminf(fmaxf(floorf(pos2), 0.f), 30.f);
        int ix = (int)b0, iy = (int)b1, iz = (int)b2;
        float fx = pos0 - b0, fy = pos1 - b1, fz = pos2 - b2;
        int ibase = (ix * NG + iy) * NG + iz;
        float4 pr;
        pr.x = __int_as_float(ibase);
        pr.y = fx; pr.z = fy; pr.w = fz;
        int bh = b * NH + h;
        pre[(long)bh * NN + n] = pr;
        atomicAdd(&hist[bh * NG3 + ibase], 1);
    }
}

// ---------------------------------------------------------------------------
// Kernel 1b: per-bh exclusive prefix scan over 32768 cell counts.
// ---------------------------------------------------------------------------
__global__ __launch_bounds__(1024)
void k_scan_cells(const int* __restrict__ hist, int* __restrict__ offs,
                  int* __restrict__ offs_live)
{
    __shared__ int tsum[1024];
    const int bh = blockIdx.x, tid = threadIdx.x;
    const int* hb = hist + (long)bh * NG3;

    int s = 0;
    #pragma unroll 4
    for (int j = 0; j < 32; ++j) s += hb[tid * 32 + j];
    tsum[tid] = s;
    __syncthreads();
    for (int d = 1; d < 1024; d <<= 1) {
        int t = (tid >= d) ? tsum[tid - d] : 0;
        __syncthreads();
        tsum[tid] += t;
        __syncthreads();
    }
    int run = bh * NN + tsum[tid] - s;
    int* ob = offs + (long)bh * NG3;
    int* lb = offs_live + (long)bh * NG3;
    #pragma unroll 4
    for (int j = 0; j < 32; ++j) {
        int c = tid * 32 + j;
        ob[c] = run;
        lb[c] = run;
        run += hb[c];
    }
}

// ---------------------------------------------------------------------------
// Kernel 1c: scatter records into cell order (80 B records, values embedded).
// ---------------------------------------------------------------------------
__global__ __launch_bounds__(256)
void k_scatter(const float4* __restrict__ pre, const float* __restrict__ values,
               int* __restrict__ offs_live, float4* __restrict__ binned5)
{
    long t = (long)blockIdx.x * 256 + threadIdx.x;
    float4 r = pre[t];
    int ibase = __float_as_int(r.x);
    int bh = (int)(t >> 14);
    int slot = atomicAdd(&offs_live[(long)bh * NG3 + ibase], 1);
    const float4* vp = (const float4*)(values + t * NC);
    float4 v0 = vp[0], v1 = vp[1], v2 = vp[2], v3 = vp[3];
    float4* out = binned5 + (long)slot * 5;
    out[0] = make_float4(r.y, r.z, r.w, 0.f);
    out[1] = v0; out[2] = v1; out[3] = v2; out[4] = v3;
}

// ---------------------------------------------------------------------------
// Kernel 2: splat — atomic-free, VGPR accumulators. Output grid in BF16.
// ---------------------------------------------------------------------------
__global__ __launch_bounds__(1024)
void k_splat4(const float4* __restrict__ binned5, const int* __restrict__ hist,
              const int* __restrict__ offs, unsigned short* __restrict__ gridb)
{
    const int tid = threadIdx.x;
    const int rx = blockIdx.x & 31;
    const int bh = blockIdx.x >> 5;
    const int y = tid >> 5, z = tid & 31;

    float acc[16];
    #pragma unroll
    for (int c = 0; c < 16; ++c) acc[c] = 0.f;

    const int* hb = hist + (long)bh * NG3;
    const int* ob = offs + (long)bh * NG3;

    #pragma unroll
    for (int dx = 0; dx < 2; ++dx) {
        int cx = rx - dx;
        if (cx < 0) continue;
        #pragma unroll
        for (int dy = 0; dy < 2; ++dy) {
            int cy = y - dy;
            if (cy < 0) continue;
            #pragma unroll
            for (int dz = 0; dz < 2; ++dz) {
                int cz = z - dz;
                if (cz < 0) continue;
                int cell = (cx << 10) | (cy << 5) | cz;
                int s = ob[cell];
                int cnt = hb[cell];
                for (int r = 0; r < cnt; ++r) {
                    const float4* R = binned5 + (long)(s + r) * 5;
                    float4 f = R[0];
                    float wx = dx ? f.x : 1.f - f.x;
                    float wy = dy ? f.y : 1.f - f.y;
                    float wz = dz ? f.z : 1.f - f.z;
                    float w = wx * wy * wz;
                    float4 a = R[1], b4 = R[2], c4 = R[3], d4 = R[4];
                    acc[0]  = fmaf(w, a.x,  acc[0]);
                    acc[1]  = fmaf(w, a.y,  acc[1]);
                    acc[2]  = fmaf(w, a.z,  acc[2]);
                    acc[3]  = fmaf(w, a.w,  acc[3]);
                    acc[4]  = fmaf(w, b4.x, acc[4]);
                    acc[5]  = fmaf(w, b4.y, acc[5]);
                    acc[6]  = fmaf(w, b4.z, acc[6]);
                    acc[7]  = fmaf(w, b4.w, acc[7]);
                    acc[8]  = fmaf(w, c4.x, acc[8]);
                    acc[9]  = fmaf(w, c4.y, acc[9]);
                    acc[10] = fmaf(w, c4.z, acc[10]);
                    acc[11] = fmaf(w, c4.w, acc[11]);
                    acc[12] = fmaf(w, d4.x, acc[12]);
                    acc[13] = fmaf(w, d4.y, acc[13]);
                    acc[14] = fmaf(w, d4.z, acc[14]);
                    acc[15] = fmaf(w, d4.w, acc[15]);
                }
            }
        }
    }

    uint4 q0, q1;
    q0.x = pack_bf2(acc[0],  acc[1]);  q0.y = pack_bf2(acc[2],  acc[3]);
    q0.z = pack_bf2(acc[4],  acc[5]);  q0.w = pack_bf2(acc[6],  acc[7]);
    q1.x = pack_bf2(acc[8],  acc[9]);  q1.y = pack_bf2(acc[10], acc[11]);
    q1.z = pack_bf2(acc[12], acc[13]); q1.w = pack_bf2(acc[14], acc[15]);
    uint4* gb = (uint4*)(gridb + ((long)bh * NG3 + (rx << 10) + tid) * NC);
    gb[0] = q0;
    gb[1] = q1;
}

// ---------------------------------------------------------------------------
// Kernel 3: grouped 3x3x3 conv via BF16 MFMA (implicit im2col).
// Block = (bh, 4x4 xy-tile, full z). 256 thr = 4 waves; wave = one x-slice.
// LDS: grid tile [ichalf][6][6][34][8ic] bf16 + weights [28tap][16oc][2][8ic].
// K=32 step = 2 taps x 16 ic; 14 MFMA per 16-cell M-tile; tap 27 zero-padded.
// ---------------------------------------------------------------------------
__global__ __launch_bounds__(256)
void k_conv2(const unsigned short* __restrict__ gridb,   // [bh][cell][16] bf16
             const float* __restrict__ cw, const float* __restrict__ cb,
             float* __restrict__ convo)
{
    __shared__ unsigned short sg[2 * 6 * 6 * 34 * 8];   // 39168 B
    __shared__ unsigned short sw[28 * 16 * 2 * 8];      // 14336 B
    const int tid = threadIdx.x;
    const int bid = blockIdx.x;
    const int xt = bid & 7, yt = (bid >> 3) & 7, bh = bid >> 6;
    const int h = bh & 7;
    const int x0 = xt * 4, y0 = yt * 4;

    // weights: cw[(h*16+oc)*432 + ic*27 + tap] -> sw[tap][oc][ic>>3][ic&7]
    for (int e = tid; e < 16 * 432; e += 256) {
        int oc = e / 432, r = e % 432;
        int ic = r / 27, tap = r % 27;
        __hip_bfloat16 hbw = __float2bfloat16(cw[(h * 16 + oc) * 432 + r]);
        sw[((tap * 16 + oc) * 2 + (ic >> 3)) * 8 + (ic & 7)] = *(unsigned short*)&hbw;
    }
    {   // zero-pad tap 27
        int oc = tid >> 4, ic = tid & 15;
        sw[((27 * 16 + oc) * 2 + (ic >> 3)) * 8 + (ic & 7)] = 0;
    }
    // grid tile with halo, 16 B chunks
    const unsigned short* gb = gridb + (long)bh * NG3 * 16;
    for (int e = tid; e < 6 * 6 * 34 * 2; e += 256) {
        int ihh = e & 1;
        int cellu = e >> 1;                       // xx*204 + yy*34 + zz
        int zz = cellu % 34;
        int yu = cellu / 34;
        int yy = yu % 6, xx = yu / 6;
        int gx = x0 + xx - 1, gy = y0 + yy - 1, gz = zz - 1;
        uint4 v = make_uint4(0, 0, 0, 0);
        if ((unsigned)gx < NG && (unsigned)gy < NG && (unsigned)gz < NG)
            v = *(const uint4*)(gb + (((gx * NG + gy) * NG + gz) * 16 + ihh * 8));
        *(uint4*)(sg + ((long)ihh * 6 * 6 * 34 + cellu) * 8) = v;
    }
    __syncthreads();

    const int lane = tid & 63;
    const int wv = tid >> 6;          // wave id = x-slice 0..3
    const int m  = lane & 15;         // z within 16-cell tile
    const int ihl = (lane >> 4) & 1;  // ic half
    const int tp = lane >> 5;         // tap within pair

    f32x4 acc[8];
    #pragma unroll
    for (int j = 0; j < 8; ++j) acc[j] = (f32x4){0.f, 0.f, 0.f, 0.f};

    #pragma unroll 1
    for (int p = 0; p < 14; ++p) {
        int tap = 2 * p + tp;
        bf16x8 bfr = *(const bf16x8*)(sw + ((tap * 16 + (lane & 15)) * 2 + ihl) * 8);
        int tap_a = tap > 26 ? 26 : tap;
        int kx = tap_a / 9, r9 = tap_a % 9;
        int ky = r9 / 3, kz = r9 % 3;
        int xx = wv + kx;
        #pragma unroll
        for (int j = 0; j < 8; ++j) {
            int yl = j >> 1, zh = j & 1;
            int yy = yl + ky;
            int zz = zh * 16 + m + kz;
            bf16x8 afr = *(const bf16x8*)(sg + ((long)ihl * 6 * 6 * 34 + ((xx * 6 + yy) * 34 + zz)) * 8);
            acc[j] = __builtin_amdgcn_mfma_f32_16x16x32_bf16(afr, bfr, acc[j], 0, 0, 0);
        }
    }

    const float bias = cb[h * 16 + (lane & 15)];
    float* cvb = convo + (long)bh * NG3 * NC;
    const int gx = x0 + wv;
    const int rowg = (lane >> 4) * 4;
    #pragma unroll
    for (int j = 0; j < 8; ++j) {
        int yl = j >> 1, zh = j & 1;
        int gy = y0 + yl;
        long cellbase = (long)(gx * NG + gy) * NG + zh * 16;
        #pragma unroll
        for (int r = 0; r < 4; ++r) {
            cvb[(cellbase + rowg + r) * NC + (lane & 15)] = acc[j][r] + bias;
        }
    }
}

// ---------------------------------------------------------------------------
// Kernel 4: slice (weighted gather) + BN + ReLU, output f32 [B, H*C, N]
// ---------------------------------------------------------------------------
__global__ __launch_bounds__(256)
void k_slice(const float* __restrict__ convo, const float4* __restrict__ pre,
             const float* __restrict__ ag, const float* __restrict__ ab,
             const float* __restrict__ am, const float* __restrict__ av,
             float* __restrict__ out)
{
    __shared__ float asc[128], ash[128];
    const int tid = threadIdx.x;
    if (tid < 128) {
        float s = rsqrtf(av[tid] + KEPS) * ag[tid];
        asc[tid] = s;
        ash[tid] = ab[tid] - am[tid] * s;
    }
    __syncthreads();

    long t = (long)blockIdx.x * 256 + tid;
    long bh = t / NN;
    int n = (int)(t % NN);
    int b = (int)(bh >> 3), h = (int)(bh & 7);
    const float* g = convo + bh * (long)NG3 * NC;

    float4 r = pre[t];
    int ibase = __float_as_int(r.x);
    float fx = r.y, fy = r.z, fz = r.w;
    float gx = 1.f - fx, gy = 1.f - fy, gz = 1.f - fz;
    const float ws8[8] = {gx*gy*gz, gx*gy*fz, gx*fy*gz, gx*fy*fz,
                          fx*gy*gz, fx*gy*fz, fx*fy*gz, fx*fy*fz};
    const int offs8[8] = {0, 1, NG, NG + 1, NG*NG, NG*NG + 1, NG*NG + NG, NG*NG + NG + 1};

    float acc[NC];
    #pragma unroll
    for (int c = 0; c < NC; ++c) acc[c] = 0.f;
    #pragma unroll
    for (int ci = 0; ci < 8; ++ci) {
        float w = ws8[ci];
        const float* gc = g + (long)(ibase + offs8[ci]) * NC;
        #pragma unroll
        for (int c = 0; c < NC; ++c) acc[c] = fmaf(gc[c], w, acc[c]);
    }
    float* ob = out + ((long)b * 128 + h * 16) * NN + n;
    #pragma unroll
    for (int c = 0; c < NC; ++c) {
        float rr = fmaf(acc[c], asc[h * 16 + c], ash[h * 16 + c]);
        ob[(long)c * NN] = fmaxf(rr, 0.f);
    }
}

// ---------------------------------------------------------------------------
extern "C" void kernel_launch(void* const* d_in, const int* in_sizes, int n_in,
                              void* d_out, int out_size, void* d_ws, size_t ws_size,
                              hipStream_t stream)
{
    (void)in_sizes; (void)n_in; (void)out_size; (void)ws_size;
    const float* x    = (const float*)d_in[0];
    const float* orig = (const float*)d_in[1];
    const float* wkv  = (const float*)d_in[2];
    const float* kg   = (const float*)d_in[3];
    const float* kb   = (const float*)d_in[4];
    const float* km   = (const float*)d_in[5];
    const float* kvv  = (const float*)d_in[6];
    const float* vg   = (const float*)d_in[7];
    const float* vb   = (const float*)d_in[8];
    const float* vm   = (const float*)d_in[9];
    const float* vv   = (const float*)d_in[10];
    const float* Wt   = (const float*)d_in[11];
    const float* bt   = (const float*)d_in[12];
    const float* cw   = (const float*)d_in[13];
    const float* cb   = (const float*)d_in[14];
    const float* ag   = (const float*)d_in[15];
    const float* ab   = (const float*)d_in[16];
    const float* am   = (const float*)d_in[17];
    const float* av   = (const float*)d_in[18];

    char* ws = (char*)d_ws;
    // Layout (bytes). convo aliases values+binned5 (dead by k_conv2 time).
    float4*         pre       = (float4*)        (ws);                 //  8,388,608
    int*            hist      = (int*)           (ws + 8388608);       //  4,194,304
    int*            offs      = (int*)           (ws + 12582912);      //  4,194,304
    int*            offs_live = (int*)           (ws + 16777216);      //  4,194,304
    float*          values    = (float*)         (ws + 20971520);      // 33,554,432
    float4*         binned5   = (float4*)        (ws + 54525952);      // 41,943,040
    unsigned short* gridb     = (unsigned short*)(ws + 96468992);      // 33,554,432 -> end 130,023,424
    float*          convo     = (float*)         (ws + 20971520);      // 67,108,864 (alias)

    hipMemsetAsync(hist, 0, (size_t)NB * NH * NG3 * sizeof(int), stream);

    k_front<<<dim3((NB * NN) / 128), dim3(128), 0, stream>>>(
        x, orig, wkv, kg, kb, km, kvv, vg, vb, vm, vv, Wt, bt, values, pre, hist);

    k_scan_cells<<<dim3(NB * NH), dim3(1024), 0, stream>>>(hist, offs, offs_live);

    k_scatter<<<dim3((NB * NH * NN) / 256), dim3(256), 0, stream>>>(
        pre, values, offs_live, binned5);

    k_splat4<<<dim3(NB * NH * NG), dim3(1024), 0, stream>>>(binned5, hist, offs, gridb);

    k_conv2<<<dim3(NB * NH * 64), dim3(256), 0, stream>>>(gridb, cw, cb, convo);

    k_slice<<<dim3((NB * NH * NN) / 256), dim3(256), 0, stream>>>(
        convo, pre, ag, ab, am, av, (float*)d_out);
}

// Round 9
// 273.516 us; speedup vs baseline: 4.6183x; 1.3191x over previous
//
#include <hip/hip_runtime.h>
#include <hip/hip_bf16.h>

#define NB  4
#define NH  8
#define NC  16
#define ND  64
#define NN  16384
#define NG  32
#define NG3 32768
#define NKV 152
#define KEPS 1e-5f
#define TN  256   // points per k_front2 block

typedef __attribute__((ext_vector_type(8))) short bf16x8;
typedef __attribute__((ext_vector_type(4))) float f32x4;

__device__ __forceinline__ unsigned pack_bf2(float lo, float hi) {
    __hip_bfloat16 a = __float2bfloat16(lo);
    __hip_bfloat16 b = __float2bfloat16(hi);
    return (unsigned)(*(unsigned short*)&a) | ((unsigned)(*(unsigned short*)&b) << 16);
}
__device__ __forceinline__ float bf_lo(unsigned u) { return __uint_as_float(u << 16); }
__device__ __forceinline__ float bf_hi(unsigned u) { return __uint_as_float(u & 0xffff0000u); }

// ---------------------------------------------------------------------------
// Kernel 1: front — keys in fp32 VALU, values via bf16 MFMA (128x64 @ 64x256
// per block). Emits values [B,H,N,C] f32, pre {ibase,fx,fy,fz}, cell hist.
// ---------------------------------------------------------------------------
__global__ __launch_bounds__(256)
void k_front2(const float* __restrict__ x,      // [B,D,N]
              const float* __restrict__ orig,   // [B,3,N]
              const float* __restrict__ wkv,    // [152,64]
              const float* __restrict__ kg, const float* __restrict__ kb,
              const float* __restrict__ km, const float* __restrict__ kvv,
              const float* __restrict__ vg, const float* __restrict__ vb,
              const float* __restrict__ vm, const float* __restrict__ vv,
              const float* __restrict__ Wt,     // [8,3,3]
              const float* __restrict__ bt,     // [8,3]
              float* __restrict__ values,       // [B,H,N,C]
              float4* __restrict__ pre,         // [B,H,N]
              int* __restrict__ hist)           // [B*H*32768]
{
    __shared__ unsigned short xb[TN * 72];      // bf16 x tile [n][d], pitch 72 (144 B)
    __shared__ float wk[24 * ND];               // key rows f32
    __shared__ float ksc[24], ksh[24], vsc[128], vsh[128], wts[72], bts[24];
    const int tid = threadIdx.x;
    const int b  = blockIdx.x >> 6;             // 64 blocks per batch
    const int n0 = (blockIdx.x & 63) * TN;
    const int n  = n0 + tid;

    for (int i = tid; i < 24 * ND; i += 256) wk[i] = wkv[i];
    if (tid < 24) {
        float s = rsqrtf(kvv[tid] + KEPS) * kg[tid];
        ksc[tid] = s;
        ksh[tid] = kb[tid] - km[tid] * s;
    }
    if (tid < 128) {
        float s = rsqrtf(vv[tid] + KEPS) * vg[tid];
        vsc[tid] = s;
        vsh[tid] = vb[tid] - vm[tid] * s;
    }
    if (tid < 72) wts[tid] = Wt[tid];
    if (tid < 24) bts[tid] = bt[tid];

    // ---- load this thread's point (all 64 d), stage bf16 row into LDS ----
    float xr[ND];
    #pragma unroll
    for (int d = 0; d < ND; ++d)
        xr[d] = x[((long)b * ND + d) * NN + n];
    #pragma unroll
    for (int j = 0; j < 8; ++j) {
        uint4 q;
        q.x = pack_bf2(xr[8*j+0], xr[8*j+1]);
        q.y = pack_bf2(xr[8*j+2], xr[8*j+3]);
        q.z = pack_bf2(xr[8*j+4], xr[8*j+5]);
        q.w = pack_bf2(xr[8*j+6], xr[8*j+7]);
        *(uint4*)(xb + tid * 72 + j * 8) = q;
    }
    __syncthreads();

    // ---- keys: 24 fp32 dots, broadcast float4 reads of wk ----
    float ko[24];
    #pragma unroll 1
    for (int o = 0; o < 24; o += 4) {
        float s0 = 0.f, s1 = 0.f, s2 = 0.f, s3 = 0.f;
        #pragma unroll
        for (int dq = 0; dq < 16; ++dq) {
            const float4 w0 = *(const float4*)&wk[(o + 0) * ND + dq * 4];
            const float4 w1 = *(const float4*)&wk[(o + 1) * ND + dq * 4];
            const float4 w2 = *(const float4*)&wk[(o + 2) * ND + dq * 4];
            const float4 w3 = *(const float4*)&wk[(o + 3) * ND + dq * 4];
            float a0 = xr[4*dq], a1 = xr[4*dq+1], a2 = xr[4*dq+2], a3 = xr[4*dq+3];
            s0 = fmaf(w0.x, a0, fmaf(w0.y, a1, fmaf(w0.z, a2, fmaf(w0.w, a3, s0))));
            s1 = fmaf(w1.x, a0, fmaf(w1.y, a1, fmaf(w1.z, a2, fmaf(w1.w, a3, s1))));
            s2 = fmaf(w2.x, a0, fmaf(w2.y, a1, fmaf(w2.z, a2, fmaf(w2.w, a3, s2))));
            s3 = fmaf(w3.x, a0, fmaf(w3.y, a1, fmaf(w3.z, a2, fmaf(w3.w, a3, s3))));
        }
        ko[o + 0] = fmaf(s0, ksc[o + 0], ksh[o + 0]);
        ko[o + 1] = fmaf(s1, ksc[o + 1], ksh[o + 1]);
        ko[o + 2] = fmaf(s2, ksc[o + 2], ksh[o + 2]);
        ko[o + 3] = fmaf(s3, ksc[o + 3], ksh[o + 3]);
    }

    // ---- values via MFMA: wave w handles heads 2w, 2w+1 ----
    {
        const int lane = tid & 63;
        const int wv = tid >> 6;
        const int l15 = lane & 15, l4 = lane >> 4;

        bf16x8 bfr[2][2];
        float bsc[2], bsh[2];
        #pragma unroll
        for (int p = 0; p < 2; ++p) {
            int oc = (2 * wv + p) * 16 + l15;
            bsc[p] = vsc[oc];
            bsh[p] = vsh[oc];
            #pragma unroll
            for (int ks = 0; ks < 2; ++ks) {
                const float* wp = wkv + (24 + oc) * ND + ks * 32 + l4 * 8;
                float4 a = *(const float4*)wp;
                float4 c = *(const float4*)(wp + 4);
                uint4 q;
                q.x = pack_bf2(a.x, a.y); q.y = pack_bf2(a.z, a.w);
                q.z = pack_bf2(c.x, c.y); q.w = pack_bf2(c.z, c.w);
                bfr[p][ks] = *(bf16x8*)&q;
            }
        }

        #pragma unroll 1
        for (int nb = 0; nb < 16; ++nb) {
            bf16x8 a0 = *(const bf16x8*)(xb + (nb * 16 + l15) * 72 + l4 * 8);
            bf16x8 a1 = *(const bf16x8*)(xb + (nb * 16 + l15) * 72 + 32 + l4 * 8);
            #pragma unroll
            for (int p = 0; p < 2; ++p) {
                f32x4 acc = (f32x4){0.f, 0.f, 0.f, 0.f};
                acc = __builtin_amdgcn_mfma_f32_16x16x32_bf16(a0, bfr[p][0], acc, 0, 0, 0);
                acc = __builtin_amdgcn_mfma_f32_16x16x32_bf16(a1, bfr[p][1], acc, 0, 0, 0);
                int h = 2 * wv + p;
                float* vp = values + (((long)(b * NH + h) * NN + n0 + nb * 16 + l4 * 4) * NC) + l15;
                #pragma unroll
                for (int r = 0; r < 4; ++r)
                    vp[r * NC] = fmaf(acc[r], bsc[p], bsh[p]);
            }
        }
    }

    // ---- lattice coords per head ----
    const float o0 = orig[((long)b * 3 + 0) * NN + n];
    const float o1 = orig[((long)b * 3 + 1) * NN + n];
    const float o2 = orig[((long)b * 3 + 2) * NN + n];

    #pragma unroll 1
    for (int h = 0; h < NH; ++h) {
        float p0 = o0 + ko[h * 3 + 0];
        float p1 = o1 + ko[h * 3 + 1];
        float p2 = o2 + ko[h * 3 + 2];
        float t0 = fmaf(wts[h * 9 + 0], p0, fmaf(wts[h * 9 + 1], p1, fmaf(wts[h * 9 + 2], p2, bts[h * 3 + 0])));
        float t1 = fmaf(wts[h * 9 + 3], p0, fmaf(wts[h * 9 + 4], p1, fmaf(wts[h * 9 + 5], p2, bts[h * 3 + 1])));
        float t2 = fmaf(wts[h * 9 + 6], p0, fmaf(wts[h * 9 + 7], p1, fmaf(wts[h * 9 + 8], p2, bts[h * 3 + 2])));
        float l0 = tanhf(t0), l1 = tanhf(t1), l2 = tanhf(t2);
        float pos0 = (l0 + 1.f) * 15.5f;
        float pos1 = (l1 + 1.f) * 15.5f;
        float pos2 = (l2 + 1.f) * 15.5f;
        float b0 = fminf(fmaxf(floorf(pos0), 0.f), 30.f);
        float b1 = fminf(fmaxf(floorf(pos1), 0.f), 30.f);
        float b2 = fminf(fmaxf(floorf(pos2), 0.f), 30.f);
        int ix = (int)b0, iy = (int)b1, iz = (int)b2;
        float fx = pos0 - b0, fy = pos1 - b1, fz = pos2 - b2;
        int ibase = (ix * NG + iy) * NG + iz;
        float4 pr;
        pr.x = __int_as_float(ibase);
        pr.y = fx; pr.z = fy; pr.w = fz;
        int bh = b * NH + h;
        pre[(long)bh * NN + n] = pr;
        atomicAdd(&hist[bh * NG3 + ibase], 1);
    }
}

// ---------------------------------------------------------------------------
// Kernel 1b: per-bh exclusive prefix scan over 32768 cell counts.
// ---------------------------------------------------------------------------
__global__ __launch_bounds__(1024)
void k_scan_cells(const int* __restrict__ hist, int* __restrict__ offs,
                  int* __restrict__ offs_live)
{
    __shared__ int tsum[1024];
    const int bh = blockIdx.x, tid = threadIdx.x;
    const int* hb = hist + (long)bh * NG3;

    int s = 0;
    #pragma unroll 4
    for (int j = 0; j < 32; ++j) s += hb[tid * 32 + j];
    tsum[tid] = s;
    __syncthreads();
    for (int d = 1; d < 1024; d <<= 1) {
        int t = (tid >= d) ? tsum[tid - d] : 0;
        __syncthreads();
        tsum[tid] += t;
        __syncthreads();
    }
    int run = bh * NN + tsum[tid] - s;
    int* ob = offs + (long)bh * NG3;
    int* lb = offs_live + (long)bh * NG3;
    #pragma unroll 4
    for (int j = 0; j < 32; ++j) {
        int c = tid * 32 + j;
        ob[c] = run;
        lb[c] = run;
        run += hb[c];
    }
}

// ---------------------------------------------------------------------------
// Kernel 1c: scatter records into cell order (80 B records, values embedded).
// ---------------------------------------------------------------------------
__global__ __launch_bounds__(256)
void k_scatter(const float4* __restrict__ pre, const float* __restrict__ values,
               int* __restrict__ offs_live, float4* __restrict__ binned5)
{
    long t = (long)blockIdx.x * 256 + threadIdx.x;
    float4 r = pre[t];
    int ibase = __float_as_int(r.x);
    int bh = (int)(t >> 14);
    int slot = atomicAdd(&offs_live[(long)bh * NG3 + ibase], 1);
    const float4* vp = (const float4*)(values + t * NC);
    float4 v0 = vp[0], v1 = vp[1], v2 = vp[2], v3 = vp[3];
    float4* out = binned5 + (long)slot * 5;
    out[0] = make_float4(r.y, r.z, r.w, 0.f);
    out[1] = v0; out[2] = v1; out[3] = v2; out[4] = v3;
}

// ---------------------------------------------------------------------------
// Kernel 2: splat — atomic-free, VGPR accumulators. Output grid in BF16.
// ---------------------------------------------------------------------------
__global__ __launch_bounds__(1024)
void k_splat4(const float4* __restrict__ binned5, const int* __restrict__ hist,
              const int* __restrict__ offs, unsigned short* __restrict__ gridb)
{
    const int tid = threadIdx.x;
    const int rx = blockIdx.x & 31;
    const int bh = blockIdx.x >> 5;
    const int y = tid >> 5, z = tid & 31;

    float acc[16];
    #pragma unroll
    for (int c = 0; c < 16; ++c) acc[c] = 0.f;

    const int* hb = hist + (long)bh * NG3;
    const int* ob = offs + (long)bh * NG3;

    #pragma unroll
    for (int dx = 0; dx < 2; ++dx) {
        int cx = rx - dx;
        if (cx < 0) continue;
        #pragma unroll
        for (int dy = 0; dy < 2; ++dy) {
            int cy = y - dy;
            if (cy < 0) continue;
            #pragma unroll
            for (int dz = 0; dz < 2; ++dz) {
                int cz = z - dz;
                if (cz < 0) continue;
                int cell = (cx << 10) | (cy << 5) | cz;
                int s = ob[cell];
                int cnt = hb[cell];
                for (int r = 0; r < cnt; ++r) {
                    const float4* R = binned5 + (long)(s + r) * 5;
                    float4 f = R[0];
                    float wx = dx ? f.x : 1.f - f.x;
                    float wy = dy ? f.y : 1.f - f.y;
                    float wz = dz ? f.z : 1.f - f.z;
                    float w = wx * wy * wz;
                    float4 a = R[1], b4 = R[2], c4 = R[3], d4 = R[4];
                    acc[0]  = fmaf(w, a.x,  acc[0]);
                    acc[1]  = fmaf(w, a.y,  acc[1]);
                    acc[2]  = fmaf(w, a.z,  acc[2]);
                    acc[3]  = fmaf(w, a.w,  acc[3]);
                    acc[4]  = fmaf(w, b4.x, acc[4]);
                    acc[5]  = fmaf(w, b4.y, acc[5]);
                    acc[6]  = fmaf(w, b4.z, acc[6]);
                    acc[7]  = fmaf(w, b4.w, acc[7]);
                    acc[8]  = fmaf(w, c4.x, acc[8]);
                    acc[9]  = fmaf(w, c4.y, acc[9]);
                    acc[10] = fmaf(w, c4.z, acc[10]);
                    acc[11] = fmaf(w, c4.w, acc[11]);
                    acc[12] = fmaf(w, d4.x, acc[12]);
                    acc[13] = fmaf(w, d4.y, acc[13]);
                    acc[14] = fmaf(w, d4.z, acc[14]);
                    acc[15] = fmaf(w, d4.w, acc[15]);
                }
            }
        }
    }

    uint4 q0, q1;
    q0.x = pack_bf2(acc[0],  acc[1]);  q0.y = pack_bf2(acc[2],  acc[3]);
    q0.z = pack_bf2(acc[4],  acc[5]);  q0.w = pack_bf2(acc[6],  acc[7]);
    q1.x = pack_bf2(acc[8],  acc[9]);  q1.y = pack_bf2(acc[10], acc[11]);
    q1.z = pack_bf2(acc[12], acc[13]); q1.w = pack_bf2(acc[14], acc[15]);
    uint4* gb = (uint4*)(gridb + ((long)bh * NG3 + (rx << 10) + tid) * NC);
    gb[0] = q0;
    gb[1] = q1;
}

// ---------------------------------------------------------------------------
// Kernel 3: grouped 3x3x3 conv via BF16 MFMA (implicit im2col). Output BF16.
// ---------------------------------------------------------------------------
__global__ __launch_bounds__(256)
void k_conv2(const unsigned short* __restrict__ gridb,   // [bh][cell][16] bf16
             const float* __restrict__ cw, const float* __restrict__ cb,
             unsigned short* __restrict__ convo)          // [bh][cell][16] bf16
{
    __shared__ unsigned short sg[2 * 6 * 6 * 34 * 8];   // 39168 B
    __shared__ unsigned short sw[28 * 16 * 2 * 8];      // 14336 B
    const int tid = threadIdx.x;
    const int bid = blockIdx.x;
    const int xt = bid & 7, yt = (bid >> 3) & 7, bh = bid >> 6;
    const int h = bh & 7;
    const int x0 = xt * 4, y0 = yt * 4;

    for (int e = tid; e < 16 * 432; e += 256) {
        int oc = e / 432, r = e % 432;
        int ic = r / 27, tap = r % 27;
        __hip_bfloat16 hbw = __float2bfloat16(cw[(h * 16 + oc) * 432 + r]);
        sw[((tap * 16 + oc) * 2 + (ic >> 3)) * 8 + (ic & 7)] = *(unsigned short*)&hbw;
    }
    {
        int oc = tid >> 4, ic = tid & 15;
        sw[((27 * 16 + oc) * 2 + (ic >> 3)) * 8 + (ic & 7)] = 0;
    }
    const unsigned short* gb = gridb + (long)bh * NG3 * 16;
    for (int e = tid; e < 6 * 6 * 34 * 2; e += 256) {
        int ihh = e & 1;
        int cellu = e >> 1;
        int zz = cellu % 34;
        int yu = cellu / 34;
        int yy = yu % 6, xx = yu / 6;
        int gx = x0 + xx - 1, gy = y0 + yy - 1, gz = zz - 1;
        uint4 v = make_uint4(0, 0, 0, 0);
        if ((unsigned)gx < NG && (unsigned)gy < NG && (unsigned)gz < NG)
            v = *(const uint4*)(gb + (((gx * NG + gy) * NG + gz) * 16 + ihh * 8));
        *(uint4*)(sg + ((long)ihh * 6 * 6 * 34 + cellu) * 8) = v;
    }
    __syncthreads();

    const int lane = tid & 63;
    const int wv = tid >> 6;
    const int m  = lane & 15;
    const int ihl = (lane >> 4) & 1;
    const int tp = lane >> 5;

    f32x4 acc[8];
    #pragma unroll
    for (int j = 0; j < 8; ++j) acc[j] = (f32x4){0.f, 0.f, 0.f, 0.f};

    #pragma unroll 1
    for (int p = 0; p < 14; ++p) {
        int tap = 2 * p + tp;
        bf16x8 bfr = *(const bf16x8*)(sw + ((tap * 16 + (lane & 15)) * 2 + ihl) * 8);
        int tap_a = tap > 26 ? 26 : tap;
        int kx = tap_a / 9, r9 = tap_a % 9;
        int ky = r9 / 3, kz = r9 % 3;
        int xx = wv + kx;
        #pragma unroll
        for (int j = 0; j < 8; ++j) {
            int yl = j >> 1, zh = j & 1;
            int yy = yl + ky;
            int zz = zh * 16 + m + kz;
            bf16x8 afr = *(const bf16x8*)(sg + ((long)ihl * 6 * 6 * 34 + ((xx * 6 + yy) * 34 + zz)) * 8);
            acc[j] = __builtin_amdgcn_mfma_f32_16x16x32_bf16(afr, bfr, acc[j], 0, 0, 0);
        }
    }

    const float bias = cb[h * 16 + (lane & 15)];
    unsigned short* cvb = convo + (long)bh * NG3 * NC;
    const int gx = x0 + wv;
    const int rowg = (lane >> 4) * 4;
    #pragma unroll
    for (int j = 0; j < 8; ++j) {
        int yl = j >> 1, zh = j & 1;
        int gy = y0 + yl;
        long cellbase = (long)(gx * NG + gy) * NG + zh * 16;
        #pragma unroll
        for (int r = 0; r < 4; ++r) {
            __hip_bfloat16 hb = __float2bfloat16(acc[j][r] + bias);
            cvb[(cellbase + rowg + r) * NC + (lane & 15)] = *(unsigned short*)&hb;
        }
    }
}

// ---------------------------------------------------------------------------
// Kernel 4: slice (weighted gather from bf16 convo) + BN + ReLU, out f32.
// ---------------------------------------------------------------------------
__global__ __launch_bounds__(256)
void k_slice(const unsigned short* __restrict__ convo, const float4* __restrict__ pre,
             const float* __restrict__ ag, const float* __restrict__ ab,
             const float* __restrict__ am, const float* __restrict__ av,
             float* __restrict__ out)
{
    __shared__ float asc[128], ash[128];
    const int tid = threadIdx.x;
    if (tid < 128) {
        float s = rsqrtf(av[tid] + KEPS) * ag[tid];
        asc[tid] = s;
        ash[tid] = ab[tid] - am[tid] * s;
    }
    __syncthreads();

    long t = (long)blockIdx.x * 256 + tid;
    long bh = t / NN;
    int n = (int)(t % NN);
    int b = (int)(bh >> 3), h = (int)(bh & 7);
    const unsigned short* g = convo + bh * (long)NG3 * NC;

    float4 r = pre[t];
    int ibase = __float_as_int(r.x);
    float fx = r.y, fy = r.z, fz = r.w;
    float gx = 1.f - fx, gy = 1.f - fy, gz = 1.f - fz;
    const float ws8[8] = {gx*gy*gz, gx*gy*fz, gx*fy*gz, gx*fy*fz,
                          fx*gy*gz, fx*gy*fz, fx*fy*gz, fx*fy*fz};
    const int offs8[8] = {0, 1, NG, NG + 1, NG*NG, NG*NG + 1, NG*NG + NG, NG*NG + NG + 1};

    float acc[NC];
    #pragma unroll
    for (int c = 0; c < NC; ++c) acc[c] = 0.f;
    #pragma unroll
    for (int ci = 0; ci < 8; ++ci) {
        float w = ws8[ci];
        const uint4* gc = (const uint4*)(g + (long)(ibase + offs8[ci]) * NC);
        uint4 u0 = gc[0], u1 = gc[1];
        acc[0]  = fmaf(w, bf_lo(u0.x), acc[0]);
        acc[1]  = fmaf(w, bf_hi(u0.x), acc[1]);
        acc[2]  = fmaf(w, bf_lo(u0.y), acc[2]);
        acc[3]  = fmaf(w, bf_hi(u0.y), acc[3]);
        acc[4]  = fmaf(w, bf_lo(u0.z), acc[4]);
        acc[5]  = fmaf(w, bf_hi(u0.z), acc[5]);
        acc[6]  = fmaf(w, bf_lo(u0.w), acc[6]);
        acc[7]  = fmaf(w, bf_hi(u0.w), acc[7]);
        acc[8]  = fmaf(w, bf_lo(u1.x), acc[8]);
        acc[9]  = fmaf(w, bf_hi(u1.x), acc[9]);
        acc[10] = fmaf(w, bf_lo(u1.y), acc[10]);
        acc[11] = fmaf(w, bf_hi(u1.y), acc[11]);
        acc[12] = fmaf(w, bf_lo(u1.z), acc[12]);
        acc[13] = fmaf(w, bf_hi(u1.z), acc[13]);
        acc[14] = fmaf(w, bf_lo(u1.w), acc[14]);
        acc[15] = fmaf(w, bf_hi(u1.w), acc[15]);
    }
    float* ob = out + ((long)b * 128 + h * 16) * NN + n;
    #pragma unroll
    for (int c = 0; c < NC; ++c) {
        float rr = fmaf(acc[c], asc[h * 16 + c], ash[h * 16 + c]);
        ob[(long)c * NN] = fmaxf(rr, 0.f);
    }
}

// ---------------------------------------------------------------------------
extern "C" void kernel_launch(void* const* d_in, const int* in_sizes, int n_in,
                              void* d_out, int out_size, void* d_ws, size_t ws_size,
                              hipStream_t stream)
{
    (void)in_sizes; (void)n_in; (void)out_size; (void)ws_size;
    const float* x    = (const float*)d_in[0];
    const float* orig = (const float*)d_in[1];
    const float* wkv  = (const float*)d_in[2];
    const float* kg   = (const float*)d_in[3];
    const float* kb   = (const float*)d_in[4];
    const float* km   = (const float*)d_in[5];
    const float* kvv  = (const float*)d_in[6];
    const float* vg   = (const float*)d_in[7];
    const float* vb   = (const float*)d_in[8];
    const float* vm   = (const float*)d_in[9];
    const float* vv   = (const float*)d_in[10];
    const float* Wt   = (const float*)d_in[11];
    const float* bt   = (const float*)d_in[12];
    const float* cw   = (const float*)d_in[13];
    const float* cb   = (const float*)d_in[14];
    const float* ag   = (const float*)d_in[15];
    const float* ab   = (const float*)d_in[16];
    const float* am   = (const float*)d_in[17];
    const float* av   = (const float*)d_in[18];

    char* ws = (char*)d_ws;
    float4*         pre       = (float4*)        (ws);                 //  8,388,608
    int*            hist      = (int*)           (ws + 8388608);       //  4,194,304
    int*            offs      = (int*)           (ws + 12582912);      //  4,194,304
    int*            offs_live = (int*)           (ws + 16777216);      //  4,194,304
    float*          values    = (float*)         (ws + 20971520);      // 33,554,432
    float4*         binned5   = (float4*)        (ws + 54525952);      // 41,943,040
    unsigned short* gridb     = (unsigned short*)(ws + 96468992);      // 33,554,432 -> end 130,023,424
    unsigned short* convo     = (unsigned short*)(ws + 20971520);      // 33,554,432 (alias over values)

    hipMemsetAsync(hist, 0, (size_t)NB * NH * NG3 * sizeof(int), stream);

    k_front2<<<dim3(NB * 64), dim3(256), 0, stream>>>(
        x, orig, wkv, kg, kb, km, kvv, vg, vb, vm, vv, Wt, bt, values, pre, hist);

    k_scan_cells<<<dim3(NB * NH), dim3(1024), 0, stream>>>(hist, offs, offs_live);

    k_scatter<<<dim3((NB * NH * NN) / 256), dim3(256), 0, stream>>>(
        pre, values, offs_live, binned5);

    k_splat4<<<dim3(NB * NH * NG), dim3(1024), 0, stream>>>(binned5, hist, offs, gridb);

    k_conv2<<<dim3(NB * NH * 64), dim3(256), 0, stream>>>(gridb, cw, cb, convo);

    k_slice<<<dim3((NB * NH * NN) / 256), dim3(256), 0, stream>>>(
        convo, pre, ag, ab, am, av, (float*)d_out);
}

// Round 10
// 234.141 us; speedup vs baseline: 5.3950x; 1.1682x over previous
//
#include <hip/hip_runtime.h>
#include <hip/hip_bf16.h>

#define NB  4
#define NH  8
#define NC  16
#define ND  64
#define NN  16384
#define NG  32
#define NG3 32768
#define NKV 152
#define KEPS 1e-5f
#define TN  256   // points per k_front2 block

typedef __attribute__((ext_vector_type(8))) short bf16x8;
typedef __attribute__((ext_vector_type(4))) float f32x4;

__device__ __forceinline__ unsigned pack_bf2(float lo, float hi) {
    __hip_bfloat16 a = __float2bfloat16(lo);
    __hip_bfloat16 b = __float2bfloat16(hi);
    return (unsigned)(*(unsigned short*)&a) | ((unsigned)(*(unsigned short*)&b) << 16);
}
__device__ __forceinline__ float bf_lo(unsigned u) { return __uint_as_float(u << 16); }
__device__ __forceinline__ float bf_hi(unsigned u) { return __uint_as_float(u & 0xffff0000u); }

// ---------------------------------------------------------------------------
// Kernel 1: front — keys fp32 VALU, values bf16 MFMA; values stored BF16.
// ---------------------------------------------------------------------------
__global__ __launch_bounds__(256)
void k_front2(const float* __restrict__ x,      // [B,D,N]
              const float* __restrict__ orig,   // [B,3,N]
              const float* __restrict__ wkv,    // [152,64]
              const float* __restrict__ kg, const float* __restrict__ kb,
              const float* __restrict__ km, const float* __restrict__ kvv,
              const float* __restrict__ vg, const float* __restrict__ vb,
              const float* __restrict__ vm, const float* __restrict__ vv,
              const float* __restrict__ Wt,     // [8,3,3]
              const float* __restrict__ bt,     // [8,3]
              unsigned short* __restrict__ valb, // [B,H,N,C] bf16
              float4* __restrict__ pre,         // [B,H,N]
              int* __restrict__ hist)           // [B*H*32768]
{
    __shared__ unsigned short xb[TN * 72];      // bf16 x tile [n][d], pitch 72
    __shared__ float wk[24 * ND];
    __shared__ float ksc[24], ksh[24], vsc[128], vsh[128], wts[72], bts[24];
    const int tid = threadIdx.x;
    const int b  = blockIdx.x >> 6;
    const int n0 = (blockIdx.x & 63) * TN;
    const int n  = n0 + tid;

    for (int i = tid; i < 24 * ND; i += 256) wk[i] = wkv[i];
    if (tid < 24) {
        float s = rsqrtf(kvv[tid] + KEPS) * kg[tid];
        ksc[tid] = s;
        ksh[tid] = kb[tid] - km[tid] * s;
    }
    if (tid < 128) {
        float s = rsqrtf(vv[tid] + KEPS) * vg[tid];
        vsc[tid] = s;
        vsh[tid] = vb[tid] - vm[tid] * s;
    }
    if (tid < 72) wts[tid] = Wt[tid];
    if (tid < 24) bts[tid] = bt[tid];

    float xr[ND];
    #pragma unroll
    for (int d = 0; d < ND; ++d)
        xr[d] = x[((long)b * ND + d) * NN + n];
    #pragma unroll
    for (int j = 0; j < 8; ++j) {
        uint4 q;
        q.x = pack_bf2(xr[8*j+0], xr[8*j+1]);
        q.y = pack_bf2(xr[8*j+2], xr[8*j+3]);
        q.z = pack_bf2(xr[8*j+4], xr[8*j+5]);
        q.w = pack_bf2(xr[8*j+6], xr[8*j+7]);
        *(uint4*)(xb + tid * 72 + j * 8) = q;
    }
    __syncthreads();

    float ko[24];
    #pragma unroll 1
    for (int o = 0; o < 24; o += 4) {
        float s0 = 0.f, s1 = 0.f, s2 = 0.f, s3 = 0.f;
        #pragma unroll
        for (int dq = 0; dq < 16; ++dq) {
            const float4 w0 = *(const float4*)&wk[(o + 0) * ND + dq * 4];
            const float4 w1 = *(const float4*)&wk[(o + 1) * ND + dq * 4];
            const float4 w2 = *(const float4*)&wk[(o + 2) * ND + dq * 4];
            const float4 w3 = *(const float4*)&wk[(o + 3) * ND + dq * 4];
            float a0 = xr[4*dq], a1 = xr[4*dq+1], a2 = xr[4*dq+2], a3 = xr[4*dq+3];
            s0 = fmaf(w0.x, a0, fmaf(w0.y, a1, fmaf(w0.z, a2, fmaf(w0.w, a3, s0))));
            s1 = fmaf(w1.x, a0, fmaf(w1.y, a1, fmaf(w1.z, a2, fmaf(w1.w, a3, s1))));
            s2 = fmaf(w2.x, a0, fmaf(w2.y, a1, fmaf(w2.z, a2, fmaf(w2.w, a3, s2))));
            s3 = fmaf(w3.x, a0, fmaf(w3.y, a1, fmaf(w3.z, a2, fmaf(w3.w, a3, s3))));
        }
        ko[o + 0] = fmaf(s0, ksc[o + 0], ksh[o + 0]);
        ko[o + 1] = fmaf(s1, ksc[o + 1], ksh[o + 1]);
        ko[o + 2] = fmaf(s2, ksc[o + 2], ksh[o + 2]);
        ko[o + 3] = fmaf(s3, ksc[o + 3], ksh[o + 3]);
    }

    {
        const int lane = tid & 63;
        const int wv = tid >> 6;
        const int l15 = lane & 15, l4 = lane >> 4;

        bf16x8 bfr[2][2];
        float bsc[2], bsh[2];
        #pragma unroll
        for (int p = 0; p < 2; ++p) {
            int oc = (2 * wv + p) * 16 + l15;
            bsc[p] = vsc[oc];
            bsh[p] = vsh[oc];
            #pragma unroll
            for (int ks = 0; ks < 2; ++ks) {
                const float* wp = wkv + (24 + oc) * ND + ks * 32 + l4 * 8;
                float4 a = *(const float4*)wp;
                float4 c = *(const float4*)(wp + 4);
                uint4 q;
                q.x = pack_bf2(a.x, a.y); q.y = pack_bf2(a.z, a.w);
                q.z = pack_bf2(c.x, c.y); q.w = pack_bf2(c.z, c.w);
                bfr[p][ks] = *(bf16x8*)&q;
            }
        }

        #pragma unroll 1
        for (int nb = 0; nb < 16; ++nb) {
            bf16x8 a0 = *(const bf16x8*)(xb + (nb * 16 + l15) * 72 + l4 * 8);
            bf16x8 a1 = *(const bf16x8*)(xb + (nb * 16 + l15) * 72 + 32 + l4 * 8);
            #pragma unroll
            for (int p = 0; p < 2; ++p) {
                f32x4 acc = (f32x4){0.f, 0.f, 0.f, 0.f};
                acc = __builtin_amdgcn_mfma_f32_16x16x32_bf16(a0, bfr[p][0], acc, 0, 0, 0);
                acc = __builtin_amdgcn_mfma_f32_16x16x32_bf16(a1, bfr[p][1], acc, 0, 0, 0);
                int h = 2 * wv + p;
                unsigned short* vp = valb + (((long)(b * NH + h) * NN + n0 + nb * 16 + l4 * 4) * NC) + l15;
                #pragma unroll
                for (int r = 0; r < 4; ++r) {
                    __hip_bfloat16 hb = __float2bfloat16(fmaf(acc[r], bsc[p], bsh[p]));
                    vp[r * NC] = *(unsigned short*)&hb;
                }
            }
        }
    }

    const float o0 = orig[((long)b * 3 + 0) * NN + n];
    const float o1 = orig[((long)b * 3 + 1) * NN + n];
    const float o2 = orig[((long)b * 3 + 2) * NN + n];

    #pragma unroll 1
    for (int h = 0; h < NH; ++h) {
        float p0 = o0 + ko[h * 3 + 0];
        float p1 = o1 + ko[h * 3 + 1];
        float p2 = o2 + ko[h * 3 + 2];
        float t0 = fmaf(wts[h * 9 + 0], p0, fmaf(wts[h * 9 + 1], p1, fmaf(wts[h * 9 + 2], p2, bts[h * 3 + 0])));
        float t1 = fmaf(wts[h * 9 + 3], p0, fmaf(wts[h * 9 + 4], p1, fmaf(wts[h * 9 + 5], p2, bts[h * 3 + 1])));
        float t2 = fmaf(wts[h * 9 + 6], p0, fmaf(wts[h * 9 + 7], p1, fmaf(wts[h * 9 + 8], p2, bts[h * 3 + 2])));
        float l0 = tanhf(t0), l1 = tanhf(t1), l2 = tanhf(t2);
        float pos0 = (l0 + 1.f) * 15.5f;
        float pos1 = (l1 + 1.f) * 15.5f;
        float pos2 = (l2 + 1.f) * 15.5f;
        float b0 = fminf(fmaxf(floorf(pos0), 0.f), 30.f);
        float b1 = fminf(fmaxf(floorf(pos1), 0.f), 30.f);
        float b2 = fminf(fmaxf(floorf(pos2), 0.f), 30.f);
        int ix = (int)b0, iy = (int)b1, iz = (int)b2;
        float fx = pos0 - b0, fy = pos1 - b1, fz = pos2 - b2;
        int ibase = (ix * NG + iy) * NG + iz;
        float4 pr;
        pr.x = __int_as_float(ibase);
        pr.y = fx; pr.z = fy; pr.w = fz;
        int bh = b * NH + h;
        pre[(long)bh * NN + n] = pr;
        atomicAdd(&hist[bh * NG3 + ibase], 1);
    }
}

// ---------------------------------------------------------------------------
// Kernel 1b: per-bh exclusive prefix scan over 32768 cell counts.
// ---------------------------------------------------------------------------
__global__ __launch_bounds__(1024)
void k_scan_cells(const int* __restrict__ hist, int* __restrict__ offs,
                  int* __restrict__ offs_live)
{
    __shared__ int tsum[1024];
    const int bh = blockIdx.x, tid = threadIdx.x;
    const int* hb = hist + (long)bh * NG3;

    int s = 0;
    #pragma unroll 4
    for (int j = 0; j < 32; ++j) s += hb[tid * 32 + j];
    tsum[tid] = s;
    __syncthreads();
    for (int d = 1; d < 1024; d <<= 1) {
        int t = (tid >= d) ? tsum[tid - d] : 0;
        __syncthreads();
        tsum[tid] += t;
        __syncthreads();
    }
    int run = bh * NN + tsum[tid] - s;
    int* ob = offs + (long)bh * NG3;
    int* lb = offs_live + (long)bh * NG3;
    #pragma unroll 4
    for (int j = 0; j < 32; ++j) {
        int c = tid * 32 + j;
        ob[c] = run;
        lb[c] = run;
        run += hb[c];
    }
}

// ---------------------------------------------------------------------------
// Kernel 1c: scatter records into cell order. Record = 3 x uint4 = 48 B:
//   [0] = {fx, fy, fz, pad} f32, [1..2] = 16 bf16 values
// ---------------------------------------------------------------------------
__global__ __launch_bounds__(256)
void k_scatter2(const float4* __restrict__ pre, const unsigned short* __restrict__ valb,
                int* __restrict__ offs_live, uint4* __restrict__ rec)
{
    long t = (long)blockIdx.x * 256 + threadIdx.x;
    float4 r = pre[t];
    int ibase = __float_as_int(r.x);
    int bh = (int)(t >> 14);
    int slot = atomicAdd(&offs_live[(long)bh * NG3 + ibase], 1);
    const uint4* vp = (const uint4*)(valb + t * NC);
    uint4 v0 = vp[0], v1 = vp[1];
    uint4* out = rec + (long)slot * 3;
    out[0] = make_uint4(__float_as_uint(r.y), __float_as_uint(r.z), __float_as_uint(r.w), 0u);
    out[1] = v0;
    out[2] = v1;
}

// ---------------------------------------------------------------------------
// Kernel 2: splat — LDS-staged record chunks. Block (bh, rx) processes planes
// cx = rx, rx-1 in <=1024-record chunks: coalesced stage -> barrier ->
// per-thread clipped segment walk via ds_read. Atomic-free; output BF16.
// ---------------------------------------------------------------------------
__global__ __launch_bounds__(1024)
void k_splat5(const uint4* __restrict__ rec, const int* __restrict__ hist,
              const int* __restrict__ offs, unsigned short* __restrict__ gridb)
{
    __shared__ uint4 sr[1024 * 3];   // 48 KB chunk
    const int tid = threadIdx.x;
    const int rx = blockIdx.x & 31;
    const int bh = blockIdx.x >> 5;
    const int y = tid >> 5, z = tid & 31;

    const int* hb = hist + (long)bh * NG3;
    const int* ob = offs + (long)bh * NG3;

    float acc[16];
    #pragma unroll
    for (int c = 0; c < 16; ++c) acc[c] = 0.f;

    // preload all 8 cell segments (invalid -> empty [0,0))
    int cs8[2][2][2], ce8[2][2][2];
    #pragma unroll
    for (int dx = 0; dx < 2; ++dx)
    #pragma unroll
    for (int dy = 0; dy < 2; ++dy)
    #pragma unroll
    for (int dz = 0; dz < 2; ++dz) {
        int cx = rx - dx, cy = y - dy, cz = z - dz;
        bool valid = (cx >= 0) && (cy >= 0) && (cz >= 0);
        int cell = (cx << 10) | (cy << 5) | cz;
        int s = valid ? ob[cell] : 0;
        int e = valid ? s + hb[cell] : 0;
        cs8[dx][dy][dz] = s;
        ce8[dx][dy][dz] = e;
    }

    #pragma unroll
    for (int dx = 0; dx < 2; ++dx) {
        int cx = rx - dx;
        if (cx < 0) continue;                       // block-uniform
        int pc0 = cx << 10;
        int ps = ob[pc0];                           // uniform plane bounds
        int pe = ob[pc0 + 1023] + hb[pc0 + 1023];
        for (int cs = ps; cs < pe; cs += 1024) {
            int ce = min(cs + 1024, pe);
            __syncthreads();
            if (tid < ce - cs) {
                const uint4* R = rec + (long)(cs + tid) * 3;
                sr[tid * 3 + 0] = R[0];
                sr[tid * 3 + 1] = R[1];
                sr[tid * 3 + 2] = R[2];
            }
            __syncthreads();
            #pragma unroll
            for (int dy = 0; dy < 2; ++dy)
            #pragma unroll
            for (int dz = 0; dz < 2; ++dz) {
                int ls = max(cs8[dx][dy][dz], cs);
                int le = min(ce8[dx][dy][dz], ce);
                for (int r = ls; r < le; ++r) {
                    int k = (r - cs) * 3;
                    uint4 q0 = sr[k], q1 = sr[k + 1], q2 = sr[k + 2];
                    float fx = __uint_as_float(q0.x);
                    float fy = __uint_as_float(q0.y);
                    float fz = __uint_as_float(q0.z);
                    float w = (dx ? fx : 1.f - fx) * (dy ? fy : 1.f - fy) * (dz ? fz : 1.f - fz);
                    acc[0]  = fmaf(w, bf_lo(q1.x), acc[0]);
                    acc[1]  = fmaf(w, bf_hi(q1.x), acc[1]);
                    acc[2]  = fmaf(w, bf_lo(q1.y), acc[2]);
                    acc[3]  = fmaf(w, bf_hi(q1.y), acc[3]);
                    acc[4]  = fmaf(w, bf_lo(q1.z), acc[4]);
                    acc[5]  = fmaf(w, bf_hi(q1.z), acc[5]);
                    acc[6]  = fmaf(w, bf_lo(q1.w), acc[6]);
                    acc[7]  = fmaf(w, bf_hi(q1.w), acc[7]);
                    acc[8]  = fmaf(w, bf_lo(q2.x), acc[8]);
                    acc[9]  = fmaf(w, bf_hi(q2.x), acc[9]);
                    acc[10] = fmaf(w, bf_lo(q2.y), acc[10]);
                    acc[11] = fmaf(w, bf_hi(q2.y), acc[11]);
                    acc[12] = fmaf(w, bf_lo(q2.z), acc[12]);
                    acc[13] = fmaf(w, bf_hi(q2.z), acc[13]);
                    acc[14] = fmaf(w, bf_lo(q2.w), acc[14]);
                    acc[15] = fmaf(w, bf_hi(q2.w), acc[15]);
                }
            }
        }
    }

    uint4 q0, q1;
    q0.x = pack_bf2(acc[0],  acc[1]);  q0.y = pack_bf2(acc[2],  acc[3]);
    q0.z = pack_bf2(acc[4],  acc[5]);  q0.w = pack_bf2(acc[6],  acc[7]);
    q1.x = pack_bf2(acc[8],  acc[9]);  q1.y = pack_bf2(acc[10], acc[11]);
    q1.z = pack_bf2(acc[12], acc[13]); q1.w = pack_bf2(acc[14], acc[15]);
    uint4* gb = (uint4*)(gridb + ((long)bh * NG3 + (rx << 10) + tid) * NC);
    gb[0] = q0;
    gb[1] = q1;
}

// ---------------------------------------------------------------------------
// Kernel 3: grouped 3x3x3 conv via BF16 MFMA (implicit im2col). Output BF16.
// ---------------------------------------------------------------------------
__global__ __launch_bounds__(256)
void k_conv2(const unsigned short* __restrict__ gridb,
             const float* __restrict__ cw, const float* __restrict__ cb,
             unsigned short* __restrict__ convo)
{
    __shared__ unsigned short sg[2 * 6 * 6 * 34 * 8];
    __shared__ unsigned short sw[28 * 16 * 2 * 8];
    const int tid = threadIdx.x;
    const int bid = blockIdx.x;
    const int xt = bid & 7, yt = (bid >> 3) & 7, bh = bid >> 6;
    const int h = bh & 7;
    const int x0 = xt * 4, y0 = yt * 4;

    for (int e = tid; e < 16 * 432; e += 256) {
        int oc = e / 432, r = e % 432;
        int ic = r / 27, tap = r % 27;
        __hip_bfloat16 hbw = __float2bfloat16(cw[(h * 16 + oc) * 432 + r]);
        sw[((tap * 16 + oc) * 2 + (ic >> 3)) * 8 + (ic & 7)] = *(unsigned short*)&hbw;
    }
    {
        int oc = tid >> 4, ic = tid & 15;
        sw[((27 * 16 + oc) * 2 + (ic >> 3)) * 8 + (ic & 7)] = 0;
    }
    const unsigned short* gb = gridb + (long)bh * NG3 * 16;
    for (int e = tid; e < 6 * 6 * 34 * 2; e += 256) {
        int ihh = e & 1;
        int cellu = e >> 1;
        int zz = cellu % 34;
        int yu = cellu / 34;
        int yy = yu % 6, xx = yu / 6;
        int gx = x0 + xx - 1, gy = y0 + yy - 1, gz = zz - 1;
        uint4 v = make_uint4(0, 0, 0, 0);
        if ((unsigned)gx < NG && (unsigned)gy < NG && (unsigned)gz < NG)
            v = *(const uint4*)(gb + (((gx * NG + gy) * NG + gz) * 16 + ihh * 8));
        *(uint4*)(sg + ((long)ihh * 6 * 6 * 34 + cellu) * 8) = v;
    }
    __syncthreads();

    const int lane = tid & 63;
    const int wv = tid >> 6;
    const int m  = lane & 15;
    const int ihl = (lane >> 4) & 1;
    const int tp = lane >> 5;

    f32x4 acc[8];
    #pragma unroll
    for (int j = 0; j < 8; ++j) acc[j] = (f32x4){0.f, 0.f, 0.f, 0.f};

    #pragma unroll 1
    for (int p = 0; p < 14; ++p) {
        int tap = 2 * p + tp;
        bf16x8 bfr = *(const bf16x8*)(sw + ((tap * 16 + (lane & 15)) * 2 + ihl) * 8);
        int tap_a = tap > 26 ? 26 : tap;
        int kx = tap_a / 9, r9 = tap_a % 9;
        int ky = r9 / 3, kz = r9 % 3;
        int xx = wv + kx;
        #pragma unroll
        for (int j = 0; j < 8; ++j) {
            int yl = j >> 1, zh = j & 1;
            int yy = yl + ky;
            int zz = zh * 16 + m + kz;
            bf16x8 afr = *(const bf16x8*)(sg + ((long)ihl * 6 * 6 * 34 + ((xx * 6 + yy) * 34 + zz)) * 8);
            acc[j] = __builtin_amdgcn_mfma_f32_16x16x32_bf16(afr, bfr, acc[j], 0, 0, 0);
        }
    }

    const float bias = cb[h * 16 + (lane & 15)];
    unsigned short* cvb = convo + (long)bh * NG3 * NC;
    const int gx = x0 + wv;
    const int rowg = (lane >> 4) * 4;
    #pragma unroll
    for (int j = 0; j < 8; ++j) {
        int yl = j >> 1, zh = j & 1;
        int gy = y0 + yl;
        long cellbase = (long)(gx * NG + gy) * NG + zh * 16;
        #pragma unroll
        for (int r = 0; r < 4; ++r) {
            __hip_bfloat16 hb = __float2bfloat16(acc[j][r] + bias);
            cvb[(cellbase + rowg + r) * NC + (lane & 15)] = *(unsigned short*)&hb;
        }
    }
}

// ---------------------------------------------------------------------------
// Kernel 4: slice (weighted gather from bf16 convo) + BN + ReLU, out f32.
// ---------------------------------------------------------------------------
__global__ __launch_bounds__(256)
void k_slice(const unsigned short* __restrict__ convo, const float4* __restrict__ pre,
             const float* __restrict__ ag, const float* __restrict__ ab,
             const float* __restrict__ am, const float* __restrict__ av,
             float* __restrict__ out)
{
    __shared__ float asc[128], ash[128];
    const int tid = threadIdx.x;
    if (tid < 128) {
        float s = rsqrtf(av[tid] + KEPS) * ag[tid];
        asc[tid] = s;
        ash[tid] = ab[tid] - am[tid] * s;
    }
    __syncthreads();

    long t = (long)blockIdx.x * 256 + tid;
    long bh = t / NN;
    int n = (int)(t % NN);
    int b = (int)(bh >> 3), h = (int)(bh & 7);
    const unsigned short* g = convo + bh * (long)NG3 * NC;

    float4 r = pre[t];
    int ibase = __float_as_int(r.x);
    float fx = r.y, fy = r.z, fz = r.w;
    float gx = 1.f - fx, gy = 1.f - fy, gz = 1.f - fz;
    const float ws8[8] = {gx*gy*gz, gx*gy*fz, gx*fy*gz, gx*fy*fz,
                          fx*gy*gz, fx*gy*fz, fx*fy*gz, fx*fy*fz};
    const int offs8[8] = {0, 1, NG, NG + 1, NG*NG, NG*NG + 1, NG*NG + NG, NG*NG + NG + 1};

    float acc[NC];
    #pragma unroll
    for (int c = 0; c < NC; ++c) acc[c] = 0.f;
    #pragma unroll
    for (int ci = 0; ci < 8; ++ci) {
        float w = ws8[ci];
        const uint4* gc = (const uint4*)(g + (long)(ibase + offs8[ci]) * NC);
        uint4 u0 = gc[0], u1 = gc[1];
        acc[0]  = fmaf(w, bf_lo(u0.x), acc[0]);
        acc[1]  = fmaf(w, bf_hi(u0.x), acc[1]);
        acc[2]  = fmaf(w, bf_lo(u0.y), acc[2]);
        acc[3]  = fmaf(w, bf_hi(u0.y), acc[3]);
        acc[4]  = fmaf(w, bf_lo(u0.z), acc[4]);
        acc[5]  = fmaf(w, bf_hi(u0.z), acc[5]);
        acc[6]  = fmaf(w, bf_lo(u0.w), acc[6]);
        acc[7]  = fmaf(w, bf_hi(u0.w), acc[7]);
        acc[8]  = fmaf(w, bf_lo(u1.x), acc[8]);
        acc[9]  = fmaf(w, bf_hi(u1.x), acc[9]);
        acc[10] = fmaf(w, bf_lo(u1.y), acc[10]);
        acc[11] = fmaf(w, bf_hi(u1.y), acc[11]);
        acc[12] = fmaf(w, bf_lo(u1.z), acc[12]);
        acc[13] = fmaf(w, bf_hi(u1.z), acc[13]);
        acc[14] = fmaf(w, bf_lo(u1.w), acc[14]);
        acc[15] = fmaf(w, bf_hi(u1.w), acc[15]);
    }
    float* ob = out + ((long)b * 128 + h * 16) * NN + n;
    #pragma unroll
    for (int c = 0; c < NC; ++c) {
        float rr = fmaf(acc[c], asc[h * 16 + c], ash[h * 16 + c]);
        ob[(long)c * NN] = fmaxf(rr, 0.f);
    }
}

// ---------------------------------------------------------------------------
extern "C" void kernel_launch(void* const* d_in, const int* in_sizes, int n_in,
                              void* d_out, int out_size, void* d_ws, size_t ws_size,
                              hipStream_t stream)
{
    (void)in_sizes; (void)n_in; (void)out_size; (void)ws_size;
    const float* x    = (const float*)d_in[0];
    const float* orig = (const float*)d_in[1];
    const float* wkv  = (const float*)d_in[2];
    const float* kg   = (const float*)d_in[3];
    const float* kb   = (const float*)d_in[4];
    const float* km   = (const float*)d_in[5];
    const float* kvv  = (const float*)d_in[6];
    const float* vg   = (const float*)d_in[7];
    const float* vb   = (const float*)d_in[8];
    const float* vm   = (const float*)d_in[9];
    const float* vv   = (const float*)d_in[10];
    const float* Wt   = (const float*)d_in[11];
    const float* bt   = (const float*)d_in[12];
    const float* cw   = (const float*)d_in[13];
    const float* cb   = (const float*)d_in[14];
    const float* ag   = (const float*)d_in[15];
    const float* ab   = (const float*)d_in[16];
    const float* am   = (const float*)d_in[17];
    const float* av   = (const float*)d_in[18];

    char* ws = (char*)d_ws;
    float4*         pre       = (float4*)        (ws);                 //  8,388,608
    int*            hist      = (int*)           (ws + 8388608);       //  4,194,304
    int*            offs      = (int*)           (ws + 12582912);      //  4,194,304
    int*            offs_live = (int*)           (ws + 16777216);      //  4,194,304
    unsigned short* valb      = (unsigned short*)(ws + 20971520);      // 16,777,216 -> end 37,748,736
    uint4*          rec       = (uint4*)         (ws + 37748736);      // 25,165,824 -> end 62,914,560
    unsigned short* gridb     = (unsigned short*)(ws + 62914560);      // 33,554,432 -> end 96,468,992
    unsigned short* convo     = (unsigned short*)(ws + 20971520);      // 33,554,432 (alias valb+rec, dead by k_conv2)

    hipMemsetAsync(hist, 0, (size_t)NB * NH * NG3 * sizeof(int), stream);

    k_front2<<<dim3(NB * 64), dim3(256), 0, stream>>>(
        x, orig, wkv, kg, kb, km, kvv, vg, vb, vm, vv, Wt, bt, valb, pre, hist);

    k_scan_cells<<<dim3(NB * NH), dim3(1024), 0, stream>>>(hist, offs, offs_live);

    k_scatter2<<<dim3((NB * NH * NN) / 256), dim3(256), 0, stream>>>(
        pre, valb, offs_live, rec);

    k_splat5<<<dim3(NB * NH * NG), dim3(1024), 0, stream>>>(rec, hist, offs, gridb);

    k_conv2<<<dim3(NB * NH * 64), dim3(256), 0, stream>>>(gridb, cw, cb, convo);

    k_slice<<<dim3((NB * NH * NN) / 256), dim3(256), 0, stream>>>(
        convo, pre, ag, ab, am, av, (float*)d_out);
}

// Round 11
// 231.250 us; speedup vs baseline: 5.4624x; 1.0125x over previous
//
#include <hip/hip_runtime.h>
#include <hip/hip_bf16.h>

#define NB  4
#define NH  8
#define NC  16
#define ND  64
#define NN  16384
#define NG  32
#define NG3 32768
#define NKV 152
#define KEPS 1e-5f
#define TN  256   // points per k_front2 block

typedef __attribute__((ext_vector_type(8))) short bf16x8;
typedef __attribute__((ext_vector_type(4))) float f32x4;

__device__ __forceinline__ unsigned pack_bf2(float lo, float hi) {
    __hip_bfloat16 a = __float2bfloat16(lo);
    __hip_bfloat16 b = __float2bfloat16(hi);
    return (unsigned)(*(unsigned short*)&a) | ((unsigned)(*(unsigned short*)&b) << 16);
}
__device__ __forceinline__ float bf_lo(unsigned u) { return __uint_as_float(u << 16); }
__device__ __forceinline__ float bf_hi(unsigned u) { return __uint_as_float(u & 0xffff0000u); }

// ---------------------------------------------------------------------------
// Kernel 1: front — keys fp32 VALU, values bf16 MFMA; values stored BF16.
// ---------------------------------------------------------------------------
__global__ __launch_bounds__(256)
void k_front2(const float* __restrict__ x,      // [B,D,N]
              const float* __restrict__ orig,   // [B,3,N]
              const float* __restrict__ wkv,    // [152,64]
              const float* __restrict__ kg, const float* __restrict__ kb,
              const float* __restrict__ km, const float* __restrict__ kvv,
              const float* __restrict__ vg, const float* __restrict__ vb,
              const float* __restrict__ vm, const float* __restrict__ vv,
              const float* __restrict__ Wt,     // [8,3,3]
              const float* __restrict__ bt,     // [8,3]
              unsigned short* __restrict__ valb, // [B,H,N,C] bf16
              float4* __restrict__ pre,         // [B,H,N]
              int* __restrict__ hist)           // [B*H*32768]
{
    __shared__ unsigned short xb[TN * 72];      // bf16 x tile [n][d], pitch 72
    __shared__ float wk[24 * ND];
    __shared__ float ksc[24], ksh[24], vsc[128], vsh[128], wts[72], bts[24];
    const int tid = threadIdx.x;
    const int b  = blockIdx.x >> 6;
    const int n0 = (blockIdx.x & 63) * TN;
    const int n  = n0 + tid;

    for (int i = tid; i < 24 * ND; i += 256) wk[i] = wkv[i];
    if (tid < 24) {
        float s = rsqrtf(kvv[tid] + KEPS) * kg[tid];
        ksc[tid] = s;
        ksh[tid] = kb[tid] - km[tid] * s;
    }
    if (tid < 128) {
        float s = rsqrtf(vv[tid] + KEPS) * vg[tid];
        vsc[tid] = s;
        vsh[tid] = vb[tid] - vm[tid] * s;
    }
    if (tid < 72) wts[tid] = Wt[tid];
    if (tid < 24) bts[tid] = bt[tid];

    float xr[ND];
    #pragma unroll
    for (int d = 0; d < ND; ++d)
        xr[d] = x[((long)b * ND + d) * NN + n];
    #pragma unroll
    for (int j = 0; j < 8; ++j) {
        uint4 q;
        q.x = pack_bf2(xr[8*j+0], xr[8*j+1]);
        q.y = pack_bf2(xr[8*j+2], xr[8*j+3]);
        q.z = pack_bf2(xr[8*j+4], xr[8*j+5]);
        q.w = pack_bf2(xr[8*j+6], xr[8*j+7]);
        *(uint4*)(xb + tid * 72 + j * 8) = q;
    }
    __syncthreads();

    float ko[24];
    #pragma unroll 1
    for (int o = 0; o < 24; o += 4) {
        float s0 = 0.f, s1 = 0.f, s2 = 0.f, s3 = 0.f;
        #pragma unroll
        for (int dq = 0; dq < 16; ++dq) {
            const float4 w0 = *(const float4*)&wk[(o + 0) * ND + dq * 4];
            const float4 w1 = *(const float4*)&wk[(o + 1) * ND + dq * 4];
            const float4 w2 = *(const float4*)&wk[(o + 2) * ND + dq * 4];
            const float4 w3 = *(const float4*)&wk[(o + 3) * ND + dq * 4];
            float a0 = xr[4*dq], a1 = xr[4*dq+1], a2 = xr[4*dq+2], a3 = xr[4*dq+3];
            s0 = fmaf(w0.x, a0, fmaf(w0.y, a1, fmaf(w0.z, a2, fmaf(w0.w, a3, s0))));
            s1 = fmaf(w1.x, a0, fmaf(w1.y, a1, fmaf(w1.z, a2, fmaf(w1.w, a3, s1))));
            s2 = fmaf(w2.x, a0, fmaf(w2.y, a1, fmaf(w2.z, a2, fmaf(w2.w, a3, s2))));
            s3 = fmaf(w3.x, a0, fmaf(w3.y, a1, fmaf(w3.z, a2, fmaf(w3.w, a3, s3))));
        }
        ko[o + 0] = fmaf(s0, ksc[o + 0], ksh[o + 0]);
        ko[o + 1] = fmaf(s1, ksc[o + 1], ksh[o + 1]);
        ko[o + 2] = fmaf(s2, ksc[o + 2], ksh[o + 2]);
        ko[o + 3] = fmaf(s3, ksc[o + 3], ksh[o + 3]);
    }

    {
        const int lane = tid & 63;
        const int wv = tid >> 6;
        const int l15 = lane & 15, l4 = lane >> 4;

        bf16x8 bfr[2][2];
        float bsc[2], bsh[2];
        #pragma unroll
        for (int p = 0; p < 2; ++p) {
            int oc = (2 * wv + p) * 16 + l15;
            bsc[p] = vsc[oc];
            bsh[p] = vsh[oc];
            #pragma unroll
            for (int ks = 0; ks < 2; ++ks) {
                const float* wp = wkv + (24 + oc) * ND + ks * 32 + l4 * 8;
                float4 a = *(const float4*)wp;
                float4 c = *(const float4*)(wp + 4);
                uint4 q;
                q.x = pack_bf2(a.x, a.y); q.y = pack_bf2(a.z, a.w);
                q.z = pack_bf2(c.x, c.y); q.w = pack_bf2(c.z, c.w);
                bfr[p][ks] = *(bf16x8*)&q;
            }
        }

        #pragma unroll 1
        for (int nb = 0; nb < 16; ++nb) {
            bf16x8 a0 = *(const bf16x8*)(xb + (nb * 16 + l15) * 72 + l4 * 8);
            bf16x8 a1 = *(const bf16x8*)(xb + (nb * 16 + l15) * 72 + 32 + l4 * 8);
            #pragma unroll
            for (int p = 0; p < 2; ++p) {
                f32x4 acc = (f32x4){0.f, 0.f, 0.f, 0.f};
                acc = __builtin_amdgcn_mfma_f32_16x16x32_bf16(a0, bfr[p][0], acc, 0, 0, 0);
                acc = __builtin_amdgcn_mfma_f32_16x16x32_bf16(a1, bfr[p][1], acc, 0, 0, 0);
                int h = 2 * wv + p;
                unsigned short* vp = valb + (((long)(b * NH + h) * NN + n0 + nb * 16 + l4 * 4) * NC) + l15;
                #pragma unroll
                for (int r = 0; r < 4; ++r) {
                    __hip_bfloat16 hb = __float2bfloat16(fmaf(acc[r], bsc[p], bsh[p]));
                    vp[r * NC] = *(unsigned short*)&hb;
                }
            }
        }
    }

    const float o0 = orig[((long)b * 3 + 0) * NN + n];
    const float o1 = orig[((long)b * 3 + 1) * NN + n];
    const float o2 = orig[((long)b * 3 + 2) * NN + n];

    #pragma unroll 1
    for (int h = 0; h < NH; ++h) {
        float p0 = o0 + ko[h * 3 + 0];
        float p1 = o1 + ko[h * 3 + 1];
        float p2 = o2 + ko[h * 3 + 2];
        float t0 = fmaf(wts[h * 9 + 0], p0, fmaf(wts[h * 9 + 1], p1, fmaf(wts[h * 9 + 2], p2, bts[h * 3 + 0])));
        float t1 = fmaf(wts[h * 9 + 3], p0, fmaf(wts[h * 9 + 4], p1, fmaf(wts[h * 9 + 5], p2, bts[h * 3 + 1])));
        float t2 = fmaf(wts[h * 9 + 6], p0, fmaf(wts[h * 9 + 7], p1, fmaf(wts[h * 9 + 8], p2, bts[h * 3 + 2])));
        float l0 = tanhf(t0), l1 = tanhf(t1), l2 = tanhf(t2);
        float pos0 = (l0 + 1.f) * 15.5f;
        float pos1 = (l1 + 1.f) * 15.5f;
        float pos2 = (l2 + 1.f) * 15.5f;
        float b0 = fminf(fmaxf(floorf(pos0), 0.f), 30.f);
        float b1 = fminf(fmaxf(floorf(pos1), 0.f), 30.f);
        float b2 = fminf(fmaxf(floorf(pos2), 0.f), 30.f);
        int ix = (int)b0, iy = (int)b1, iz = (int)b2;
        float fx = pos0 - b0, fy = pos1 - b1, fz = pos2 - b2;
        int ibase = (ix * NG + iy) * NG + iz;
        float4 pr;
        pr.x = __int_as_float(ibase);
        pr.y = fx; pr.z = fy; pr.w = fz;
        int bh = b * NH + h;
        pre[(long)bh * NN + n] = pr;
        atomicAdd(&hist[bh * NG3 + ibase], 1);
    }
}

// ---------------------------------------------------------------------------
// Kernel 1b: per-bh exclusive prefix scan over 32768 cell counts.
// ---------------------------------------------------------------------------
__global__ __launch_bounds__(1024)
void k_scan_cells(const int* __restrict__ hist, int* __restrict__ offs,
                  int* __restrict__ offs_live)
{
    __shared__ int tsum[1024];
    const int bh = blockIdx.x, tid = threadIdx.x;
    const int* hb = hist + (long)bh * NG3;

    int s = 0;
    #pragma unroll 4
    for (int j = 0; j < 32; ++j) s += hb[tid * 32 + j];
    tsum[tid] = s;
    __syncthreads();
    for (int d = 1; d < 1024; d <<= 1) {
        int t = (tid >= d) ? tsum[tid - d] : 0;
        __syncthreads();
        tsum[tid] += t;
        __syncthreads();
    }
    int run = bh * NN + tsum[tid] - s;
    int* ob = offs + (long)bh * NG3;
    int* lb = offs_live + (long)bh * NG3;
    #pragma unroll 4
    for (int j = 0; j < 32; ++j) {
        int c = tid * 32 + j;
        ob[c] = run;
        lb[c] = run;
        run += hb[c];
    }
}

// ---------------------------------------------------------------------------
// Kernel 1c: scatter records into cell order. Record = 3 x uint4 = 48 B.
// ---------------------------------------------------------------------------
__global__ __launch_bounds__(256)
void k_scatter2(const float4* __restrict__ pre, const unsigned short* __restrict__ valb,
                int* __restrict__ offs_live, uint4* __restrict__ rec)
{
    long t = (long)blockIdx.x * 256 + threadIdx.x;
    float4 r = pre[t];
    int ibase = __float_as_int(r.x);
    int bh = (int)(t >> 14);
    int slot = atomicAdd(&offs_live[(long)bh * NG3 + ibase], 1);
    const uint4* vp = (const uint4*)(valb + t * NC);
    uint4 v0 = vp[0], v1 = vp[1];
    uint4* out = rec + (long)slot * 3;
    out[0] = make_uint4(__float_as_uint(r.y), __float_as_uint(r.z), __float_as_uint(r.w), 0u);
    out[1] = v0;
    out[2] = v1;
}

// ---------------------------------------------------------------------------
// Kernel 2: splat — LDS-staged record chunks, atomic-free, output BF16.
// ---------------------------------------------------------------------------
__global__ __launch_bounds__(1024)
void k_splat5(const uint4* __restrict__ rec, const int* __restrict__ hist,
              const int* __restrict__ offs, unsigned short* __restrict__ gridb)
{
    __shared__ uint4 sr[1024 * 3];   // 48 KB chunk
    const int tid = threadIdx.x;
    const int rx = blockIdx.x & 31;
    const int bh = blockIdx.x >> 5;
    const int y = tid >> 5, z = tid & 31;

    const int* hb = hist + (long)bh * NG3;
    const int* ob = offs + (long)bh * NG3;

    float acc[16];
    #pragma unroll
    for (int c = 0; c < 16; ++c) acc[c] = 0.f;

    int cs8[2][2][2], ce8[2][2][2];
    #pragma unroll
    for (int dx = 0; dx < 2; ++dx)
    #pragma unroll
    for (int dy = 0; dy < 2; ++dy)
    #pragma unroll
    for (int dz = 0; dz < 2; ++dz) {
        int cx = rx - dx, cy = y - dy, cz = z - dz;
        bool valid = (cx >= 0) && (cy >= 0) && (cz >= 0);
        int cell = (cx << 10) | (cy << 5) | cz;
        int s = valid ? ob[cell] : 0;
        int e = valid ? s + hb[cell] : 0;
        cs8[dx][dy][dz] = s;
        ce8[dx][dy][dz] = e;
    }

    #pragma unroll
    for (int dx = 0; dx < 2; ++dx) {
        int cx = rx - dx;
        if (cx < 0) continue;
        int pc0 = cx << 10;
        int ps = ob[pc0];
        int pe = ob[pc0 + 1023] + hb[pc0 + 1023];
        for (int cs = ps; cs < pe; cs += 1024) {
            int ce = min(cs + 1024, pe);
            __syncthreads();
            if (tid < ce - cs) {
                const uint4* R = rec + (long)(cs + tid) * 3;
                sr[tid * 3 + 0] = R[0];
                sr[tid * 3 + 1] = R[1];
                sr[tid * 3 + 2] = R[2];
            }
            __syncthreads();
            #pragma unroll
            for (int dy = 0; dy < 2; ++dy)
            #pragma unroll
            for (int dz = 0; dz < 2; ++dz) {
                int ls = max(cs8[dx][dy][dz], cs);
                int le = min(ce8[dx][dy][dz], ce);
                for (int r = ls; r < le; ++r) {
                    int k = (r - cs) * 3;
                    uint4 q0 = sr[k], q1 = sr[k + 1], q2 = sr[k + 2];
                    float fx = __uint_as_float(q0.x);
                    float fy = __uint_as_float(q0.y);
                    float fz = __uint_as_float(q0.z);
                    float w = (dx ? fx : 1.f - fx) * (dy ? fy : 1.f - fy) * (dz ? fz : 1.f - fz);
                    acc[0]  = fmaf(w, bf_lo(q1.x), acc[0]);
                    acc[1]  = fmaf(w, bf_hi(q1.x), acc[1]);
                    acc[2]  = fmaf(w, bf_lo(q1.y), acc[2]);
                    acc[3]  = fmaf(w, bf_hi(q1.y), acc[3]);
                    acc[4]  = fmaf(w, bf_lo(q1.z), acc[4]);
                    acc[5]  = fmaf(w, bf_hi(q1.z), acc[5]);
                    acc[6]  = fmaf(w, bf_lo(q1.w), acc[6]);
                    acc[7]  = fmaf(w, bf_hi(q1.w), acc[7]);
                    acc[8]  = fmaf(w, bf_lo(q2.x), acc[8]);
                    acc[9]  = fmaf(w, bf_hi(q2.x), acc[9]);
                    acc[10] = fmaf(w, bf_lo(q2.y), acc[10]);
                    acc[11] = fmaf(w, bf_hi(q2.y), acc[11]);
                    acc[12] = fmaf(w, bf_lo(q2.z), acc[12]);
                    acc[13] = fmaf(w, bf_hi(q2.z), acc[13]);
                    acc[14] = fmaf(w, bf_lo(q2.w), acc[14]);
                    acc[15] = fmaf(w, bf_hi(q2.w), acc[15]);
                }
            }
        }
    }

    uint4 q0, q1;
    q0.x = pack_bf2(acc[0],  acc[1]);  q0.y = pack_bf2(acc[2],  acc[3]);
    q0.z = pack_bf2(acc[4],  acc[5]);  q0.w = pack_bf2(acc[6],  acc[7]);
    q1.x = pack_bf2(acc[8],  acc[9]);  q1.y = pack_bf2(acc[10], acc[11]);
    q1.z = pack_bf2(acc[12], acc[13]); q1.w = pack_bf2(acc[14], acc[15]);
    uint4* gb = (uint4*)(gridb + ((long)bh * NG3 + (rx << 10) + tid) * NC);
    gb[0] = q0;
    gb[1] = q1;
}

// ---------------------------------------------------------------------------
// Kernel 3: grouped 3x3x3 conv via BF16 MFMA. Conflict-free LDS layouts:
//   sg [ihl][xx 6][yy 6][zz 18][8ic]  (20736 B) — A-frag reads 16-lane contig
//   sw [tap 28][ihl 2][oc 16][8ic]    (14336 B) — B-frag reads 16-lane contig,
//   staging uses linear e-map (shifts/masks only, coalesced, conflict-free).
// Block = (bh, xt, yt, zt): 4x4 xy-tile, 16-z-tile. 35 KB LDS -> 4 blocks/CU.
// ---------------------------------------------------------------------------
__global__ __launch_bounds__(256)
void k_conv3(const unsigned short* __restrict__ gridb,
             const float* __restrict__ cw, const float* __restrict__ cb,
             unsigned short* __restrict__ convo)
{
    __shared__ unsigned short sg[2 * 6 * 6 * 18 * 8];   // 20736 B
    __shared__ unsigned short sw[28 * 2 * 16 * 8];      // 14336 B
    const int tid = threadIdx.x;
    const int bid = blockIdx.x;
    const int zt = bid & 1, yt = (bid >> 1) & 7, xt = (bid >> 4) & 7, bh = bid >> 7;
    const int h = bh & 7;
    const int x0 = xt * 4, y0 = yt * 4, z0 = zt * 16;

    // weights: sw[e], e = tap*256 + ihl*128 + oc*8 + icl (consecutive lanes ->
    // consecutive 2B -> conflict-free; pure shift/mask decode)
    for (int e = tid; e < 28 * 256; e += 256) {
        int icl = e & 7, oc = (e >> 3) & 15, ihl = (e >> 7) & 1, tap = e >> 8;
        int ic = ihl * 8 + icl;
        float wv = (tap < 27) ? cw[(h * 16 + oc) * 432 + ic * 27 + tap] : 0.f;
        __hip_bfloat16 hbw = __float2bfloat16(wv);
        sw[e] = *(unsigned short*)&hbw;
    }
    // grid tile with halo: e = cell*2 + ihl -> global chunk (cell*16+ihl*8),
    // consecutive lanes coalesced 16 B
    const unsigned short* gb = gridb + (long)bh * NG3 * 16;
    for (int e = tid; e < 2 * 6 * 6 * 18; e += 256) {
        int ihl = e & 1, c = e >> 1;
        int zz = c % 18, yu = c / 18;
        int yy = yu % 6, xx = yu / 6;
        int gx = x0 + xx - 1, gy = y0 + yy - 1, gz = z0 + zz - 1;
        uint4 v = make_uint4(0, 0, 0, 0);
        if ((unsigned)gx < NG && (unsigned)gy < NG && (unsigned)gz < NG)
            v = *(const uint4*)(gb + (((gx * NG + gy) * NG + gz) * 16 + ihl * 8));
        *(uint4*)(sg + (((ihl * 6 + xx) * 6 + yy) * 18 + zz) * 8) = v;
    }
    __syncthreads();

    const int lane = tid & 63;
    const int wv = tid >> 6;          // x-slice 0..3
    const int m  = lane & 15;         // z within 16-cell tile (A row / oc col)
    const int l4 = lane >> 4;
    const int ihl = l4 & 1;
    const int tp = l4 >> 1;

    f32x4 acc[4];
    #pragma unroll
    for (int j = 0; j < 4; ++j) acc[j] = (f32x4){0.f, 0.f, 0.f, 0.f};

    #pragma unroll 1
    for (int p = 0; p < 14; ++p) {
        int tap = 2 * p + tp;
        bf16x8 bfr = *(const bf16x8*)(sw + ((tap * 2 + ihl) * 16 + m) * 8);
        int tap_a = tap > 26 ? 26 : tap;
        int kx = tap_a / 9, r9 = tap_a % 9;
        int ky = r9 / 3, kz = r9 % 3;
        int xx = wv + kx;
        #pragma unroll
        for (int j = 0; j < 4; ++j) {
            int yy = j + ky;
            int zz = m + kz;
            bf16x8 afr = *(const bf16x8*)(sg + (((ihl * 6 + xx) * 6 + yy) * 18 + zz) * 8);
            acc[j] = __builtin_amdgcn_mfma_f32_16x16x32_bf16(afr, bfr, acc[j], 0, 0, 0);
        }
    }

    const float bias = cb[h * 16 + m];
    unsigned short* cvb = convo + (long)bh * NG3 * NC;
    const int gx = x0 + wv;
    #pragma unroll
    for (int j = 0; j < 4; ++j) {
        int gy = y0 + j;
        long cellbase = (long)(gx * NG + gy) * NG + z0 + l4 * 4;
        #pragma unroll
        for (int r = 0; r < 4; ++r) {
            __hip_bfloat16 hb = __float2bfloat16(acc[j][r] + bias);
            cvb[(cellbase + r) * NC + m] = *(unsigned short*)&hb;
        }
    }
}

// ---------------------------------------------------------------------------
// Kernel 4: slice (weighted gather from bf16 convo) + BN + ReLU, out f32.
// ---------------------------------------------------------------------------
__global__ __launch_bounds__(256)
void k_slice(const unsigned short* __restrict__ convo, const float4* __restrict__ pre,
             const float* __restrict__ ag, const float* __restrict__ ab,
             const float* __restrict__ am, const float* __restrict__ av,
             float* __restrict__ out)
{
    __shared__ float asc[128], ash[128];
    const int tid = threadIdx.x;
    if (tid < 128) {
        float s = rsqrtf(av[tid] + KEPS) * ag[tid];
        asc[tid] = s;
        ash[tid] = ab[tid] - am[tid] * s;
    }
    __syncthreads();

    long t = (long)blockIdx.x * 256 + tid;
    long bh = t / NN;
    int n = (int)(t % NN);
    int b = (int)(bh >> 3), h = (int)(bh & 7);
    const unsigned short* g = convo + bh * (long)NG3 * NC;

    float4 r = pre[t];
    int ibase = __float_as_int(r.x);
    float fx = r.y, fy = r.z, fz = r.w;
    float gx = 1.f - fx, gy = 1.f - fy, gz = 1.f - fz;
    const float ws8[8] = {gx*gy*gz, gx*gy*fz, gx*fy*gz, gx*fy*fz,
                          fx*gy*gz, fx*gy*fz, fx*fy*gz, fx*fy*fz};
    const int offs8[8] = {0, 1, NG, NG + 1, NG*NG, NG*NG + 1, NG*NG + NG, NG*NG + NG + 1};

    float acc[NC];
    #pragma unroll
    for (int c = 0; c < NC; ++c) acc[c] = 0.f;
    #pragma unroll
    for (int ci = 0; ci < 8; ++ci) {
        float w = ws8[ci];
        const uint4* gc = (const uint4*)(g + (long)(ibase + offs8[ci]) * NC);
        uint4 u0 = gc[0], u1 = gc[1];
        acc[0]  = fmaf(w, bf_lo(u0.x), acc[0]);
        acc[1]  = fmaf(w, bf_hi(u0.x), acc[1]);
        acc[2]  = fmaf(w, bf_lo(u0.y), acc[2]);
        acc[3]  = fmaf(w, bf_hi(u0.y), acc[3]);
        acc[4]  = fmaf(w, bf_lo(u0.z), acc[4]);
        acc[5]  = fmaf(w, bf_hi(u0.z), acc[5]);
        acc[6]  = fmaf(w, bf_lo(u0.w), acc[6]);
        acc[7]  = fmaf(w, bf_hi(u0.w), acc[7]);
        acc[8]  = fmaf(w, bf_lo(u1.x), acc[8]);
        acc[9]  = fmaf(w, bf_hi(u1.x), acc[9]);
        acc[10] = fmaf(w, bf_lo(u1.y), acc[10]);
        acc[11] = fmaf(w, bf_hi(u1.y), acc[11]);
        acc[12] = fmaf(w, bf_lo(u1.z), acc[12]);
        acc[13] = fmaf(w, bf_hi(u1.z), acc[13]);
        acc[14] = fmaf(w, bf_lo(u1.w), acc[14]);
        acc[15] = fmaf(w, bf_hi(u1.w), acc[15]);
    }
    float* ob = out + ((long)b * 128 + h * 16) * NN + n;
    #pragma unroll
    for (int c = 0; c < NC; ++c) {
        float rr = fmaf(acc[c], asc[h * 16 + c], ash[h * 16 + c]);
        ob[(long)c * NN] = fmaxf(rr, 0.f);
    }
}

// ---------------------------------------------------------------------------
extern "C" void kernel_launch(void* const* d_in, const int* in_sizes, int n_in,
                              void* d_out, int out_size, void* d_ws, size_t ws_size,
                              hipStream_t stream)
{
    (void)in_sizes; (void)n_in; (void)out_size; (void)ws_size;
    const float* x    = (const float*)d_in[0];
    const float* orig = (const float*)d_in[1];
    const float* wkv  = (const float*)d_in[2];
    const float* kg   = (const float*)d_in[3];
    const float* kb   = (const float*)d_in[4];
    const float* km   = (const float*)d_in[5];
    const float* kvv  = (const float*)d_in[6];
    const float* vg   = (const float*)d_in[7];
    const float* vb   = (const float*)d_in[8];
    const float* vm   = (const float*)d_in[9];
    const float* vv   = (const float*)d_in[10];
    const float* Wt   = (const float*)d_in[11];
    const float* bt   = (const float*)d_in[12];
    const float* cw   = (const float*)d_in[13];
    const float* cb   = (const float*)d_in[14];
    const float* ag   = (const float*)d_in[15];
    const float* ab   = (const float*)d_in[16];
    const float* am   = (const float*)d_in[17];
    const float* av   = (const float*)d_in[18];

    char* ws = (char*)d_ws;
    float4*         pre       = (float4*)        (ws);                 //  8,388,608
    int*            hist      = (int*)           (ws + 8388608);       //  4,194,304
    int*            offs      = (int*)           (ws + 12582912);      //  4,194,304
    int*            offs_live = (int*)           (ws + 16777216);      //  4,194,304
    unsigned short* valb      = (unsigned short*)(ws + 20971520);      // 16,777,216 -> end 37,748,736
    uint4*          rec       = (uint4*)         (ws + 37748736);      // 25,165,824 -> end 62,914,560
    unsigned short* gridb     = (unsigned short*)(ws + 62914560);      // 33,554,432 -> end 96,468,992
    unsigned short* convo     = (unsigned short*)(ws + 20971520);      // 33,554,432 (alias valb+rec, dead by k_conv3)

    hipMemsetAsync(hist, 0, (size_t)NB * NH * NG3 * sizeof(int), stream);

    k_front2<<<dim3(NB * 64), dim3(256), 0, stream>>>(
        x, orig, wkv, kg, kb, km, kvv, vg, vb, vm, vv, Wt, bt, valb, pre, hist);

    k_scan_cells<<<dim3(NB * NH), dim3(1024), 0, stream>>>(hist, offs, offs_live);

    k_scatter2<<<dim3((NB * NH * NN) / 256), dim3(256), 0, stream>>>(
        pre, valb, offs_live, rec);

    k_splat5<<<dim3(NB * NH * NG), dim3(1024), 0, stream>>>(rec, hist, offs, gridb);

    k_conv3<<<dim3(NB * NH * 128), dim3(256), 0, stream>>>(gridb, cw, cb, convo);

    k_slice<<<dim3((NB * NH * NN) / 256), dim3(256), 0, stream>>>(
        convo, pre, ag, ab, am, av, (float*)d_out);
}

// Round 12
// 228.072 us; speedup vs baseline: 5.5386x; 1.0139x over previous
//
#include <hip/hip_runtime.h>
#include <hip/hip_bf16.h>

#define NB  4
#define NH  8
#define NC  16
#define ND  64
#define NN  16384
#define NG  32
#define NG3 32768
#define NKV 152
#define KEPS 1e-5f
#define TN  256   // points per k_front2 block

typedef __attribute__((ext_vector_type(8))) short bf16x8;
typedef __attribute__((ext_vector_type(4))) float f32x4;

__device__ __forceinline__ unsigned pack_bf2(float lo, float hi) {
    __hip_bfloat16 a = __float2bfloat16(lo);
    __hip_bfloat16 b = __float2bfloat16(hi);
    return (unsigned)(*(unsigned short*)&a) | ((unsigned)(*(unsigned short*)&b) << 16);
}
__device__ __forceinline__ float bf_lo(unsigned u) { return __uint_as_float(u << 16); }
__device__ __forceinline__ float bf_hi(unsigned u) { return __uint_as_float(u & 0xffff0000u); }

// ---------------------------------------------------------------------------
// Kernel 1: front — keys fp32 VALU, values bf16 MFMA; values stored BF16.
// ---------------------------------------------------------------------------
__global__ __launch_bounds__(256)
void k_front2(const float* __restrict__ x,      // [B,D,N]
              const float* __restrict__ orig,   // [B,3,N]
              const float* __restrict__ wkv,    // [152,64]
              const float* __restrict__ kg, const float* __restrict__ kb,
              const float* __restrict__ km, const float* __restrict__ kvv,
              const float* __restrict__ vg, const float* __restrict__ vb,
              const float* __restrict__ vm, const float* __restrict__ vv,
              const float* __restrict__ Wt,     // [8,3,3]
              const float* __restrict__ bt,     // [8,3]
              unsigned short* __restrict__ valb, // [B,H,N,C] bf16
              float4* __restrict__ pre,         // [B,H,N]
              int* __restrict__ hist)           // [B*H*32768]
{
    __shared__ unsigned short xb[TN * 72];      // bf16 x tile [n][d], pitch 72
    __shared__ float wk[24 * ND];
    __shared__ float ksc[24], ksh[24], vsc[128], vsh[128], wts[72], bts[24];
    const int tid = threadIdx.x;
    const int b  = blockIdx.x >> 6;
    const int n0 = (blockIdx.x & 63) * TN;
    const int n  = n0 + tid;

    for (int i = tid; i < 24 * ND; i += 256) wk[i] = wkv[i];
    if (tid < 24) {
        float s = rsqrtf(kvv[tid] + KEPS) * kg[tid];
        ksc[tid] = s;
        ksh[tid] = kb[tid] - km[tid] * s;
    }
    if (tid < 128) {
        float s = rsqrtf(vv[tid] + KEPS) * vg[tid];
        vsc[tid] = s;
        vsh[tid] = vb[tid] - vm[tid] * s;
    }
    if (tid < 72) wts[tid] = Wt[tid];
    if (tid < 24) bts[tid] = bt[tid];

    float xr[ND];
    #pragma unroll
    for (int d = 0; d < ND; ++d)
        xr[d] = x[((long)b * ND + d) * NN + n];
    #pragma unroll
    for (int j = 0; j < 8; ++j) {
        uint4 q;
        q.x = pack_bf2(xr[8*j+0], xr[8*j+1]);
        q.y = pack_bf2(xr[8*j+2], xr[8*j+3]);
        q.z = pack_bf2(xr[8*j+4], xr[8*j+5]);
        q.w = pack_bf2(xr[8*j+6], xr[8*j+7]);
        *(uint4*)(xb + tid * 72 + j * 8) = q;
    }
    __syncthreads();

    float ko[24];
    #pragma unroll 1
    for (int o = 0; o < 24; o += 4) {
        float s0 = 0.f, s1 = 0.f, s2 = 0.f, s3 = 0.f;
        #pragma unroll
        for (int dq = 0; dq < 16; ++dq) {
            const float4 w0 = *(const float4*)&wk[(o + 0) * ND + dq * 4];
            const float4 w1 = *(const float4*)&wk[(o + 1) * ND + dq * 4];
            const float4 w2 = *(const float4*)&wk[(o + 2) * ND + dq * 4];
            const float4 w3 = *(const float4*)&wk[(o + 3) * ND + dq * 4];
            float a0 = xr[4*dq], a1 = xr[4*dq+1], a2 = xr[4*dq+2], a3 = xr[4*dq+3];
            s0 = fmaf(w0.x, a0, fmaf(w0.y, a1, fmaf(w0.z, a2, fmaf(w0.w, a3, s0))));
            s1 = fmaf(w1.x, a0, fmaf(w1.y, a1, fmaf(w1.z, a2, fmaf(w1.w, a3, s1))));
            s2 = fmaf(w2.x, a0, fmaf(w2.y, a1, fmaf(w2.z, a2, fmaf(w2.w, a3, s2))));
            s3 = fmaf(w3.x, a0, fmaf(w3.y, a1, fmaf(w3.z, a2, fmaf(w3.w, a3, s3))));
        }
        ko[o + 0] = fmaf(s0, ksc[o + 0], ksh[o + 0]);
        ko[o + 1] = fmaf(s1, ksc[o + 1], ksh[o + 1]);
        ko[o + 2] = fmaf(s2, ksc[o + 2], ksh[o + 2]);
        ko[o + 3] = fmaf(s3, ksc[o + 3], ksh[o + 3]);
    }

    {
        const int lane = tid & 63;
        const int wv = tid >> 6;
        const int l15 = lane & 15, l4 = lane >> 4;

        bf16x8 bfr[2][2];
        float bsc[2], bsh[2];
        #pragma unroll
        for (int p = 0; p < 2; ++p) {
            int oc = (2 * wv + p) * 16 + l15;
            bsc[p] = vsc[oc];
            bsh[p] = vsh[oc];
            #pragma unroll
            for (int ks = 0; ks < 2; ++ks) {
                const float* wp = wkv + (24 + oc) * ND + ks * 32 + l4 * 8;
                float4 a = *(const float4*)wp;
                float4 c = *(const float4*)(wp + 4);
                uint4 q;
                q.x = pack_bf2(a.x, a.y); q.y = pack_bf2(a.z, a.w);
                q.z = pack_bf2(c.x, c.y); q.w = pack_bf2(c.z, c.w);
                bfr[p][ks] = *(bf16x8*)&q;
            }
        }

        #pragma unroll 1
        for (int nb = 0; nb < 16; ++nb) {
            bf16x8 a0 = *(const bf16x8*)(xb + (nb * 16 + l15) * 72 + l4 * 8);
            bf16x8 a1 = *(const bf16x8*)(xb + (nb * 16 + l15) * 72 + 32 + l4 * 8);
            #pragma unroll
            for (int p = 0; p < 2; ++p) {
                f32x4 acc = (f32x4){0.f, 0.f, 0.f, 0.f};
                acc = __builtin_amdgcn_mfma_f32_16x16x32_bf16(a0, bfr[p][0], acc, 0, 0, 0);
                acc = __builtin_amdgcn_mfma_f32_16x16x32_bf16(a1, bfr[p][1], acc, 0, 0, 0);
                int h = 2 * wv + p;
                unsigned short* vp = valb + (((long)(b * NH + h) * NN + n0 + nb * 16 + l4 * 4) * NC) + l15;
                #pragma unroll
                for (int r = 0; r < 4; ++r) {
                    __hip_bfloat16 hb = __float2bfloat16(fmaf(acc[r], bsc[p], bsh[p]));
                    vp[r * NC] = *(unsigned short*)&hb;
                }
            }
        }
    }

    const float o0 = orig[((long)b * 3 + 0) * NN + n];
    const float o1 = orig[((long)b * 3 + 1) * NN + n];
    const float o2 = orig[((long)b * 3 + 2) * NN + n];

    #pragma unroll 1
    for (int h = 0; h < NH; ++h) {
        float p0 = o0 + ko[h * 3 + 0];
        float p1 = o1 + ko[h * 3 + 1];
        float p2 = o2 + ko[h * 3 + 2];
        float t0 = fmaf(wts[h * 9 + 0], p0, fmaf(wts[h * 9 + 1], p1, fmaf(wts[h * 9 + 2], p2, bts[h * 3 + 0])));
        float t1 = fmaf(wts[h * 9 + 3], p0, fmaf(wts[h * 9 + 4], p1, fmaf(wts[h * 9 + 5], p2, bts[h * 3 + 1])));
        float t2 = fmaf(wts[h * 9 + 6], p0, fmaf(wts[h * 9 + 7], p1, fmaf(wts[h * 9 + 8], p2, bts[h * 3 + 2])));
        float l0 = tanhf(t0), l1 = tanhf(t1), l2 = tanhf(t2);
        float pos0 = (l0 + 1.f) * 15.5f;
        float pos1 = (l1 + 1.f) * 15.5f;
        float pos2 = (l2 + 1.f) * 15.5f;
        float b0 = fminf(fmaxf(floorf(pos0), 0.f), 30.f);
        float b1 = fminf(fmaxf(floorf(pos1), 0.f), 30.f);
        float b2 = fminf(fmaxf(floorf(pos2), 0.f), 30.f);
        int ix = (int)b0, iy = (int)b1, iz = (int)b2;
        float fx = pos0 - b0, fy = pos1 - b1, fz = pos2 - b2;
        int ibase = (ix * NG + iy) * NG + iz;
        float4 pr;
        pr.x = __int_as_float(ibase);
        pr.y = fx; pr.z = fy; pr.w = fz;
        int bh = b * NH + h;
        pre[(long)bh * NN + n] = pr;
        atomicAdd(&hist[bh * NG3 + ibase], 1);
    }
}

// ---------------------------------------------------------------------------
// Kernel 1b: per-bh exclusive prefix scan over 32768 cell counts.
// ---------------------------------------------------------------------------
__global__ __launch_bounds__(1024)
void k_scan_cells(const int* __restrict__ hist, int* __restrict__ offs,
                  int* __restrict__ offs_live)
{
    __shared__ int tsum[1024];
    const int bh = blockIdx.x, tid = threadIdx.x;
    const int* hb = hist + (long)bh * NG3;

    int s = 0;
    #pragma unroll 4
    for (int j = 0; j < 32; ++j) s += hb[tid * 32 + j];
    tsum[tid] = s;
    __syncthreads();
    for (int d = 1; d < 1024; d <<= 1) {
        int t = (tid >= d) ? tsum[tid - d] : 0;
        __syncthreads();
        tsum[tid] += t;
        __syncthreads();
    }
    int run = bh * NN + tsum[tid] - s;
    int* ob = offs + (long)bh * NG3;
    int* lb = offs_live + (long)bh * NG3;
    #pragma unroll 4
    for (int j = 0; j < 32; ++j) {
        int c = tid * 32 + j;
        ob[c] = run;
        lb[c] = run;
        run += hb[c];
    }
}

// ---------------------------------------------------------------------------
// Kernel 1c: scatter records into cell order. Record = 3 x uint4 = 48 B.
// ---------------------------------------------------------------------------
__global__ __launch_bounds__(256)
void k_scatter2(const float4* __restrict__ pre, const unsigned short* __restrict__ valb,
                int* __restrict__ offs_live, uint4* __restrict__ rec)
{
    long t = (long)blockIdx.x * 256 + threadIdx.x;
    float4 r = pre[t];
    int ibase = __float_as_int(r.x);
    int bh = (int)(t >> 14);
    int slot = atomicAdd(&offs_live[(long)bh * NG3 + ibase], 1);
    const uint4* vp = (const uint4*)(valb + t * NC);
    uint4 v0 = vp[0], v1 = vp[1];
    uint4* out = rec + (long)slot * 3;
    out[0] = make_uint4(__float_as_uint(r.y), __float_as_uint(r.z), __float_as_uint(r.w), 0u);
    out[1] = v0;
    out[2] = v1;
}

// ---------------------------------------------------------------------------
// Kernel 2: splat — LDS-staged record chunks, atomic-free, output BF16.
// ---------------------------------------------------------------------------
__global__ __launch_bounds__(1024)
void k_splat5(const uint4* __restrict__ rec, const int* __restrict__ hist,
              const int* __restrict__ offs, unsigned short* __restrict__ gridb)
{
    __shared__ uint4 sr[1024 * 3];   // 48 KB chunk
    const int tid = threadIdx.x;
    const int rx = blockIdx.x & 31;
    const int bh = blockIdx.x >> 5;
    const int y = tid >> 5, z = tid & 31;

    const int* hb = hist + (long)bh * NG3;
    const int* ob = offs + (long)bh * NG3;

    float acc[16];
    #pragma unroll
    for (int c = 0; c < 16; ++c) acc[c] = 0.f;

    int cs8[2][2][2], ce8[2][2][2];
    #pragma unroll
    for (int dx = 0; dx < 2; ++dx)
    #pragma unroll
    for (int dy = 0; dy < 2; ++dy)
    #pragma unroll
    for (int dz = 0; dz < 2; ++dz) {
        int cx = rx - dx, cy = y - dy, cz = z - dz;
        bool valid = (cx >= 0) && (cy >= 0) && (cz >= 0);
        int cell = (cx << 10) | (cy << 5) | cz;
        int s = valid ? ob[cell] : 0;
        int e = valid ? s + hb[cell] : 0;
        cs8[dx][dy][dz] = s;
        ce8[dx][dy][dz] = e;
    }

    #pragma unroll
    for (int dx = 0; dx < 2; ++dx) {
        int cx = rx - dx;
        if (cx < 0) continue;
        int pc0 = cx << 10;
        int ps = ob[pc0];
        int pe = ob[pc0 + 1023] + hb[pc0 + 1023];
        for (int cs = ps; cs < pe; cs += 1024) {
            int ce = min(cs + 1024, pe);
            __syncthreads();
            if (tid < ce - cs) {
                const uint4* R = rec + (long)(cs + tid) * 3;
                sr[tid * 3 + 0] = R[0];
                sr[tid * 3 + 1] = R[1];
                sr[tid * 3 + 2] = R[2];
            }
            __syncthreads();
            #pragma unroll
            for (int dy = 0; dy < 2; ++dy)
            #pragma unroll
            for (int dz = 0; dz < 2; ++dz) {
                int ls = max(cs8[dx][dy][dz], cs);
                int le = min(ce8[dx][dy][dz], ce);
                for (int r = ls; r < le; ++r) {
                    int k = (r - cs) * 3;
                    uint4 q0 = sr[k], q1 = sr[k + 1], q2 = sr[k + 2];
                    float fx = __uint_as_float(q0.x);
                    float fy = __uint_as_float(q0.y);
                    float fz = __uint_as_float(q0.z);
                    float w = (dx ? fx : 1.f - fx) * (dy ? fy : 1.f - fy) * (dz ? fz : 1.f - fz);
                    acc[0]  = fmaf(w, bf_lo(q1.x), acc[0]);
                    acc[1]  = fmaf(w, bf_hi(q1.x), acc[1]);
                    acc[2]  = fmaf(w, bf_lo(q1.y), acc[2]);
                    acc[3]  = fmaf(w, bf_hi(q1.y), acc[3]);
                    acc[4]  = fmaf(w, bf_lo(q1.z), acc[4]);
                    acc[5]  = fmaf(w, bf_hi(q1.z), acc[5]);
                    acc[6]  = fmaf(w, bf_lo(q1.w), acc[6]);
                    acc[7]  = fmaf(w, bf_hi(q1.w), acc[7]);
                    acc[8]  = fmaf(w, bf_lo(q2.x), acc[8]);
                    acc[9]  = fmaf(w, bf_hi(q2.x), acc[9]);
                    acc[10] = fmaf(w, bf_lo(q2.y), acc[10]);
                    acc[11] = fmaf(w, bf_hi(q2.y), acc[11]);
                    acc[12] = fmaf(w, bf_lo(q2.z), acc[12]);
                    acc[13] = fmaf(w, bf_hi(q2.z), acc[13]);
                    acc[14] = fmaf(w, bf_lo(q2.w), acc[14]);
                    acc[15] = fmaf(w, bf_hi(q2.w), acc[15]);
                }
            }
        }
    }

    uint4 q0, q1;
    q0.x = pack_bf2(acc[0],  acc[1]);  q0.y = pack_bf2(acc[2],  acc[3]);
    q0.z = pack_bf2(acc[4],  acc[5]);  q0.w = pack_bf2(acc[6],  acc[7]);
    q1.x = pack_bf2(acc[8],  acc[9]);  q1.y = pack_bf2(acc[10], acc[11]);
    q1.z = pack_bf2(acc[12], acc[13]); q1.w = pack_bf2(acc[14], acc[15]);
    uint4* gb = (uint4*)(gridb + ((long)bh * NG3 + (rx << 10) + tid) * NC);
    gb[0] = q0;
    gb[1] = q1;
}

// ---------------------------------------------------------------------------
// Kernel 3a: one-time weight conversion into conv's sw layout (bf16).
// wpre[h][e], e = tap*256 + ihl*128 + oc*8 + icl; tap 27 zero-padded.
// ---------------------------------------------------------------------------
__global__ __launch_bounds__(256)
void k_wprep(const float* __restrict__ cw, unsigned short* __restrict__ wpre)
{
    const int h = blockIdx.x;
    for (int e = threadIdx.x; e < 7168; e += 256) {
        int icl = e & 7, oc = (e >> 3) & 15, ihl = (e >> 7) & 1, tap = e >> 8;
        int ic = ihl * 8 + icl;
        float wv = (tap < 27) ? cw[(h * 16 + oc) * 432 + ic * 27 + tap] : 0.f;
        __hip_bfloat16 hbw = __float2bfloat16(wv);
        wpre[h * 7168 + e] = *(unsigned short*)&hbw;
    }
}

// ---------------------------------------------------------------------------
// Kernel 3: grouped 3x3x3 conv via BF16 MFMA. Block = (bh, xt, yt, zt):
// 4x8 xy-tile, 16-z-tile. sg [ihl][xx6][yy10][zz18][8ic] (34560 B) +
// sw uint4-copied from wpre (14336 B) -> 48.9 KB, 3 blocks/CU.
// Per wave: 14 phases x (1 B-read + 8 A-reads + 8 MFMA).
// ---------------------------------------------------------------------------
__global__ __launch_bounds__(256)
void k_conv4(const unsigned short* __restrict__ gridb,
             const unsigned short* __restrict__ wpre,
             const float* __restrict__ cb,
             unsigned short* __restrict__ convo)
{
    __shared__ unsigned short sg[2 * 6 * 10 * 18 * 8];  // 34560 B
    __shared__ unsigned short sw[28 * 2 * 16 * 8];      // 14336 B
    const int tid = threadIdx.x;
    const int bid = blockIdx.x;
    const int zt = bid & 1, yt = (bid >> 1) & 3, xt = (bid >> 3) & 7, bh = bid >> 6;
    const int h = bh & 7;
    const int x0 = xt * 4, y0 = yt * 8, z0 = zt * 16;

    {   // weights: coalesced uint4 copy of pre-converted layout
        const uint4* wsrc = (const uint4*)(wpre + (long)h * 7168);
        uint4* wdst = (uint4*)sw;
        for (int e = tid; e < 896; e += 256) wdst[e] = wsrc[e];
    }
    // grid tile with halo
    const unsigned short* gb = gridb + (long)bh * NG3 * 16;
    for (int e = tid; e < 2 * 6 * 10 * 18; e += 256) {
        int ihl = e & 1, c = e >> 1;           // c = xx*180 + yy*18 + zz
        int zz = c % 18, yu = c / 18;
        int yy = yu % 10, xx = yu / 10;
        int gx = x0 + xx - 1, gy = y0 + yy - 1, gz = z0 + zz - 1;
        uint4 v = make_uint4(0, 0, 0, 0);
        if ((unsigned)gx < NG && (unsigned)gy < NG && (unsigned)gz < NG)
            v = *(const uint4*)(gb + (((gx * NG + gy) * NG + gz) * 16 + ihl * 8));
        *(uint4*)(sg + ((((ihl * 6 + xx) * 10 + yy) * 18) + zz) * 8) = v;
    }
    __syncthreads();

    const int lane = tid & 63;
    const int wv = tid >> 6;          // x-slice 0..3
    const int m  = lane & 15;         // z cell within 16-tile (A row / oc col)
    const int l4 = lane >> 4;
    const int ihl = l4 & 1;
    const int tp = l4 >> 1;

    f32x4 acc[8];
    #pragma unroll
    for (int j = 0; j < 8; ++j) acc[j] = (f32x4){0.f, 0.f, 0.f, 0.f};

    #pragma unroll 1
    for (int p = 0; p < 14; ++p) {
        int tap = 2 * p + tp;
        bf16x8 bfr = *(const bf16x8*)(sw + ((tap * 2 + ihl) * 16 + m) * 8);
        int tap_a = tap > 26 ? 26 : tap;
        int kx = tap_a / 9, r9 = tap_a % 9;
        int ky = r9 / 3, kz = r9 % 3;
        int xx = wv + kx;
        #pragma unroll
        for (int j = 0; j < 8; ++j) {
            int yy = j + ky;
            int zz = m + kz;
            bf16x8 afr = *(const bf16x8*)(sg + ((((ihl * 6 + xx) * 10 + yy) * 18) + zz) * 8);
            acc[j] = __builtin_amdgcn_mfma_f32_16x16x32_bf16(afr, bfr, acc[j], 0, 0, 0);
        }
    }

    const float bias = cb[h * 16 + m];
    unsigned short* cvb = convo + (long)bh * NG3 * NC;
    const int gx = x0 + wv;
    #pragma unroll
    for (int j = 0; j < 8; ++j) {
        int gy = y0 + j;
        long cellbase = (long)(gx * NG + gy) * NG + z0 + l4 * 4;
        #pragma unroll
        for (int r = 0; r < 4; ++r) {
            __hip_bfloat16 hb = __float2bfloat16(acc[j][r] + bias);
            cvb[(cellbase + r) * NC + m] = *(unsigned short*)&hb;
        }
    }
}

// ---------------------------------------------------------------------------
// Kernel 4: slice (weighted gather from bf16 convo) + BN + ReLU, out f32.
// ---------------------------------------------------------------------------
__global__ __launch_bounds__(256)
void k_slice(const unsigned short* __restrict__ convo, const float4* __restrict__ pre,
             const float* __restrict__ ag, const float* __restrict__ ab,
             const float* __restrict__ am, const float* __restrict__ av,
             float* __restrict__ out)
{
    __shared__ float asc[128], ash[128];
    const int tid = threadIdx.x;
    if (tid < 128) {
        float s = rsqrtf(av[tid] + KEPS) * ag[tid];
        asc[tid] = s;
        ash[tid] = ab[tid] - am[tid] * s;
    }
    __syncthreads();

    long t = (long)blockIdx.x * 256 + tid;
    long bh = t / NN;
    int n = (int)(t % NN);
    int b = (int)(bh >> 3), h = (int)(bh & 7);
    const unsigned short* g = convo + bh * (long)NG3 * NC;

    float4 r = pre[t];
    int ibase = __float_as_int(r.x);
    float fx = r.y, fy = r.z, fz = r.w;
    float gx = 1.f - fx, gy = 1.f - fy, gz = 1.f - fz;
    const float ws8[8] = {gx*gy*gz, gx*gy*fz, gx*fy*gz, gx*fy*fz,
                          fx*gy*gz, fx*gy*fz, fx*fy*gz, fx*fy*fz};
    const int offs8[8] = {0, 1, NG, NG + 1, NG*NG, NG*NG + 1, NG*NG + NG, NG*NG + NG + 1};

    float acc[NC];
    #pragma unroll
    for (int c = 0; c < NC; ++c) acc[c] = 0.f;
    #pragma unroll
    for (int ci = 0; ci < 8; ++ci) {
        float w = ws8[ci];
        const uint4* gc = (const uint4*)(g + (long)(ibase + offs8[ci]) * NC);
        uint4 u0 = gc[0], u1 = gc[1];
        acc[0]  = fmaf(w, bf_lo(u0.x), acc[0]);
        acc[1]  = fmaf(w, bf_hi(u0.x), acc[1]);
        acc[2]  = fmaf(w, bf_lo(u0.y), acc[2]);
        acc[3]  = fmaf(w, bf_hi(u0.y), acc[3]);
        acc[4]  = fmaf(w, bf_lo(u0.z), acc[4]);
        acc[5]  = fmaf(w, bf_hi(u0.z), acc[5]);
        acc[6]  = fmaf(w, bf_lo(u0.w), acc[6]);
        acc[7]  = fmaf(w, bf_hi(u0.w), acc[7]);
        acc[8]  = fmaf(w, bf_lo(u1.x), acc[8]);
        acc[9]  = fmaf(w, bf_hi(u1.x), acc[9]);
        acc[10] = fmaf(w, bf_lo(u1.y), acc[10]);
        acc[11] = fmaf(w, bf_hi(u1.y), acc[11]);
        acc[12] = fmaf(w, bf_lo(u1.z), acc[12]);
        acc[13] = fmaf(w, bf_hi(u1.z), acc[13]);
        acc[14] = fmaf(w, bf_lo(u1.w), acc[14]);
        acc[15] = fmaf(w, bf_hi(u1.w), acc[15]);
    }
    float* ob = out + ((long)b * 128 + h * 16) * NN + n;
    #pragma unroll
    for (int c = 0; c < NC; ++c) {
        float rr = fmaf(acc[c], asc[h * 16 + c], ash[h * 16 + c]);
        ob[(long)c * NN] = fmaxf(rr, 0.f);
    }
}

// ---------------------------------------------------------------------------
extern "C" void kernel_launch(void* const* d_in, const int* in_sizes, int n_in,
                              void* d_out, int out_size, void* d_ws, size_t ws_size,
                              hipStream_t stream)
{
    (void)in_sizes; (void)n_in; (void)out_size; (void)ws_size;
    const float* x    = (const float*)d_in[0];
    const float* orig = (const float*)d_in[1];
    const float* wkv  = (const float*)d_in[2];
    const float* kg   = (const float*)d_in[3];
    const float* kb   = (const float*)d_in[4];
    const float* km   = (const float*)d_in[5];
    const float* kvv  = (const float*)d_in[6];
    const float* vg   = (const float*)d_in[7];
    const float* vb   = (const float*)d_in[8];
    const float* vm   = (const float*)d_in[9];
    const float* vv   = (const float*)d_in[10];
    const float* Wt   = (const float*)d_in[11];
    const float* bt   = (const float*)d_in[12];
    const float* cw   = (const float*)d_in[13];
    const float* cb   = (const float*)d_in[14];
    const float* ag   = (const float*)d_in[15];
    const float* ab   = (const float*)d_in[16];
    const float* am   = (const float*)d_in[17];
    const float* av   = (const float*)d_in[18];

    char* ws = (char*)d_ws;
    float4*         pre       = (float4*)        (ws);                 //  8,388,608
    int*            hist      = (int*)           (ws + 8388608);       //  4,194,304
    int*            offs      = (int*)           (ws + 12582912);      //  4,194,304
    int*            offs_live = (int*)           (ws + 16777216);      //  4,194,304
    unsigned short* valb      = (unsigned short*)(ws + 20971520);      // 16,777,216 -> end 37,748,736
    uint4*          rec       = (uint4*)         (ws + 37748736);      // 25,165,824 -> end 62,914,560
    unsigned short* gridb     = (unsigned short*)(ws + 62914560);      // 33,554,432 -> end 96,468,992
    unsigned short* wpre      = (unsigned short*)(ws + 96468992);      //    114,688 -> end 96,583,680
    unsigned short* convo     = (unsigned short*)(ws + 20971520);      // 33,554,432 (alias valb+rec, dead by k_conv4)

    hipMemsetAsync(hist, 0, (size_t)NB * NH * NG3 * sizeof(int), stream);

    k_wprep<<<dim3(NH), dim3(256), 0, stream>>>(cw, wpre);

    k_front2<<<dim3(NB * 64), dim3(256), 0, stream>>>(
        x, orig, wkv, kg, kb, km, kvv, vg, vb, vm, vv, Wt, bt, valb, pre, hist);

    k_scan_cells<<<dim3(NB * NH), dim3(1024), 0, stream>>>(hist, offs, offs_live);

    k_scatter2<<<dim3((NB * NH * NN) / 256), dim3(256), 0, stream>>>(
        pre, valb, offs_live, rec);

    k_splat5<<<dim3(NB * NH * NG), dim3(1024), 0, stream>>>(rec, hist, offs, gridb);

    k_conv4<<<dim3(NB * NH * 64), dim3(256), 0, stream>>>(gridb, wpre, cb, convo);

    k_slice<<<dim3((NB * NH * NN) / 256), dim3(256), 0, stream>>>(
        convo, pre, ag, ab, am, av, (float*)d_out);
}

// Round 13
// 208.870 us; speedup vs baseline: 6.0477x; 1.0919x over previous
//
#include <hip/hip_runtime.h>
#include <hip/hip_bf16.h>

#define NB  4
#define NH  8
#define NC  16
#define ND  64
#define NN  16384
#define NG  32
#define NG3 32768
#define NKV 152
#define KEPS 1e-5f
#define TN  256   // points per k_front2 block

typedef __attribute__((ext_vector_type(8))) short bf16x8;
typedef __attribute__((ext_vector_type(4))) float f32x4;

__device__ __forceinline__ unsigned pack_bf2(float lo, float hi) {
    __hip_bfloat16 a = __float2bfloat16(lo);
    __hip_bfloat16 b = __float2bfloat16(hi);
    return (unsigned)(*(unsigned short*)&a) | ((unsigned)(*(unsigned short*)&b) << 16);
}
__device__ __forceinline__ float bf_lo(unsigned u) { return __uint_as_float(u << 16); }
__device__ __forceinline__ float bf_hi(unsigned u) { return __uint_as_float(u & 0xffff0000u); }

// ---------------------------------------------------------------------------
// Kernel 1: front — keys fp32 VALU, values bf16 MFMA; values stored BF16.
// ---------------------------------------------------------------------------
__global__ __launch_bounds__(256)
void k_front2(const float* __restrict__ x,      // [B,D,N]
              const float* __restrict__ orig,   // [B,3,N]
              const float* __restrict__ wkv,    // [152,64]
              const float* __restrict__ kg, const float* __restrict__ kb,
              const float* __restrict__ km, const float* __restrict__ kvv,
              const float* __restrict__ vg, const float* __restrict__ vb,
              const float* __restrict__ vm, const float* __restrict__ vv,
              const float* __restrict__ Wt,     // [8,3,3]
              const float* __restrict__ bt,     // [8,3]
              unsigned short* __restrict__ valb, // [B,H,N,C] bf16
              float4* __restrict__ pre,         // [B,H,N]
              int* __restrict__ hist)           // [B*H*32768]
{
    __shared__ unsigned short xb[TN * 72];      // bf16 x tile [n][d], pitch 72
    __shared__ float wk[24 * ND];
    __shared__ float ksc[24], ksh[24], vsc[128], vsh[128], wts[72], bts[24];
    const int tid = threadIdx.x;
    const int b  = blockIdx.x >> 6;
    const int n0 = (blockIdx.x & 63) * TN;
    const int n  = n0 + tid;

    for (int i = tid; i < 24 * ND; i += 256) wk[i] = wkv[i];
    if (tid < 24) {
        float s = rsqrtf(kvv[tid] + KEPS) * kg[tid];
        ksc[tid] = s;
        ksh[tid] = kb[tid] - km[tid] * s;
    }
    if (tid < 128) {
        float s = rsqrtf(vv[tid] + KEPS) * vg[tid];
        vsc[tid] = s;
        vsh[tid] = vb[tid] - vm[tid] * s;
    }
    if (tid < 72) wts[tid] = Wt[tid];
    if (tid < 24) bts[tid] = bt[tid];

    float xr[ND];
    #pragma unroll
    for (int d = 0; d < ND; ++d)
        xr[d] = x[((long)b * ND + d) * NN + n];
    #pragma unroll
    for (int j = 0; j < 8; ++j) {
        uint4 q;
        q.x = pack_bf2(xr[8*j+0], xr[8*j+1]);
        q.y = pack_bf2(xr[8*j+2], xr[8*j+3]);
        q.z = pack_bf2(xr[8*j+4], xr[8*j+5]);
        q.w = pack_bf2(xr[8*j+6], xr[8*j+7]);
        *(uint4*)(xb + tid * 72 + j * 8) = q;
    }
    __syncthreads();

    float ko[24];
    #pragma unroll 1
    for (int o = 0; o < 24; o += 4) {
        float s0 = 0.f, s1 = 0.f, s2 = 0.f, s3 = 0.f;
        #pragma unroll
        for (int dq = 0; dq < 16; ++dq) {
            const float4 w0 = *(const float4*)&wk[(o + 0) * ND + dq * 4];
            const float4 w1 = *(const float4*)&wk[(o + 1) * ND + dq * 4];
            const float4 w2 = *(const float4*)&wk[(o + 2) * ND + dq * 4];
            const float4 w3 = *(const float4*)&wk[(o + 3) * ND + dq * 4];
            float a0 = xr[4*dq], a1 = xr[4*dq+1], a2 = xr[4*dq+2], a3 = xr[4*dq+3];
            s0 = fmaf(w0.x, a0, fmaf(w0.y, a1, fmaf(w0.z, a2, fmaf(w0.w, a3, s0))));
            s1 = fmaf(w1.x, a0, fmaf(w1.y, a1, fmaf(w1.z, a2, fmaf(w1.w, a3, s1))));
            s2 = fmaf(w2.x, a0, fmaf(w2.y, a1, fmaf(w2.z, a2, fmaf(w2.w, a3, s2))));
            s3 = fmaf(w3.x, a0, fmaf(w3.y, a1, fmaf(w3.z, a2, fmaf(w3.w, a3, s3))));
        }
        ko[o + 0] = fmaf(s0, ksc[o + 0], ksh[o + 0]);
        ko[o + 1] = fmaf(s1, ksc[o + 1], ksh[o + 1]);
        ko[o + 2] = fmaf(s2, ksc[o + 2], ksh[o + 2]);
        ko[o + 3] = fmaf(s3, ksc[o + 3], ksh[o + 3]);
    }

    {
        const int lane = tid & 63;
        const int wv = tid >> 6;
        const int l15 = lane & 15, l4 = lane >> 4;

        bf16x8 bfr[2][2];
        float bsc[2], bsh[2];
        #pragma unroll
        for (int p = 0; p < 2; ++p) {
            int oc = (2 * wv + p) * 16 + l15;
            bsc[p] = vsc[oc];
            bsh[p] = vsh[oc];
            #pragma unroll
            for (int ks = 0; ks < 2; ++ks) {
                const float* wp = wkv + (24 + oc) * ND + ks * 32 + l4 * 8;
                float4 a = *(const float4*)wp;
                float4 c = *(const float4*)(wp + 4);
                uint4 q;
                q.x = pack_bf2(a.x, a.y); q.y = pack_bf2(a.z, a.w);
                q.z = pack_bf2(c.x, c.y); q.w = pack_bf2(c.z, c.w);
                bfr[p][ks] = *(bf16x8*)&q;
            }
        }

        #pragma unroll 1
        for (int nb = 0; nb < 16; ++nb) {
            bf16x8 a0 = *(const bf16x8*)(xb + (nb * 16 + l15) * 72 + l4 * 8);
            bf16x8 a1 = *(const bf16x8*)(xb + (nb * 16 + l15) * 72 + 32 + l4 * 8);
            #pragma unroll
            for (int p = 0; p < 2; ++p) {
                f32x4 acc = (f32x4){0.f, 0.f, 0.f, 0.f};
                acc = __builtin_amdgcn_mfma_f32_16x16x32_bf16(a0, bfr[p][0], acc, 0, 0, 0);
                acc = __builtin_amdgcn_mfma_f32_16x16x32_bf16(a1, bfr[p][1], acc, 0, 0, 0);
                int h = 2 * wv + p;
                unsigned short* vp = valb + (((long)(b * NH + h) * NN + n0 + nb * 16 + l4 * 4) * NC) + l15;
                #pragma unroll
                for (int r = 0; r < 4; ++r) {
                    __hip_bfloat16 hb = __float2bfloat16(fmaf(acc[r], bsc[p], bsh[p]));
                    vp[r * NC] = *(unsigned short*)&hb;
                }
            }
        }
    }

    const float o0 = orig[((long)b * 3 + 0) * NN + n];
    const float o1 = orig[((long)b * 3 + 1) * NN + n];
    const float o2 = orig[((long)b * 3 + 2) * NN + n];

    #pragma unroll 1
    for (int h = 0; h < NH; ++h) {
        float p0 = o0 + ko[h * 3 + 0];
        float p1 = o1 + ko[h * 3 + 1];
        float p2 = o2 + ko[h * 3 + 2];
        float t0 = fmaf(wts[h * 9 + 0], p0, fmaf(wts[h * 9 + 1], p1, fmaf(wts[h * 9 + 2], p2, bts[h * 3 + 0])));
        float t1 = fmaf(wts[h * 9 + 3], p0, fmaf(wts[h * 9 + 4], p1, fmaf(wts[h * 9 + 5], p2, bts[h * 3 + 1])));
        float t2 = fmaf(wts[h * 9 + 6], p0, fmaf(wts[h * 9 + 7], p1, fmaf(wts[h * 9 + 8], p2, bts[h * 3 + 2])));
        float l0 = tanhf(t0), l1 = tanhf(t1), l2 = tanhf(t2);
        float pos0 = (l0 + 1.f) * 15.5f;
        float pos1 = (l1 + 1.f) * 15.5f;
        float pos2 = (l2 + 1.f) * 15.5f;
        float b0 = fminf(fmaxf(floorf(pos0), 0.f), 30.f);
        float b1 = fminf(fmaxf(floorf(pos1), 0.f), 30.f);
        float b2 = fminf(fmaxf(floorf(pos2), 0.f), 30.f);
        int ix = (int)b0, iy = (int)b1, iz = (int)b2;
        float fx = pos0 - b0, fy = pos1 - b1, fz = pos2 - b2;
        int ibase = (ix * NG + iy) * NG + iz;
        float4 pr;
        pr.x = __int_as_float(ibase);
        pr.y = fx; pr.z = fy; pr.w = fz;
        int bh = b * NH + h;
        pre[(long)bh * NN + n] = pr;
        atomicAdd(&hist[bh * NG3 + ibase], 1);
    }
}

// ---------------------------------------------------------------------------
// Kernel 1b: per-bh exclusive prefix scan over 32768 cell counts.
// ---------------------------------------------------------------------------
__global__ __launch_bounds__(1024)
void k_scan_cells(const int* __restrict__ hist, int* __restrict__ offs,
                  int* __restrict__ offs_live)
{
    __shared__ int tsum[1024];
    const int bh = blockIdx.x, tid = threadIdx.x;
    const int* hb = hist + (long)bh * NG3;

    int s = 0;
    #pragma unroll 4
    for (int j = 0; j < 32; ++j) s += hb[tid * 32 + j];
    tsum[tid] = s;
    __syncthreads();
    for (int d = 1; d < 1024; d <<= 1) {
        int t = (tid >= d) ? tsum[tid - d] : 0;
        __syncthreads();
        tsum[tid] += t;
        __syncthreads();
    }
    int run = bh * NN + tsum[tid] - s;
    int* ob = offs + (long)bh * NG3;
    int* lb = offs_live + (long)bh * NG3;
    #pragma unroll 4
    for (int j = 0; j < 32; ++j) {
        int c = tid * 32 + j;
        ob[c] = run;
        lb[c] = run;
        run += hb[c];
    }
}

// ---------------------------------------------------------------------------
// Kernel 1c: scatter records into cell order. Record = 3 x uint4 = 48 B.
// ---------------------------------------------------------------------------
__global__ __launch_bounds__(256)
void k_scatter2(const float4* __restrict__ pre, const unsigned short* __restrict__ valb,
                int* __restrict__ offs_live, uint4* __restrict__ rec)
{
    long t = (long)blockIdx.x * 256 + threadIdx.x;
    float4 r = pre[t];
    int ibase = __float_as_int(r.x);
    int bh = (int)(t >> 14);
    int slot = atomicAdd(&offs_live[(long)bh * NG3 + ibase], 1);
    const uint4* vp = (const uint4*)(valb + t * NC);
    uint4 v0 = vp[0], v1 = vp[1];
    uint4* out = rec + (long)slot * 3;
    out[0] = make_uint4(__float_as_uint(r.y), __float_as_uint(r.z), __float_as_uint(r.w), 0u);
    out[1] = v0;
    out[2] = v1;
}

// ---------------------------------------------------------------------------
// Kernel 2: splat — LDS-staged chunks, merged-z segments (2 per dy,dx pass
// instead of 4): cells (cy,z-1),(cy,z) are adjacent in sort order, so one
// contiguous walk with wz = (r < split) ? fz : 1-fz. Atomic-free, BF16 out.
// ---------------------------------------------------------------------------
__global__ __launch_bounds__(1024)
void k_splat6(const uint4* __restrict__ rec, const int* __restrict__ hist,
              const int* __restrict__ offs, unsigned short* __restrict__ gridb)
{
    __shared__ uint4 sr[1024 * 3];   // 48 KB chunk
    const int tid = threadIdx.x;
    const int rx = blockIdx.x & 31;
    const int bh = blockIdx.x >> 5;
    const int y = tid >> 5, z = tid & 31;
    const int zlo = (z > 0) ? z - 1 : 0;

    const int* hb = hist + (long)bh * NG3;
    const int* ob = offs + (long)bh * NG3;

    float acc[16];
    #pragma unroll
    for (int c = 0; c < 16; ++c) acc[c] = 0.f;

    #pragma unroll
    for (int dx = 0; dx < 2; ++dx) {
        int cx = rx - dx;
        if (cx < 0) continue;                       // block-uniform
        int st[2], sp[2], en[2];
        #pragma unroll
        for (int dy = 0; dy < 2; ++dy) {
            int cy = y - dy;
            bool valid = cy >= 0;
            int base = (cx << 10) | (cy << 5);
            int c1 = base | zlo;
            int c2 = base | z;
            st[dy] = valid ? ob[c1] : 0;
            sp[dy] = valid ? ob[c2] : 0;
            en[dy] = valid ? sp[dy] + hb[c2] : 0;
        }
        int pc0 = cx << 10;
        int ps = ob[pc0];                           // uniform plane bounds
        int pe = ob[pc0 + 1023] + hb[pc0 + 1023];
        for (int cs = ps; cs < pe; cs += 1024) {
            int ce = min(cs + 1024, pe);
            __syncthreads();
            if (tid < ce - cs) {
                const uint4* R = rec + (long)(cs + tid) * 3;
                sr[tid * 3 + 0] = R[0];
                sr[tid * 3 + 1] = R[1];
                sr[tid * 3 + 2] = R[2];
            }
            __syncthreads();
            #pragma unroll
            for (int dy = 0; dy < 2; ++dy) {
                int ls = max(st[dy], cs);
                int le = min(en[dy], ce);
                int split = sp[dy];
                for (int r = ls; r < le; ++r) {
                    int k = (r - cs) * 3;
                    uint4 q0 = sr[k], q1 = sr[k + 1], q2 = sr[k + 2];
                    float fx = __uint_as_float(q0.x);
                    float fy = __uint_as_float(q0.y);
                    float fz = __uint_as_float(q0.z);
                    float wx = dx ? fx : 1.f - fx;
                    float wy = dy ? fy : 1.f - fy;
                    float wz = (r < split) ? fz : 1.f - fz;
                    float w = wx * wy * wz;
                    acc[0]  = fmaf(w, bf_lo(q1.x), acc[0]);
                    acc[1]  = fmaf(w, bf_hi(q1.x), acc[1]);
                    acc[2]  = fmaf(w, bf_lo(q1.y), acc[2]);
                    acc[3]  = fmaf(w, bf_hi(q1.y), acc[3]);
                    acc[4]  = fmaf(w, bf_lo(q1.z), acc[4]);
                    acc[5]  = fmaf(w, bf_hi(q1.z), acc[5]);
                    acc[6]  = fmaf(w, bf_lo(q1.w), acc[6]);
                    acc[7]  = fmaf(w, bf_hi(q1.w), acc[7]);
                    acc[8]  = fmaf(w, bf_lo(q2.x), acc[8]);
                    acc[9]  = fmaf(w, bf_hi(q2.x), acc[9]);
                    acc[10] = fmaf(w, bf_lo(q2.y), acc[10]);
                    acc[11] = fmaf(w, bf_hi(q2.y), acc[11]);
                    acc[12] = fmaf(w, bf_lo(q2.z), acc[12]);
                    acc[13] = fmaf(w, bf_hi(q2.z), acc[13]);
                    acc[14] = fmaf(w, bf_lo(q2.w), acc[14]);
                    acc[15] = fmaf(w, bf_hi(q2.w), acc[15]);
                }
            }
        }
    }

    uint4 q0, q1;
    q0.x = pack_bf2(acc[0],  acc[1]);  q0.y = pack_bf2(acc[2],  acc[3]);
    q0.z = pack_bf2(acc[4],  acc[5]);  q0.w = pack_bf2(acc[6],  acc[7]);
    q1.x = pack_bf2(acc[8],  acc[9]);  q1.y = pack_bf2(acc[10], acc[11]);
    q1.z = pack_bf2(acc[12], acc[13]); q1.w = pack_bf2(acc[14], acc[15]);
    uint4* gb = (uint4*)(gridb + ((long)bh * NG3 + (rx << 10) + tid) * NC);
    gb[0] = q0;
    gb[1] = q1;
}

// ---------------------------------------------------------------------------
// Kernel 3a: one-time weight conversion into conv's sw layout (bf16).
// wpre[h][e], e = tap*256 + ihl*128 + oc*8 + icl; tap 27 zero-padded.
// ---------------------------------------------------------------------------
__global__ __launch_bounds__(256)
void k_wprep(const float* __restrict__ cw, unsigned short* __restrict__ wpre)
{
    const int h = blockIdx.x;
    for (int e = threadIdx.x; e < 7168; e += 256) {
        int icl = e & 7, oc = (e >> 3) & 15, ihl = (e >> 7) & 1, tap = e >> 8;
        int ic = ihl * 8 + icl;
        float wv = (tap < 27) ? cw[(h * 16 + oc) * 432 + ic * 27 + tap] : 0.f;
        __hip_bfloat16 hbw = __float2bfloat16(wv);
        wpre[h * 7168 + e] = *(unsigned short*)&hbw;
    }
}

// ---------------------------------------------------------------------------
// Kernel 3: grouped 3x3x3 conv via BF16 MFMA. Block = (bh, xt, yt):
// 4x8x32 tile, 512 thr = 8 waves (4 x-slices x 2 z-halves).
// sg [ihl2][xx6][yy10][zz34][8ic] = 65280 B + sw 14336 B -> 2 blocks/CU.
// Phase loop FULLY UNROLLED: tap->(kx,ky,kz) and all LDS offsets fold to
// immediates; per phase only 1 cndmask+add (tp-half select).
// ---------------------------------------------------------------------------
__global__ __launch_bounds__(512)
void k_conv5(const unsigned short* __restrict__ gridb,
             const unsigned short* __restrict__ wpre,
             const float* __restrict__ cb,
             unsigned short* __restrict__ convo)
{
    __shared__ unsigned short sg[2 * 6 * 10 * 34 * 8];  // 65280 B
    __shared__ unsigned short sw[28 * 2 * 16 * 8];      // 14336 B
    const int tid = threadIdx.x;
    const int bid = blockIdx.x;
    const int yt = bid & 3, xt = (bid >> 2) & 7, bh = bid >> 5;
    const int h = bh & 7;
    const int x0 = xt * 4, y0 = yt * 8;

    {   // weights: coalesced uint4 copy of pre-converted layout
        const uint4* wsrc = (const uint4*)(wpre + (long)h * 7168);
        uint4* wdst = (uint4*)sw;
        for (int e = tid; e < 896; e += 512) wdst[e] = wsrc[e];
    }
    // grid tile with halo (4080 uint4 chunks)
    const unsigned short* gb = gridb + (long)bh * NG3 * 16;
    for (int e = tid; e < 2 * 6 * 10 * 34; e += 512) {
        int ihl = e & 1, c = e >> 1;           // c = xx*340 + yy*34 + zz
        int zz = c % 34, yu = c / 34;
        int yy = yu % 10, xx = yu / 10;
        int gx = x0 + xx - 1, gy = y0 + yy - 1, gz = zz - 1;
        uint4 v = make_uint4(0, 0, 0, 0);
        if ((unsigned)gx < NG && (unsigned)gy < NG && (unsigned)gz < NG)
            v = *(const uint4*)(gb + (((gx * NG + gy) * NG + gz) * 16 + ihl * 8));
        *(uint4*)(sg + ((((ihl * 6 + xx) * 10 + yy) * 34) + zz) * 8) = v;
    }
    __syncthreads();

    const int lane = tid & 63;
    const int w  = tid >> 6;          // wave 0..7
    const int wv = w & 3;             // x-slice
    const int zh = w >> 2;            // z-half
    const int m  = lane & 15;
    const int l4 = lane >> 4;
    const int ihl = l4 & 1;
    const int tp = l4 >> 1;

    // lane-constant byte bases
    const int aLaneByte = ((((ihl * 6 + wv) * 10) * 34) + zh * 16 + m) * 16;
    const int bLaneByte = l4 * 256 + m * 16;
    const char* sgb = (const char*)sg;
    const char* swb = (const char*)sw;

    f32x4 acc[8];
    #pragma unroll
    for (int j = 0; j < 8; ++j) acc[j] = (f32x4){0.f, 0.f, 0.f, 0.f};

    #pragma unroll
    for (int p = 0; p < 14; ++p) {
        const int t0 = 2 * p, t1 = 2 * p + 1;
        const int ta0 = (t0 > 26) ? 26 : t0, ta1 = (t1 > 26) ? 26 : t1;
        const int off0 = ((ta0 / 9) * 340 + ((ta0 % 9) / 3) * 34 + (ta0 % 3)) * 16;
        const int off1 = ((ta1 / 9) * 340 + ((ta1 % 9) / 3) * 34 + (ta1 % 3)) * 16;
        const int aoff = aLaneByte + (tp ? off1 : off0);
        bf16x8 bfr = *(const bf16x8*)(swb + p * 1024 + bLaneByte);
        #pragma unroll
        for (int j = 0; j < 8; ++j) {
            bf16x8 afr = *(const bf16x8*)(sgb + aoff + j * 544);
            acc[j] = __builtin_amdgcn_mfma_f32_16x16x32_bf16(afr, bfr, acc[j], 0, 0, 0);
        }
    }

    const float bias = cb[h * 16 + m];
    unsigned short* cvb = convo + (long)bh * NG3 * NC;
    const int gx = x0 + wv;
    const int z0 = zh * 16;
    #pragma unroll
    for (int j = 0; j < 8; ++j) {
        int gy = y0 + j;
        long cellbase = (long)(gx * NG + gy) * NG + z0 + l4 * 4;
        #pragma unroll
        for (int r = 0; r < 4; ++r) {
            __hip_bfloat16 hb = __float2bfloat16(acc[j][r] + bias);
            cvb[(cellbase + r) * NC + m] = *(unsigned short*)&hb;
        }
    }
}

// ---------------------------------------------------------------------------
// Kernel 4: slice (weighted gather from bf16 convo) + BN + ReLU, out f32.
// ---------------------------------------------------------------------------
__global__ __launch_bounds__(256)
void k_slice(const unsigned short* __restrict__ convo, const float4* __restrict__ pre,
             const float* __restrict__ ag, const float* __restrict__ ab,
             const float* __restrict__ am, const float* __restrict__ av,
             float* __restrict__ out)
{
    __shared__ float asc[128], ash[128];
    const int tid = threadIdx.x;
    if (tid < 128) {
        float s = rsqrtf(av[tid] + KEPS) * ag[tid];
        asc[tid] = s;
        ash[tid] = ab[tid] - am[tid] * s;
    }
    __syncthreads();

    long t = (long)blockIdx.x * 256 + tid;
    long bh = t / NN;
    int n = (int)(t % NN);
    int b = (int)(bh >> 3), h = (int)(bh & 7);
    const unsigned short* g = convo + bh * (long)NG3 * NC;

    float4 r = pre[t];
    int ibase = __float_as_int(r.x);
    float fx = r.y, fy = r.z, fz = r.w;
    float gx = 1.f - fx, gy = 1.f - fy, gz = 1.f - fz;
    const float ws8[8] = {gx*gy*gz, gx*gy*fz, gx*fy*gz, gx*fy*fz,
                          fx*gy*gz, fx*gy*fz, fx*fy*gz, fx*fy*fz};
    const int offs8[8] = {0, 1, NG, NG + 1, NG*NG, NG*NG + 1, NG*NG + NG, NG*NG + NG + 1};

    float acc[NC];
    #pragma unroll
    for (int c = 0; c < NC; ++c) acc[c] = 0.f;
    #pragma unroll
    for (int ci = 0; ci < 8; ++ci) {
        float w = ws8[ci];
        const uint4* gc = (const uint4*)(g + (long)(ibase + offs8[ci]) * NC);
        uint4 u0 = gc[0], u1 = gc[1];
        acc[0]  = fmaf(w, bf_lo(u0.x), acc[0]);
        acc[1]  = fmaf(w, bf_hi(u0.x), acc[1]);
        acc[2]  = fmaf(w, bf_lo(u0.y), acc[2]);
        acc[3]  = fmaf(w, bf_hi(u0.y), acc[3]);
        acc[4]  = fmaf(w, bf_lo(u0.z), acc[4]);
        acc[5]  = fmaf(w, bf_hi(u0.z), acc[5]);
        acc[6]  = fmaf(w, bf_lo(u0.w), acc[6]);
        acc[7]  = fmaf(w, bf_hi(u0.w), acc[7]);
        acc[8]  = fmaf(w, bf_lo(u1.x), acc[8]);
        acc[9]  = fmaf(w, bf_hi(u1.x), acc[9]);
        acc[10] = fmaf(w, bf_lo(u1.y), acc[10]);
        acc[11] = fmaf(w, bf_hi(u1.y), acc[11]);
        acc[12] = fmaf(w, bf_lo(u1.z), acc[12]);
        acc[13] = fmaf(w, bf_hi(u1.z), acc[13]);
        acc[14] = fmaf(w, bf_lo(u1.w), acc[14]);
        acc[15] = fmaf(w, bf_hi(u1.w), acc[15]);
    }
    float* ob = out + ((long)b * 128 + h * 16) * NN + n;
    #pragma unroll
    for (int c = 0; c < NC; ++c) {
        float rr = fmaf(acc[c], asc[h * 16 + c], ash[h * 16 + c]);
        ob[(long)c * NN] = fmaxf(rr, 0.f);
    }
}

// ---------------------------------------------------------------------------
extern "C" void kernel_launch(void* const* d_in, const int* in_sizes, int n_in,
                              void* d_out, int out_size, void* d_ws, size_t ws_size,
                              hipStream_t stream)
{
    (void)in_sizes; (void)n_in; (void)out_size; (void)ws_size;
    const float* x    = (const float*)d_in[0];
    const float* orig = (const float*)d_in[1];
    const float* wkv  = (const float*)d_in[2];
    const float* kg   = (const float*)d_in[3];
    const float* kb   = (const float*)d_in[4];
    const float* km   = (const float*)d_in[5];
    const float* kvv  = (const float*)d_in[6];
    const float* vg   = (const float*)d_in[7];
    const float* vb   = (const float*)d_in[8];
    const float* vm   = (const float*)d_in[9];
    const float* vv   = (const float*)d_in[10];
    const float* Wt   = (const float*)d_in[11];
    const float* bt   = (const float*)d_in[12];
    const float* cw   = (const float*)d_in[13];
    const float* cb   = (const float*)d_in[14];
    const float* ag   = (const float*)d_in[15];
    const float* ab   = (const float*)d_in[16];
    const float* am   = (const float*)d_in[17];
    const float* av   = (const float*)d_in[18];

    char* ws = (char*)d_ws;
    float4*         pre       = (float4*)        (ws);                 //  8,388,608
    int*            hist      = (int*)           (ws + 8388608);       //  4,194,304
    int*            offs      = (int*)           (ws + 12582912);      //  4,194,304
    int*            offs_live = (int*)           (ws + 16777216);      //  4,194,304
    unsigned short* valb      = (unsigned short*)(ws + 20971520);      // 16,777,216 -> end 37,748,736
    uint4*          rec       = (uint4*)         (ws + 37748736);      // 25,165,824 -> end 62,914,560
    unsigned short* gridb     = (unsigned short*)(ws + 62914560);      // 33,554,432 -> end 96,468,992
    unsigned short* wpre      = (unsigned short*)(ws + 96468992);      //    114,688 -> end 96,583,680
    unsigned short* convo     = (unsigned short*)(ws + 20971520);      // 33,554,432 (alias valb+rec, dead by k_conv5)

    hipMemsetAsync(hist, 0, (size_t)NB * NH * NG3 * sizeof(int), stream);

    k_wprep<<<dim3(NH), dim3(256), 0, stream>>>(cw, wpre);

    k_front2<<<dim3(NB * 64), dim3(256), 0, stream>>>(
        x, orig, wkv, kg, kb, km, kvv, vg, vb, vm, vv, Wt, bt, valb, pre, hist);

    k_scan_cells<<<dim3(NB * NH), dim3(1024), 0, stream>>>(hist, offs, offs_live);

    k_scatter2<<<dim3((NB * NH * NN) / 256), dim3(256), 0, stream>>>(
        pre, valb, offs_live, rec);

    k_splat6<<<dim3(NB * NH * NG), dim3(1024), 0, stream>>>(rec, hist, offs, gridb);

    k_conv5<<<dim3(NB * NH * 32), dim3(512), 0, stream>>>(gridb, wpre, cb, convo);

    k_slice<<<dim3((NB * NH * NN) / 256), dim3(256), 0, stream>>>(
        convo, pre, ag, ab, am, av, (float*)d_out);
}

// Round 14
// 208.753 us; speedup vs baseline: 6.0511x; 1.0006x over previous
//
#include <hip/hip_runtime.h>
#include <hip/hip_bf16.h>

#define NB  4
#define NH  8
#define NC  16
#define ND  64
#define NN  16384
#define NG  32
#define NG3 32768
#define NKV 152
#define KEPS 1e-5f
#define TN  256   // points per k_front3 block

typedef __attribute__((ext_vector_type(8))) short bf16x8;
typedef __attribute__((ext_vector_type(4))) float f32x4;

__device__ __forceinline__ unsigned pack_bf2(float lo, float hi) {
    __hip_bfloat16 a = __float2bfloat16(lo);
    __hip_bfloat16 b = __float2bfloat16(hi);
    return (unsigned)(*(unsigned short*)&a) | ((unsigned)(*(unsigned short*)&b) << 16);
}
__device__ __forceinline__ float bf_lo(unsigned u) { return __uint_as_float(u << 16); }
__device__ __forceinline__ float bf_hi(unsigned u) { return __uint_as_float(u & 0xffff0000u); }

// ---------------------------------------------------------------------------
// Kernel 0: fast zero of hist (4 MB) — the runtime's fillBuffer ran at
// 100 GB/s (42 us); this runs at streaming BW (~1.5 us).
// ---------------------------------------------------------------------------
__global__ __launch_bounds__(256)
void k_zero(uint4* __restrict__ p)
{
    p[(long)blockIdx.x * 256 + threadIdx.x] = make_uint4(0, 0, 0, 0);
}

// ---------------------------------------------------------------------------
// Kernel 1: front — split into 2 head-group blocks per point-tile for 2x
// occupancy (512 blocks = 2/CU = 2 waves/SIMD). Block handles heads
// hg*4..hg*4+3: 12 key rows fp32, 1 head/wave values-MFMA, 4-head lattice.
// ---------------------------------------------------------------------------
__global__ __launch_bounds__(256)
void k_front3(const float* __restrict__ x,      // [B,D,N]
              const float* __restrict__ orig,   // [B,3,N]
              const float* __restrict__ wkv,    // [152,64]
              const float* __restrict__ kg, const float* __restrict__ kb,
              const float* __restrict__ km, const float* __restrict__ kvv,
              const float* __restrict__ vg, const float* __restrict__ vb,
              const float* __restrict__ vm, const float* __restrict__ vv,
              const float* __restrict__ Wt,     // [8,3,3]
              const float* __restrict__ bt,     // [8,3]
              unsigned short* __restrict__ valb, // [B,H,N,C] bf16
              float4* __restrict__ pre,         // [B,H,N]
              int* __restrict__ hist)           // [B*H*32768]
{
    __shared__ unsigned short xb[TN * 72];      // bf16 x tile [n][d], pitch 72
    __shared__ float wk[12 * ND];               // this group's key rows
    __shared__ float ksc[12], ksh[12], vsc[64], vsh[64], wts[36], bts[12];
    const int tid = threadIdx.x;
    const int hg   = blockIdx.x & 1;            // head group: heads hg*4..hg*4+3
    const int tile = (blockIdx.x >> 1) & 63;
    const int b    = blockIdx.x >> 7;
    const int n0 = tile * TN;
    const int n  = n0 + tid;

    for (int i = tid; i < 12 * ND; i += 256) wk[i] = wkv[hg * 768 + i];
    if (tid < 12) {
        int ch = hg * 12 + tid;
        float s = rsqrtf(kvv[ch] + KEPS) * kg[ch];
        ksc[tid] = s;
        ksh[tid] = kb[ch] - km[ch] * s;
    }
    if (tid < 64) {
        int ch = hg * 64 + tid;
        float s = rsqrtf(vv[ch] + KEPS) * vg[ch];
        vsc[tid] = s;
        vsh[tid] = vb[ch] - vm[ch] * s;
    }
    if (tid < 36) wts[tid] = Wt[hg * 36 + tid];
    if (tid < 12) bts[tid] = bt[hg * 12 + tid];

    float xr[ND];
    #pragma unroll
    for (int d = 0; d < ND; ++d)
        xr[d] = x[((long)b * ND + d) * NN + n];
    #pragma unroll
    for (int j = 0; j < 8; ++j) {
        uint4 q;
        q.x = pack_bf2(xr[8*j+0], xr[8*j+1]);
        q.y = pack_bf2(xr[8*j+2], xr[8*j+3]);
        q.z = pack_bf2(xr[8*j+4], xr[8*j+5]);
        q.w = pack_bf2(xr[8*j+6], xr[8*j+7]);
        *(uint4*)(xb + tid * 72 + j * 8) = q;
    }
    __syncthreads();

    // keys: this group's 12 rows
    float ko[12];
    #pragma unroll 1
    for (int o = 0; o < 12; o += 4) {
        float s0 = 0.f, s1 = 0.f, s2 = 0.f, s3 = 0.f;
        #pragma unroll
        for (int dq = 0; dq < 16; ++dq) {
            const float4 w0 = *(const float4*)&wk[(o + 0) * ND + dq * 4];
            const float4 w1 = *(const float4*)&wk[(o + 1) * ND + dq * 4];
            const float4 w2 = *(const float4*)&wk[(o + 2) * ND + dq * 4];
            const float4 w3 = *(const float4*)&wk[(o + 3) * ND + dq * 4];
            float a0 = xr[4*dq], a1 = xr[4*dq+1], a2 = xr[4*dq+2], a3 = xr[4*dq+3];
            s0 = fmaf(w0.x, a0, fmaf(w0.y, a1, fmaf(w0.z, a2, fmaf(w0.w, a3, s0))));
            s1 = fmaf(w1.x, a0, fmaf(w1.y, a1, fmaf(w1.z, a2, fmaf(w1.w, a3, s1))));
            s2 = fmaf(w2.x, a0, fmaf(w2.y, a1, fmaf(w2.z, a2, fmaf(w2.w, a3, s2))));
            s3 = fmaf(w3.x, a0, fmaf(w3.y, a1, fmaf(w3.z, a2, fmaf(w3.w, a3, s3))));
        }
        ko[o + 0] = fmaf(s0, ksc[o + 0], ksh[o + 0]);
        ko[o + 1] = fmaf(s1, ksc[o + 1], ksh[o + 1]);
        ko[o + 2] = fmaf(s2, ksc[o + 2], ksh[o + 2]);
        ko[o + 3] = fmaf(s3, ksc[o + 3], ksh[o + 3]);
    }

    // values via MFMA: wave wv handles head hg*4+wv (16 oc)
    {
        const int lane = tid & 63;
        const int wv = tid >> 6;
        const int l15 = lane & 15, l4 = lane >> 4;
        const int h = hg * 4 + wv;
        const int ocg = h * 16 + l15;               // channel in [0,128)
        const float bsc = vsc[wv * 16 + l15];
        const float bsh = vsh[wv * 16 + l15];

        bf16x8 bfr[2];
        #pragma unroll
        for (int ks = 0; ks < 2; ++ks) {
            const float* wp = wkv + (24 + ocg) * ND + ks * 32 + l4 * 8;
            float4 a = *(const float4*)wp;
            float4 c = *(const float4*)(wp + 4);
            uint4 q;
            q.x = pack_bf2(a.x, a.y); q.y = pack_bf2(a.z, a.w);
            q.z = pack_bf2(c.x, c.y); q.w = pack_bf2(c.z, c.w);
            bfr[ks] = *(bf16x8*)&q;
        }

        #pragma unroll 1
        for (int nb = 0; nb < 16; ++nb) {
            bf16x8 a0 = *(const bf16x8*)(xb + (nb * 16 + l15) * 72 + l4 * 8);
            bf16x8 a1 = *(const bf16x8*)(xb + (nb * 16 + l15) * 72 + 32 + l4 * 8);
            f32x4 acc = (f32x4){0.f, 0.f, 0.f, 0.f};
            acc = __builtin_amdgcn_mfma_f32_16x16x32_bf16(a0, bfr[0], acc, 0, 0, 0);
            acc = __builtin_amdgcn_mfma_f32_16x16x32_bf16(a1, bfr[1], acc, 0, 0, 0);
            unsigned short* vp = valb + (((long)(b * NH + h) * NN + n0 + nb * 16 + l4 * 4) * NC) + l15;
            #pragma unroll
            for (int r = 0; r < 4; ++r) {
                __hip_bfloat16 hb = __float2bfloat16(fmaf(acc[r], bsc, bsh));
                vp[r * NC] = *(unsigned short*)&hb;
            }
        }
    }

    // lattice coords for this group's 4 heads
    const float o0 = orig[((long)b * 3 + 0) * NN + n];
    const float o1 = orig[((long)b * 3 + 1) * NN + n];
    const float o2 = orig[((long)b * 3 + 2) * NN + n];

    #pragma unroll 1
    for (int lh = 0; lh < 4; ++lh) {
        float p0 = o0 + ko[lh * 3 + 0];
        float p1 = o1 + ko[lh * 3 + 1];
        float p2 = o2 + ko[lh * 3 + 2];
        float t0 = fmaf(wts[lh * 9 + 0], p0, fmaf(wts[lh * 9 + 1], p1, fmaf(wts[lh * 9 + 2], p2, bts[lh * 3 + 0])));
        float t1 = fmaf(wts[lh * 9 + 3], p0, fmaf(wts[lh * 9 + 4], p1, fmaf(wts[lh * 9 + 5], p2, bts[lh * 3 + 1])));
        float t2 = fmaf(wts[lh * 9 + 6], p0, fmaf(wts[lh * 9 + 7], p1, fmaf(wts[lh * 9 + 8], p2, bts[lh * 3 + 2])));
        float l0 = tanhf(t0), l1 = tanhf(t1), l2 = tanhf(t2);
        float pos0 = (l0 + 1.f) * 15.5f;
        float pos1 = (l1 + 1.f) * 15.5f;
        float pos2 = (l2 + 1.f) * 15.5f;
        float b0 = fminf(fmaxf(floorf(pos0), 0.f), 30.f);
        float b1 = fminf(fmaxf(floorf(pos1), 0.f), 30.f);
        float b2 = fminf(fmaxf(floorf(pos2), 0.f), 30.f);
        int ix = (int)b0, iy = (int)b1, iz = (int)b2;
        float fx = pos0 - b0, fy = pos1 - b1, fz = pos2 - b2;
        int ibase = (ix * NG + iy) * NG + iz;
        float4 pr;
        pr.x = __int_as_float(ibase);
        pr.y = fx; pr.z = fy; pr.w = fz;
        int bh = b * NH + hg * 4 + lh;
        pre[(long)bh * NN + n] = pr;
        atomicAdd(&hist[bh * NG3 + ibase], 1);
    }
}

// ---------------------------------------------------------------------------
// Kernel 1b: per-bh exclusive prefix scan over 32768 cell counts.
// ---------------------------------------------------------------------------
__global__ __launch_bounds__(1024)
void k_scan_cells(const int* __restrict__ hist, int* __restrict__ offs,
                  int* __restrict__ offs_live)
{
    __shared__ int tsum[1024];
    const int bh = blockIdx.x, tid = threadIdx.x;
    const int* hb = hist + (long)bh * NG3;

    int s = 0;
    #pragma unroll 4
    for (int j = 0; j < 32; ++j) s += hb[tid * 32 + j];
    tsum[tid] = s;
    __syncthreads();
    for (int d = 1; d < 1024; d <<= 1) {
        int t = (tid >= d) ? tsum[tid - d] : 0;
        __syncthreads();
        tsum[tid] += t;
        __syncthreads();
    }
    int run = bh * NN + tsum[tid] - s;
    int* ob = offs + (long)bh * NG3;
    int* lb = offs_live + (long)bh * NG3;
    #pragma unroll 4
    for (int j = 0; j < 32; ++j) {
        int c = tid * 32 + j;
        ob[c] = run;
        lb[c] = run;
        run += hb[c];
    }
}

// ---------------------------------------------------------------------------
// Kernel 1c: scatter records into cell order. Record = 3 x uint4 = 48 B.
// ---------------------------------------------------------------------------
__global__ __launch_bounds__(256)
void k_scatter2(const float4* __restrict__ pre, const unsigned short* __restrict__ valb,
                int* __restrict__ offs_live, uint4* __restrict__ rec)
{
    long t = (long)blockIdx.x * 256 + threadIdx.x;
    float4 r = pre[t];
    int ibase = __float_as_int(r.x);
    int bh = (int)(t >> 14);
    int slot = atomicAdd(&offs_live[(long)bh * NG3 + ibase], 1);
    const uint4* vp = (const uint4*)(valb + t * NC);
    uint4 v0 = vp[0], v1 = vp[1];
    uint4* out = rec + (long)slot * 3;
    out[0] = make_uint4(__float_as_uint(r.y), __float_as_uint(r.z), __float_as_uint(r.w), 0u);
    out[1] = v0;
    out[2] = v1;
}

// ---------------------------------------------------------------------------
// Kernel 2: splat — LDS-staged chunks, merged-z segments. Atomic-free.
// ---------------------------------------------------------------------------
__global__ __launch_bounds__(1024)
void k_splat6(const uint4* __restrict__ rec, const int* __restrict__ hist,
              const int* __restrict__ offs, unsigned short* __restrict__ gridb)
{
    __shared__ uint4 sr[1024 * 3];   // 48 KB chunk
    const int tid = threadIdx.x;
    const int rx = blockIdx.x & 31;
    const int bh = blockIdx.x >> 5;
    const int y = tid >> 5, z = tid & 31;
    const int zlo = (z > 0) ? z - 1 : 0;

    const int* hb = hist + (long)bh * NG3;
    const int* ob = offs + (long)bh * NG3;

    float acc[16];
    #pragma unroll
    for (int c = 0; c < 16; ++c) acc[c] = 0.f;

    #pragma unroll
    for (int dx = 0; dx < 2; ++dx) {
        int cx = rx - dx;
        if (cx < 0) continue;                       // block-uniform
        int st[2], sp[2], en[2];
        #pragma unroll
        for (int dy = 0; dy < 2; ++dy) {
            int cy = y - dy;
            bool valid = cy >= 0;
            int base = (cx << 10) | (cy << 5);
            int c1 = base | zlo;
            int c2 = base | z;
            st[dy] = valid ? ob[c1] : 0;
            sp[dy] = valid ? ob[c2] : 0;
            en[dy] = valid ? sp[dy] + hb[c2] : 0;
        }
        int pc0 = cx << 10;
        int ps = ob[pc0];                           // uniform plane bounds
        int pe = ob[pc0 + 1023] + hb[pc0 + 1023];
        for (int cs = ps; cs < pe; cs += 1024) {
            int ce = min(cs + 1024, pe);
            __syncthreads();
            if (tid < ce - cs) {
                const uint4* R = rec + (long)(cs + tid) * 3;
                sr[tid * 3 + 0] = R[0];
                sr[tid * 3 + 1] = R[1];
                sr[tid * 3 + 2] = R[2];
            }
            __syncthreads();
            #pragma unroll
            for (int dy = 0; dy < 2; ++dy) {
                int ls = max(st[dy], cs);
                int le = min(en[dy], ce);
                int split = sp[dy];
                for (int r = ls; r < le; ++r) {
                    int k = (r - cs) * 3;
                    uint4 q0 = sr[k], q1 = sr[k + 1], q2 = sr[k + 2];
                    float fx = __uint_as_float(q0.x);
                    float fy = __uint_as_float(q0.y);
                    float fz = __uint_as_float(q0.z);
                    float wx = dx ? fx : 1.f - fx;
                    float wy = dy ? fy : 1.f - fy;
                    float wz = (r < split) ? fz : 1.f - fz;
                    float w = wx * wy * wz;
                    acc[0]  = fmaf(w, bf_lo(q1.x), acc[0]);
                    acc[1]  = fmaf(w, bf_hi(q1.x), acc[1]);
                    acc[2]  = fmaf(w, bf_lo(q1.y), acc[2]);
                    acc[3]  = fmaf(w, bf_hi(q1.y), acc[3]);
                    acc[4]  = fmaf(w, bf_lo(q1.z), acc[4]);
                    acc[5]  = fmaf(w, bf_hi(q1.z), acc[5]);
                    acc[6]  = fmaf(w, bf_lo(q1.w), acc[6]);
                    acc[7]  = fmaf(w, bf_hi(q1.w), acc[7]);
                    acc[8]  = fmaf(w, bf_lo(q2.x), acc[8]);
                    acc[9]  = fmaf(w, bf_hi(q2.x), acc[9]);
                    acc[10] = fmaf(w, bf_lo(q2.y), acc[10]);
                    acc[11] = fmaf(w, bf_hi(q2.y), acc[11]);
                    acc[12] = fmaf(w, bf_lo(q2.z), acc[12]);
                    acc[13] = fmaf(w, bf_hi(q2.z), acc[13]);
                    acc[14] = fmaf(w, bf_lo(q2.w), acc[14]);
                    acc[15] = fmaf(w, bf_hi(q2.w), acc[15]);
                }
            }
        }
    }

    uint4 q0, q1;
    q0.x = pack_bf2(acc[0],  acc[1]);  q0.y = pack_bf2(acc[2],  acc[3]);
    q0.z = pack_bf2(acc[4],  acc[5]);  q0.w = pack_bf2(acc[6],  acc[7]);
    q1.x = pack_bf2(acc[8],  acc[9]);  q1.y = pack_bf2(acc[10], acc[11]);
    q1.z = pack_bf2(acc[12], acc[13]); q1.w = pack_bf2(acc[14], acc[15]);
    uint4* gb = (uint4*)(gridb + ((long)bh * NG3 + (rx << 10) + tid) * NC);
    gb[0] = q0;
    gb[1] = q1;
}

// ---------------------------------------------------------------------------
// Kernel 3a: one-time weight conversion into conv's sw layout (bf16).
// ---------------------------------------------------------------------------
__global__ __launch_bounds__(256)
void k_wprep(const float* __restrict__ cw, unsigned short* __restrict__ wpre)
{
    const int h = blockIdx.x;
    for (int e = threadIdx.x; e < 7168; e += 256) {
        int icl = e & 7, oc = (e >> 3) & 15, ihl = (e >> 7) & 1, tap = e >> 8;
        int ic = ihl * 8 + icl;
        float wv = (tap < 27) ? cw[(h * 16 + oc) * 432 + ic * 27 + tap] : 0.f;
        __hip_bfloat16 hbw = __float2bfloat16(wv);
        wpre[h * 7168 + e] = *(unsigned short*)&hbw;
    }
}

// ---------------------------------------------------------------------------
// Kernel 3: grouped 3x3x3 conv via BF16 MFMA, fully-unrolled phase loop.
// ---------------------------------------------------------------------------
__global__ __launch_bounds__(512)
void k_conv5(const unsigned short* __restrict__ gridb,
             const unsigned short* __restrict__ wpre,
             const float* __restrict__ cb,
             unsigned short* __restrict__ convo)
{
    __shared__ unsigned short sg[2 * 6 * 10 * 34 * 8];  // 65280 B
    __shared__ unsigned short sw[28 * 2 * 16 * 8];      // 14336 B
    const int tid = threadIdx.x;
    const int bid = blockIdx.x;
    const int yt = bid & 3, xt = (bid >> 2) & 7, bh = bid >> 5;
    const int h = bh & 7;
    const int x0 = xt * 4, y0 = yt * 8;

    {
        const uint4* wsrc = (const uint4*)(wpre + (long)h * 7168);
        uint4* wdst = (uint4*)sw;
        for (int e = tid; e < 896; e += 512) wdst[e] = wsrc[e];
    }
    const unsigned short* gb = gridb + (long)bh * NG3 * 16;
    for (int e = tid; e < 2 * 6 * 10 * 34; e += 512) {
        int ihl = e & 1, c = e >> 1;
        int zz = c % 34, yu = c / 34;
        int yy = yu % 10, xx = yu / 10;
        int gx = x0 + xx - 1, gy = y0 + yy - 1, gz = zz - 1;
        uint4 v = make_uint4(0, 0, 0, 0);
        if ((unsigned)gx < NG && (unsigned)gy < NG && (unsigned)gz < NG)
            v = *(const uint4*)(gb + (((gx * NG + gy) * NG + gz) * 16 + ihl * 8));
        *(uint4*)(sg + ((((ihl * 6 + xx) * 10 + yy) * 34) + zz) * 8) = v;
    }
    __syncthreads();

    const int lane = tid & 63;
    const int w  = tid >> 6;
    const int wv = w & 3;
    const int zh = w >> 2;
    const int m  = lane & 15;
    const int l4 = lane >> 4;
    const int ihl = l4 & 1;
    const int tp = l4 >> 1;

    const int aLaneByte = ((((ihl * 6 + wv) * 10) * 34) + zh * 16 + m) * 16;
    const int bLaneByte = l4 * 256 + m * 16;
    const char* sgb = (const char*)sg;
    const char* swb = (const char*)sw;

    f32x4 acc[8];
    #pragma unroll
    for (int j = 0; j < 8; ++j) acc[j] = (f32x4){0.f, 0.f, 0.f, 0.f};

    #pragma unroll
    for (int p = 0; p < 14; ++p) {
        const int t0 = 2 * p, t1 = 2 * p + 1;
        const int ta0 = (t0 > 26) ? 26 : t0, ta1 = (t1 > 26) ? 26 : t1;
        const int off0 = ((ta0 / 9) * 340 + ((ta0 % 9) / 3) * 34 + (ta0 % 3)) * 16;
        const int off1 = ((ta1 / 9) * 340 + ((ta1 % 9) / 3) * 34 + (ta1 % 3)) * 16;
        const int aoff = aLaneByte + (tp ? off1 : off0);
        bf16x8 bfr = *(const bf16x8*)(swb + p * 1024 + bLaneByte);
        #pragma unroll
        for (int j = 0; j < 8; ++j) {
            bf16x8 afr = *(const bf16x8*)(sgb + aoff + j * 544);
            acc[j] = __builtin_amdgcn_mfma_f32_16x16x32_bf16(afr, bfr, acc[j], 0, 0, 0);
        }
    }

    const float bias = cb[h * 16 + m];
    unsigned short* cvb = convo + (long)bh * NG3 * NC;
    const int gx = x0 + wv;
    const int z0 = zh * 16;
    #pragma unroll
    for (int j = 0; j < 8; ++j) {
        int gy = y0 + j;
        long cellbase = (long)(gx * NG + gy) * NG + z0 + l4 * 4;
        #pragma unroll
        for (int r = 0; r < 4; ++r) {
            __hip_bfloat16 hb = __float2bfloat16(acc[j][r] + bias);
            cvb[(cellbase + r) * NC + m] = *(unsigned short*)&hb;
        }
    }
}

// ---------------------------------------------------------------------------
// Kernel 4: slice (weighted gather from bf16 convo) + BN + ReLU, out f32.
// ---------------------------------------------------------------------------
__global__ __launch_bounds__(256)
void k_slice(const unsigned short* __restrict__ convo, const float4* __restrict__ pre,
             const float* __restrict__ ag, const float* __restrict__ ab,
             const float* __restrict__ am, const float* __restrict__ av,
             float* __restrict__ out)
{
    __shared__ float asc[128], ash[128];
    const int tid = threadIdx.x;
    if (tid < 128) {
        float s = rsqrtf(av[tid] + KEPS) * ag[tid];
        asc[tid] = s;
        ash[tid] = ab[tid] - am[tid] * s;
    }
    __syncthreads();

    long t = (long)blockIdx.x * 256 + tid;
    long bh = t / NN;
    int n = (int)(t % NN);
    int b = (int)(bh >> 3), h = (int)(bh & 7);
    const unsigned short* g = convo + bh * (long)NG3 * NC;

    float4 r = pre[t];
    int ibase = __float_as_int(r.x);
    float fx = r.y, fy = r.z, fz = r.w;
    float gx = 1.f - fx, gy = 1.f - fy, gz = 1.f - fz;
    const float ws8[8] = {gx*gy*gz, gx*gy*fz, gx*fy*gz, gx*fy*fz,
                          fx*gy*gz, fx*gy*fz, fx*fy*gz, fx*fy*fz};
    const int offs8[8] = {0, 1, NG, NG + 1, NG*NG, NG*NG + 1, NG*NG + NG, NG*NG + NG + 1};

    float acc[NC];
    #pragma unroll
    for (int c = 0; c < NC; ++c) acc[c] = 0.f;
    #pragma unroll
    for (int ci = 0; ci < 8; ++ci) {
        float w = ws8[ci];
        const uint4* gc = (const uint4*)(g + (long)(ibase + offs8[ci]) * NC);
        uint4 u0 = gc[0], u1 = gc[1];
        acc[0]  = fmaf(w, bf_lo(u0.x), acc[0]);
        acc[1]  = fmaf(w, bf_hi(u0.x), acc[1]);
        acc[2]  = fmaf(w, bf_lo(u0.y), acc[2]);
        acc[3]  = fmaf(w, bf_hi(u0.y), acc[3]);
        acc[4]  = fmaf(w, bf_lo(u0.z), acc[4]);
        acc[5]  = fmaf(w, bf_hi(u0.z), acc[5]);
        acc[6]  = fmaf(w, bf_lo(u0.w), acc[6]);
        acc[7]  = fmaf(w, bf_hi(u0.w), acc[7]);
        acc[8]  = fmaf(w, bf_lo(u1.x), acc[8]);
        acc[9]  = fmaf(w, bf_hi(u1.x), acc[9]);
        acc[10] = fmaf(w, bf_lo(u1.y), acc[10]);
        acc[11] = fmaf(w, bf_hi(u1.y), acc[11]);
        acc[12] = fmaf(w, bf_lo(u1.z), acc[12]);
        acc[13] = fmaf(w, bf_hi(u1.z), acc[13]);
        acc[14] = fmaf(w, bf_lo(u1.w), acc[14]);
        acc[15] = fmaf(w, bf_hi(u1.w), acc[15]);
    }
    float* ob = out + ((long)b * 128 + h * 16) * NN + n;
    #pragma unroll
    for (int c = 0; c < NC; ++c) {
        float rr = fmaf(acc[c], asc[h * 16 + c], ash[h * 16 + c]);
        ob[(long)c * NN] = fmaxf(rr, 0.f);
    }
}

// ---------------------------------------------------------------------------
extern "C" void kernel_launch(void* const* d_in, const int* in_sizes, int n_in,
                              void* d_out, int out_size, void* d_ws, size_t ws_size,
                              hipStream_t stream)
{
    (void)in_sizes; (void)n_in; (void)out_size; (void)ws_size;
    const float* x    = (const float*)d_in[0];
    const float* orig = (const float*)d_in[1];
    const float* wkv  = (const float*)d_in[2];
    const float* kg   = (const float*)d_in[3];
    const float* kb   = (const float*)d_in[4];
    const float* km   = (const float*)d_in[5];
    const float* kvv  = (const float*)d_in[6];
    const float* vg   = (const float*)d_in[7];
    const float* vb   = (const float*)d_in[8];
    const float* vm   = (const float*)d_in[9];
    const float* vv   = (const float*)d_in[10];
    const float* Wt   = (const float*)d_in[11];
    const float* bt   = (const float*)d_in[12];
    const float* cw   = (const float*)d_in[13];
    const float* cb   = (const float*)d_in[14];
    const float* ag   = (const float*)d_in[15];
    const float* ab   = (const float*)d_in[16];
    const float* am   = (const float*)d_in[17];
    const float* av   = (const float*)d_in[18];

    char* ws = (char*)d_ws;
    float4*         pre       = (float4*)        (ws);                 //  8,388,608
    int*            hist      = (int*)           (ws + 8388608);       //  4,194,304
    int*            offs      = (int*)           (ws + 12582912);      //  4,194,304
    int*            offs_live = (int*)           (ws + 16777216);      //  4,194,304
    unsigned short* valb      = (unsigned short*)(ws + 20971520);      // 16,777,216 -> end 37,748,736
    uint4*          rec       = (uint4*)         (ws + 37748736);      // 25,165,824 -> end 62,914,560
    unsigned short* gridb     = (unsigned short*)(ws + 62914560);      // 33,554,432 -> end 96,468,992
    unsigned short* wpre      = (unsigned short*)(ws + 96468992);      //    114,688 -> end 96,583,680
    unsigned short* convo     = (unsigned short*)(ws + 20971520);      // 33,554,432 (alias valb+rec, dead by k_conv5)

    k_zero<<<dim3(1024), dim3(256), 0, stream>>>((uint4*)hist);

    k_wprep<<<dim3(NH), dim3(256), 0, stream>>>(cw, wpre);

    k_front3<<<dim3(NB * 128), dim3(256), 0, stream>>>(
        x, orig, wkv, kg, kb, km, kvv, vg, vb, vm, vv, Wt, bt, valb, pre, hist);

    k_scan_cells<<<dim3(NB * NH), dim3(1024), 0, stream>>>(hist, offs, offs_live);

    k_scatter2<<<dim3((NB * NH * NN) / 256), dim3(256), 0, stream>>>(
        pre, valb, offs_live, rec);

    k_splat6<<<dim3(NB * NH * NG), dim3(1024), 0, stream>>>(rec, hist, offs, gridb);

    k_conv5<<<dim3(NB * NH * 32), dim3(512), 0, stream>>>(gridb, wpre, cb, convo);

    k_slice<<<dim3((NB * NH * NN) / 256), dim3(256), 0, stream>>>(
        convo, pre, ag, ab, am, av, (float*)d_out);
}

// Round 15
// 195.078 us; speedup vs baseline: 6.4753x; 1.0701x over previous
//
#include <hip/hip_runtime.h>
#include <hip/hip_bf16.h>

#define NB  4
#define NH  8
#define NC  16
#define ND  64
#define NN  16384
#define NG  32
#define NG3 32768
#define NKV 152
#define KEPS 1e-5f
#define TN  256   // points per k_front3 block

typedef __attribute__((ext_vector_type(8))) short bf16x8;
typedef __attribute__((ext_vector_type(4))) float f32x4;

__device__ __forceinline__ unsigned pack_bf2(float lo, float hi) {
    __hip_bfloat16 a = __float2bfloat16(lo);
    __hip_bfloat16 b = __float2bfloat16(hi);
    return (unsigned)(*(unsigned short*)&a) | ((unsigned)(*(unsigned short*)&b) << 16);
}
__device__ __forceinline__ float bf_lo(unsigned u) { return __uint_as_float(u << 16); }
__device__ __forceinline__ float bf_hi(unsigned u) { return __uint_as_float(u & 0xffff0000u); }

// ---------------------------------------------------------------------------
// Kernel 0: fast zero of hist (4 MB).
// ---------------------------------------------------------------------------
__global__ __launch_bounds__(256)
void k_zero(uint4* __restrict__ p)
{
    p[(long)blockIdx.x * 256 + threadIdx.x] = make_uint4(0, 0, 0, 0);
}

// ---------------------------------------------------------------------------
// Kernel 1: front — 2 head-group blocks per point-tile (2x occupancy).
// ---------------------------------------------------------------------------
__global__ __launch_bounds__(256)
void k_front3(const float* __restrict__ x,      // [B,D,N]
              const float* __restrict__ orig,   // [B,3,N]
              const float* __restrict__ wkv,    // [152,64]
              const float* __restrict__ kg, const float* __restrict__ kb,
              const float* __restrict__ km, const float* __restrict__ kvv,
              const float* __restrict__ vg, const float* __restrict__ vb,
              const float* __restrict__ vm, const float* __restrict__ vv,
              const float* __restrict__ Wt,     // [8,3,3]
              const float* __restrict__ bt,     // [8,3]
              unsigned short* __restrict__ valb, // [B,H,N,C] bf16
              float4* __restrict__ pre,         // [B,H,N]
              int* __restrict__ hist)           // [B*H*32768]
{
    __shared__ unsigned short xb[TN * 72];      // bf16 x tile [n][d], pitch 72
    __shared__ float wk[12 * ND];               // this group's key rows
    __shared__ float ksc[12], ksh[12], vsc[64], vsh[64], wts[36], bts[12];
    const int tid = threadIdx.x;
    const int hg   = blockIdx.x & 1;            // head group: heads hg*4..hg*4+3
    const int tile = (blockIdx.x >> 1) & 63;
    const int b    = blockIdx.x >> 7;
    const int n0 = tile * TN;
    const int n  = n0 + tid;

    for (int i = tid; i < 12 * ND; i += 256) wk[i] = wkv[hg * 768 + i];
    if (tid < 12) {
        int ch = hg * 12 + tid;
        float s = rsqrtf(kvv[ch] + KEPS) * kg[ch];
        ksc[tid] = s;
        ksh[tid] = kb[ch] - km[ch] * s;
    }
    if (tid < 64) {
        int ch = hg * 64 + tid;
        float s = rsqrtf(vv[ch] + KEPS) * vg[ch];
        vsc[tid] = s;
        vsh[tid] = vb[ch] - vm[ch] * s;
    }
    if (tid < 36) wts[tid] = Wt[hg * 36 + tid];
    if (tid < 12) bts[tid] = bt[hg * 12 + tid];

    float xr[ND];
    #pragma unroll
    for (int d = 0; d < ND; ++d)
        xr[d] = x[((long)b * ND + d) * NN + n];
    #pragma unroll
    for (int j = 0; j < 8; ++j) {
        uint4 q;
        q.x = pack_bf2(xr[8*j+0], xr[8*j+1]);
        q.y = pack_bf2(xr[8*j+2], xr[8*j+3]);
        q.z = pack_bf2(xr[8*j+4], xr[8*j+5]);
        q.w = pack_bf2(xr[8*j+6], xr[8*j+7]);
        *(uint4*)(xb + tid * 72 + j * 8) = q;
    }
    __syncthreads();

    float ko[12];
    #pragma unroll 1
    for (int o = 0; o < 12; o += 4) {
        float s0 = 0.f, s1 = 0.f, s2 = 0.f, s3 = 0.f;
        #pragma unroll
        for (int dq = 0; dq < 16; ++dq) {
            const float4 w0 = *(const float4*)&wk[(o + 0) * ND + dq * 4];
            const float4 w1 = *(const float4*)&wk[(o + 1) * ND + dq * 4];
            const float4 w2 = *(const float4*)&wk[(o + 2) * ND + dq * 4];
            const float4 w3 = *(const float4*)&wk[(o + 3) * ND + dq * 4];
            float a0 = xr[4*dq], a1 = xr[4*dq+1], a2 = xr[4*dq+2], a3 = xr[4*dq+3];
            s0 = fmaf(w0.x, a0, fmaf(w0.y, a1, fmaf(w0.z, a2, fmaf(w0.w, a3, s0))));
            s1 = fmaf(w1.x, a0, fmaf(w1.y, a1, fmaf(w1.z, a2, fmaf(w1.w, a3, s1))));
            s2 = fmaf(w2.x, a0, fmaf(w2.y, a1, fmaf(w2.z, a2, fmaf(w2.w, a3, s2))));
            s3 = fmaf(w3.x, a0, fmaf(w3.y, a1, fmaf(w3.z, a2, fmaf(w3.w, a3, s3))));
        }
        ko[o + 0] = fmaf(s0, ksc[o + 0], ksh[o + 0]);
        ko[o + 1] = fmaf(s1, ksc[o + 1], ksh[o + 1]);
        ko[o + 2] = fmaf(s2, ksc[o + 2], ksh[o + 2]);
        ko[o + 3] = fmaf(s3, ksc[o + 3], ksh[o + 3]);
    }

    {
        const int lane = tid & 63;
        const int wv = tid >> 6;
        const int l15 = lane & 15, l4 = lane >> 4;
        const int h = hg * 4 + wv;
        const int ocg = h * 16 + l15;
        const float bsc = vsc[wv * 16 + l15];
        const float bsh = vsh[wv * 16 + l15];

        bf16x8 bfr[2];
        #pragma unroll
        for (int ks = 0; ks < 2; ++ks) {
            const float* wp = wkv + (24 + ocg) * ND + ks * 32 + l4 * 8;
            float4 a = *(const float4*)wp;
            float4 c = *(const float4*)(wp + 4);
            uint4 q;
            q.x = pack_bf2(a.x, a.y); q.y = pack_bf2(a.z, a.w);
            q.z = pack_bf2(c.x, c.y); q.w = pack_bf2(c.z, c.w);
            bfr[ks] = *(bf16x8*)&q;
        }

        #pragma unroll 1
        for (int nb = 0; nb < 16; ++nb) {
            bf16x8 a0 = *(const bf16x8*)(xb + (nb * 16 + l15) * 72 + l4 * 8);
            bf16x8 a1 = *(const bf16x8*)(xb + (nb * 16 + l15) * 72 + 32 + l4 * 8);
            f32x4 acc = (f32x4){0.f, 0.f, 0.f, 0.f};
            acc = __builtin_amdgcn_mfma_f32_16x16x32_bf16(a0, bfr[0], acc, 0, 0, 0);
            acc = __builtin_amdgcn_mfma_f32_16x16x32_bf16(a1, bfr[1], acc, 0, 0, 0);
            unsigned short* vp = valb + (((long)(b * NH + h) * NN + n0 + nb * 16 + l4 * 4) * NC) + l15;
            #pragma unroll
            for (int r = 0; r < 4; ++r) {
                __hip_bfloat16 hb = __float2bfloat16(fmaf(acc[r], bsc, bsh));
                vp[r * NC] = *(unsigned short*)&hb;
            }
        }
    }

    const float o0 = orig[((long)b * 3 + 0) * NN + n];
    const float o1 = orig[((long)b * 3 + 1) * NN + n];
    const float o2 = orig[((long)b * 3 + 2) * NN + n];

    #pragma unroll 1
    for (int lh = 0; lh < 4; ++lh) {
        float p0 = o0 + ko[lh * 3 + 0];
        float p1 = o1 + ko[lh * 3 + 1];
        float p2 = o2 + ko[lh * 3 + 2];
        float t0 = fmaf(wts[lh * 9 + 0], p0, fmaf(wts[lh * 9 + 1], p1, fmaf(wts[lh * 9 + 2], p2, bts[lh * 3 + 0])));
        float t1 = fmaf(wts[lh * 9 + 3], p0, fmaf(wts[lh * 9 + 4], p1, fmaf(wts[lh * 9 + 5], p2, bts[lh * 3 + 1])));
        float t2 = fmaf(wts[lh * 9 + 6], p0, fmaf(wts[lh * 9 + 7], p1, fmaf(wts[lh * 9 + 8], p2, bts[lh * 3 + 2])));
        float l0 = tanhf(t0), l1 = tanhf(t1), l2 = tanhf(t2);
        float pos0 = (l0 + 1.f) * 15.5f;
        float pos1 = (l1 + 1.f) * 15.5f;
        float pos2 = (l2 + 1.f) * 15.5f;
        float b0 = fminf(fmaxf(floorf(pos0), 0.f), 30.f);
        float b1 = fminf(fmaxf(floorf(pos1), 0.f), 30.f);
        float b2 = fminf(fmaxf(floorf(pos2), 0.f), 30.f);
        int ix = (int)b0, iy = (int)b1, iz = (int)b2;
        float fx = pos0 - b0, fy = pos1 - b1, fz = pos2 - b2;
        int ibase = (ix * NG + iy) * NG + iz;
        float4 pr;
        pr.x = __int_as_float(ibase);
        pr.y = fx; pr.z = fy; pr.w = fz;
        int bh = b * NH + hg * 4 + lh;
        pre[(long)bh * NN + n] = pr;
        atomicAdd(&hist[bh * NG3 + ibase], 1);
    }
}

// ---------------------------------------------------------------------------
// Kernel 1b: per-bh exclusive prefix scan over 32768 cell counts.
// ---------------------------------------------------------------------------
__global__ __launch_bounds__(1024)
void k_scan_cells(const int* __restrict__ hist, int* __restrict__ offs,
                  int* __restrict__ offs_live)
{
    __shared__ int tsum[1024];
    const int bh = blockIdx.x, tid = threadIdx.x;
    const int* hb = hist + (long)bh * NG3;

    int s = 0;
    #pragma unroll 4
    for (int j = 0; j < 32; ++j) s += hb[tid * 32 + j];
    tsum[tid] = s;
    __syncthreads();
    for (int d = 1; d < 1024; d <<= 1) {
        int t = (tid >= d) ? tsum[tid - d] : 0;
        __syncthreads();
        tsum[tid] += t;
        __syncthreads();
    }
    int run = bh * NN + tsum[tid] - s;
    int* ob = offs + (long)bh * NG3;
    int* lb = offs_live + (long)bh * NG3;
    #pragma unroll 4
    for (int j = 0; j < 32; ++j) {
        int c = tid * 32 + j;
        ob[c] = run;
        lb[c] = run;
        run += hb[c];
    }
}

// ---------------------------------------------------------------------------
// Kernel 1c: scatter records into cell order. Record = 3 x uint4 = 48 B.
// XCD-grouped block mapping: bh = 8*grp + (blockIdx&7) so each XCD keeps
// a 4-bh working set (round-robin dispatch heuristic; perf-only).
// ---------------------------------------------------------------------------
__global__ __launch_bounds__(256)
void k_scatter2(const float4* __restrict__ pre, const unsigned short* __restrict__ valb,
                int* __restrict__ offs_live, uint4* __restrict__ rec)
{
    const int bh   = 8 * ((blockIdx.x >> 3) & 3) + (blockIdx.x & 7);
    const int tile = blockIdx.x >> 5;
    long t = (long)bh * NN + tile * 256 + threadIdx.x;
    float4 r = pre[t];
    int ibase = __float_as_int(r.x);
    int slot = atomicAdd(&offs_live[(long)bh * NG3 + ibase], 1);
    const uint4* vp = (const uint4*)(valb + t * NC);
    uint4 v0 = vp[0], v1 = vp[1];
    uint4* out = rec + (long)slot * 3;
    out[0] = make_uint4(__float_as_uint(r.y), __float_as_uint(r.z), __float_as_uint(r.w), 0u);
    out[1] = v0;
    out[2] = v1;
}

// ---------------------------------------------------------------------------
// Kernel 2: splat — LDS-staged chunks, merged-z segments. Atomic-free.
// ---------------------------------------------------------------------------
__global__ __launch_bounds__(1024)
void k_splat6(const uint4* __restrict__ rec, const int* __restrict__ hist,
              const int* __restrict__ offs, unsigned short* __restrict__ gridb)
{
    __shared__ uint4 sr[1024 * 3];   // 48 KB chunk
    const int tid = threadIdx.x;
    const int rx = blockIdx.x & 31;
    const int bh = blockIdx.x >> 5;
    const int y = tid >> 5, z = tid & 31;
    const int zlo = (z > 0) ? z - 1 : 0;

    const int* hb = hist + (long)bh * NG3;
    const int* ob = offs + (long)bh * NG3;

    float acc[16];
    #pragma unroll
    for (int c = 0; c < 16; ++c) acc[c] = 0.f;

    #pragma unroll
    for (int dx = 0; dx < 2; ++dx) {
        int cx = rx - dx;
        if (cx < 0) continue;                       // block-uniform
        int st[2], sp[2], en[2];
        #pragma unroll
        for (int dy = 0; dy < 2; ++dy) {
            int cy = y - dy;
            bool valid = cy >= 0;
            int base = (cx << 10) | (cy << 5);
            int c1 = base | zlo;
            int c2 = base | z;
            st[dy] = valid ? ob[c1] : 0;
            sp[dy] = valid ? ob[c2] : 0;
            en[dy] = valid ? sp[dy] + hb[c2] : 0;
        }
        int pc0 = cx << 10;
        int ps = ob[pc0];
        int pe = ob[pc0 + 1023] + hb[pc0 + 1023];
        for (int cs = ps; cs < pe; cs += 1024) {
            int ce = min(cs + 1024, pe);
            __syncthreads();
            if (tid < ce - cs) {
                const uint4* R = rec + (long)(cs + tid) * 3;
                sr[tid * 3 + 0] = R[0];
                sr[tid * 3 + 1] = R[1];
                sr[tid * 3 + 2] = R[2];
            }
            __syncthreads();
            #pragma unroll
            for (int dy = 0; dy < 2; ++dy) {
                int ls = max(st[dy], cs);
                int le = min(en[dy], ce);
                int split = sp[dy];
                for (int r = ls; r < le; ++r) {
                    int k = (r - cs) * 3;
                    uint4 q0 = sr[k], q1 = sr[k + 1], q2 = sr[k + 2];
                    float fx = __uint_as_float(q0.x);
                    float fy = __uint_as_float(q0.y);
                    float fz = __uint_as_float(q0.z);
                    float wx = dx ? fx : 1.f - fx;
                    float wy = dy ? fy : 1.f - fy;
                    float wz = (r < split) ? fz : 1.f - fz;
                    float w = wx * wy * wz;
                    acc[0]  = fmaf(w, bf_lo(q1.x), acc[0]);
                    acc[1]  = fmaf(w, bf_hi(q1.x), acc[1]);
                    acc[2]  = fmaf(w, bf_lo(q1.y), acc[2]);
                    acc[3]  = fmaf(w, bf_hi(q1.y), acc[3]);
                    acc[4]  = fmaf(w, bf_lo(q1.z), acc[4]);
                    acc[5]  = fmaf(w, bf_hi(q1.z), acc[5]);
                    acc[6]  = fmaf(w, bf_lo(q1.w), acc[6]);
                    acc[7]  = fmaf(w, bf_hi(q1.w), acc[7]);
                    acc[8]  = fmaf(w, bf_lo(q2.x), acc[8]);
                    acc[9]  = fmaf(w, bf_hi(q2.x), acc[9]);
                    acc[10] = fmaf(w, bf_lo(q2.y), acc[10]);
                    acc[11] = fmaf(w, bf_hi(q2.y), acc[11]);
                    acc[12] = fmaf(w, bf_lo(q2.z), acc[12]);
                    acc[13] = fmaf(w, bf_hi(q2.z), acc[13]);
                    acc[14] = fmaf(w, bf_lo(q2.w), acc[14]);
                    acc[15] = fmaf(w, bf_hi(q2.w), acc[15]);
                }
            }
        }
    }

    uint4 q0, q1;
    q0.x = pack_bf2(acc[0],  acc[1]);  q0.y = pack_bf2(acc[2],  acc[3]);
    q0.z = pack_bf2(acc[4],  acc[5]);  q0.w = pack_bf2(acc[6],  acc[7]);
    q1.x = pack_bf2(acc[8],  acc[9]);  q1.y = pack_bf2(acc[10], acc[11]);
    q1.z = pack_bf2(acc[12], acc[13]); q1.w = pack_bf2(acc[14], acc[15]);
    uint4* gb = (uint4*)(gridb + ((long)bh * NG3 + (rx << 10) + tid) * NC);
    gb[0] = q0;
    gb[1] = q1;
}

// ---------------------------------------------------------------------------
// Kernel 3a: one-time weight conversion into conv's sw layout (bf16).
// ---------------------------------------------------------------------------
__global__ __launch_bounds__(256)
void k_wprep(const float* __restrict__ cw, unsigned short* __restrict__ wpre)
{
    const int h = blockIdx.x;
    for (int e = threadIdx.x; e < 7168; e += 256) {
        int icl = e & 7, oc = (e >> 3) & 15, ihl = (e >> 7) & 1, tap = e >> 8;
        int ic = ihl * 8 + icl;
        float wv = (tap < 27) ? cw[(h * 16 + oc) * 432 + ic * 27 + tap] : 0.f;
        __hip_bfloat16 hbw = __float2bfloat16(wv);
        wpre[h * 7168 + e] = *(unsigned short*)&hbw;
    }
}

// ---------------------------------------------------------------------------
// Kernel 3: grouped 3x3x3 conv via BF16 MFMA, fully-unrolled phase loop.
// ---------------------------------------------------------------------------
__global__ __launch_bounds__(512)
void k_conv5(const unsigned short* __restrict__ gridb,
             const unsigned short* __restrict__ wpre,
             const float* __restrict__ cb,
             unsigned short* __restrict__ convo)
{
    __shared__ unsigned short sg[2 * 6 * 10 * 34 * 8];  // 65280 B
    __shared__ unsigned short sw[28 * 2 * 16 * 8];      // 14336 B
    const int tid = threadIdx.x;
    const int bid = blockIdx.x;
    const int yt = bid & 3, xt = (bid >> 2) & 7, bh = bid >> 5;
    const int h = bh & 7;
    const int x0 = xt * 4, y0 = yt * 8;

    {
        const uint4* wsrc = (const uint4*)(wpre + (long)h * 7168);
        uint4* wdst = (uint4*)sw;
        for (int e = tid; e < 896; e += 512) wdst[e] = wsrc[e];
    }
    const unsigned short* gb = gridb + (long)bh * NG3 * 16;
    for (int e = tid; e < 2 * 6 * 10 * 34; e += 512) {
        int ihl = e & 1, c = e >> 1;
        int zz = c % 34, yu = c / 34;
        int yy = yu % 10, xx = yu / 10;
        int gx = x0 + xx - 1, gy = y0 + yy - 1, gz = zz - 1;
        uint4 v = make_uint4(0, 0, 0, 0);
        if ((unsigned)gx < NG && (unsigned)gy < NG && (unsigned)gz < NG)
            v = *(const uint4*)(gb + (((gx * NG + gy) * NG + gz) * 16 + ihl * 8));
        *(uint4*)(sg + ((((ihl * 6 + xx) * 10 + yy) * 34) + zz) * 8) = v;
    }
    __syncthreads();

    const int lane = tid & 63;
    const int w  = tid >> 6;
    const int wv = w & 3;
    const int zh = w >> 2;
    const int m  = lane & 15;
    const int l4 = lane >> 4;
    const int ihl = l4 & 1;
    const int tp = l4 >> 1;

    const int aLaneByte = ((((ihl * 6 + wv) * 10) * 34) + zh * 16 + m) * 16;
    const int bLaneByte = l4 * 256 + m * 16;
    const char* sgb = (const char*)sg;
    const char* swb = (const char*)sw;

    f32x4 acc[8];
    #pragma unroll
    for (int j = 0; j < 8; ++j) acc[j] = (f32x4){0.f, 0.f, 0.f, 0.f};

    #pragma unroll
    for (int p = 0; p < 14; ++p) {
        const int t0 = 2 * p, t1 = 2 * p + 1;
        const int ta0 = (t0 > 26) ? 26 : t0, ta1 = (t1 > 26) ? 26 : t1;
        const int off0 = ((ta0 / 9) * 340 + ((ta0 % 9) / 3) * 34 + (ta0 % 3)) * 16;
        const int off1 = ((ta1 / 9) * 340 + ((ta1 % 9) / 3) * 34 + (ta1 % 3)) * 16;
        const int aoff = aLaneByte + (tp ? off1 : off0);
        bf16x8 bfr = *(const bf16x8*)(swb + p * 1024 + bLaneByte);
        #pragma unroll
        for (int j = 0; j < 8; ++j) {
            bf16x8 afr = *(const bf16x8*)(sgb + aoff + j * 544);
            acc[j] = __builtin_amdgcn_mfma_f32_16x16x32_bf16(afr, bfr, acc[j], 0, 0, 0);
        }
    }

    const float bias = cb[h * 16 + m];
    unsigned short* cvb = convo + (long)bh * NG3 * NC;
    const int gx = x0 + wv;
    const int z0 = zh * 16;
    #pragma unroll
    for (int j = 0; j < 8; ++j) {
        int gy = y0 + j;
        long cellbase = (long)(gx * NG + gy) * NG + z0 + l4 * 4;
        #pragma unroll
        for (int r = 0; r < 4; ++r) {
            __hip_bfloat16 hb = __float2bfloat16(acc[j][r] + bias);
            cvb[(cellbase + r) * NC + m] = *(unsigned short*)&hb;
        }
    }
}

// ---------------------------------------------------------------------------
// Kernel 4: slice + BN + ReLU, out f32. XCD-grouped bh mapping: each XCD
// keeps 4 bh (4 MB convo working set = one L2) -> corner gathers L2-hit.
// ---------------------------------------------------------------------------
__global__ __launch_bounds__(256)
void k_slice(const unsigned short* __restrict__ convo, const float4* __restrict__ pre,
             const float* __restrict__ ag, const float* __restrict__ ab,
             const float* __restrict__ am, const float* __restrict__ av,
             float* __restrict__ out)
{
    __shared__ float asc[128], ash[128];
    const int tid = threadIdx.x;
    if (tid < 128) {
        float s = rsqrtf(av[tid] + KEPS) * ag[tid];
        asc[tid] = s;
        ash[tid] = ab[tid] - am[tid] * s;
    }
    __syncthreads();

    const int bh   = 8 * ((blockIdx.x >> 3) & 3) + (blockIdx.x & 7);
    const int tile = blockIdx.x >> 5;
    const int n = tile * 256 + tid;
    long t = (long)bh * NN + n;
    int b = bh >> 3, h = bh & 7;
    const unsigned short* g = convo + (long)bh * NG3 * NC;

    float4 r = pre[t];
    int ibase = __float_as_int(r.x);
    float fx = r.y, fy = r.z, fz = r.w;
    float gx = 1.f - fx, gy = 1.f - fy, gz = 1.f - fz;
    const float ws8[8] = {gx*gy*gz, gx*gy*fz, gx*fy*gz, gx*fy*fz,
                          fx*gy*gz, fx*gy*fz, fx*fy*gz, fx*fy*fz};
    const int offs8[8] = {0, 1, NG, NG + 1, NG*NG, NG*NG + 1, NG*NG + NG, NG*NG + NG + 1};

    float acc[NC];
    #pragma unroll
    for (int c = 0; c < NC; ++c) acc[c] = 0.f;
    #pragma unroll
    for (int ci = 0; ci < 8; ++ci) {
        float w = ws8[ci];
        const uint4* gc = (const uint4*)(g + (long)(ibase + offs8[ci]) * NC);
        uint4 u0 = gc[0], u1 = gc[1];
        acc[0]  = fmaf(w, bf_lo(u0.x), acc[0]);
        acc[1]  = fmaf(w, bf_hi(u0.x), acc[1]);
        acc[2]  = fmaf(w, bf_lo(u0.y), acc[2]);
        acc[3]  = fmaf(w, bf_hi(u0.y), acc[3]);
        acc[4]  = fmaf(w, bf_lo(u0.z), acc[4]);
        acc[5]  = fmaf(w, bf_hi(u0.z), acc[5]);
        acc[6]  = fmaf(w, bf_lo(u0.w), acc[6]);
        acc[7]  = fmaf(w, bf_hi(u0.w), acc[7]);
        acc[8]  = fmaf(w, bf_lo(u1.x), acc[8]);
        acc[9]  = fmaf(w, bf_hi(u1.x), acc[9]);
        acc[10] = fmaf(w, bf_lo(u1.y), acc[10]);
        acc[11] = fmaf(w, bf_hi(u1.y), acc[11]);
        acc[12] = fmaf(w, bf_lo(u1.z), acc[12]);
        acc[13] = fmaf(w, bf_hi(u1.z), acc[13]);
        acc[14] = fmaf(w, bf_lo(u1.w), acc[14]);
        acc[15] = fmaf(w, bf_hi(u1.w), acc[15]);
    }
    float* ob = out + ((long)b * 128 + h * 16) * NN + n;
    #pragma unroll
    for (int c = 0; c < NC; ++c) {
        float rr = fmaf(acc[c], asc[h * 16 + c], ash[h * 16 + c]);
        ob[(long)c * NN] = fmaxf(rr, 0.f);
    }
}

// ---------------------------------------------------------------------------
extern "C" void kernel_launch(void* const* d_in, const int* in_sizes, int n_in,
                              void* d_out, int out_size, void* d_ws, size_t ws_size,
                              hipStream_t stream)
{
    (void)in_sizes; (void)n_in; (void)out_size; (void)ws_size;
    const float* x    = (const float*)d_in[0];
    const float* orig = (const float*)d_in[1];
    const float* wkv  = (const float*)d_in[2];
    const float* kg   = (const float*)d_in[3];
    const float* kb   = (const float*)d_in[4];
    const float* km   = (const float*)d_in[5];
    const float* kvv  = (const float*)d_in[6];
    const float* vg   = (const float*)d_in[7];
    const float* vb   = (const float*)d_in[8];
    const float* vm   = (const float*)d_in[9];
    const float* vv   = (const float*)d_in[10];
    const float* Wt   = (const float*)d_in[11];
    const float* bt   = (const float*)d_in[12];
    const float* cw   = (const float*)d_in[13];
    const float* cb   = (const float*)d_in[14];
    const float* ag   = (const float*)d_in[15];
    const float* ab   = (const float*)d_in[16];
    const float* am   = (const float*)d_in[17];
    const float* av   = (const float*)d_in[18];

    char* ws = (char*)d_ws;
    float4*         pre       = (float4*)        (ws);                 //  8,388,608
    int*            hist      = (int*)           (ws + 8388608);       //  4,194,304
    int*            offs      = (int*)           (ws + 12582912);      //  4,194,304
    int*            offs_live = (int*)           (ws + 16777216);      //  4,194,304
    unsigned short* valb      = (unsigned short*)(ws + 20971520);      // 16,777,216 -> end 37,748,736
    uint4*          rec       = (uint4*)         (ws + 37748736);      // 25,165,824 -> end 62,914,560
    unsigned short* gridb     = (unsigned short*)(ws + 62914560);      // 33,554,432 -> end 96,468,992
    unsigned short* wpre      = (unsigned short*)(ws + 96468992);      //    114,688 -> end 96,583,680
    unsigned short* convo     = (unsigned short*)(ws + 20971520);      // 33,554,432 (alias valb+rec, dead by k_conv5)

    k_zero<<<dim3(1024), dim3(256), 0, stream>>>((uint4*)hist);

    k_wprep<<<dim3(NH), dim3(256), 0, stream>>>(cw, wpre);

    k_front3<<<dim3(NB * 128), dim3(256), 0, stream>>>(
        x, orig, wkv, kg, kb, km, kvv, vg, vb, vm, vv, Wt, bt, valb, pre, hist);

    k_scan_cells<<<dim3(NB * NH), dim3(1024), 0, stream>>>(hist, offs, offs_live);

    k_scatter2<<<dim3((NB * NH * NN) / 256), dim3(256), 0, stream>>>(
        pre, valb, offs_live, rec);

    k_splat6<<<dim3(NB * NH * NG), dim3(1024), 0, stream>>>(rec, hist, offs, gridb);

    k_conv5<<<dim3(NB * NH * 32), dim3(512), 0, stream>>>(gridb, wpre, cb, convo);

    k_slice<<<dim3((NB * NH * NN) / 256), dim3(256), 0, stream>>>(
        convo, pre, ag, ab, am, av, (float*)d_out);
}